// Round 1
// baseline (1278.607 us; speedup 1.0000x reference)
//
#include <hip/hip_runtime.h>
#include <hip/hip_bf16.h>
#include <math.h>

#define DM   512
#define DI   1024
#define NS   64
#define RDT  32
#define BB   2
#define LL   1000
#define MROWS (BB*LL)   // 2000

// ---------------------------------------------------------------- rmsnorm ---
__global__ __launch_bounds__(256)
void rmsnorm_k(const float* __restrict__ x, float* __restrict__ xn) {
    int row = blockIdx.x;               // 0..1999 = (b*L + l)
    int tid = threadIdx.x;              // 256 threads, 2 floats each
    const float* xr = x + (size_t)row * DM;
    float2 v = *(const float2*)(xr + tid * 2);
    float ss = v.x * v.x + v.y * v.y;
    #pragma unroll
    for (int off = 32; off; off >>= 1) ss += __shfl_xor(ss, off, 64);
    __shared__ float red[4];
    if ((tid & 63) == 0) red[tid >> 6] = ss;
    __syncthreads();
    float tot = red[0] + red[1] + red[2] + red[3];
    float scale = rsqrtf(tot / (float)DM + 1e-5f);
    float* o = xn + (size_t)row * DM;
    o[tid * 2]     = v.x * scale;
    o[tid * 2 + 1] = v.y * scale;
}

// ------------------------------------------------------------ generic GEMM --
// C[M,N] = A[M,K] (opt. row-flipped in time, opt. scaled along K) * W[N,K]^T
// EPI: 0 = store; 1 = softplus(acc + bias[n]); 2 = store acc + 2*X[m];
//      3 = C[fliprow(m)] += acc
template<int EPI>
__global__ __launch_bounds__(256)
void gemm_k(const float* __restrict__ A, int lda, int flipA,
            const float* __restrict__ kscale,
            const float* __restrict__ W,          // (N,K) row-major
            float* __restrict__ C, int ldc,
            const float* __restrict__ bias,
            const float* __restrict__ X,
            int M, int N, int K)
{
    __shared__ float As[16 * 68];
    __shared__ float Ws[16 * 68];
    int tid = threadIdx.x;
    int tx = tid & 15, ty = tid >> 4;
    int m0 = blockIdx.y * 64, n0 = blockIdx.x * 64;
    int lr = tid >> 2;     // 0..63 row within tile
    int lq = tid & 3;      // k-quad (4 floats)

    float acc[4][4] = {};

    for (int k0 = 0; k0 < K; k0 += 16) {
        // ---- stage A tile (transposed to As[k][m], pitch 68)
        {
            int rg = m0 + lr;
            float4 v = make_float4(0.f, 0.f, 0.f, 0.f);
            if (rg < M) {
                int rs = rg;
                if (flipA) { int b = rg / LL, t = rg % LL; rs = b * LL + (LL - 1 - t); }
                v = *(const float4*)(A + (size_t)rs * lda + k0 + lq * 4);
            }
            if (kscale) {
                const float* s = kscale + k0 + lq * 4;
                v.x *= s[0]; v.y *= s[1]; v.z *= s[2]; v.w *= s[3];
            }
            As[(lq * 4 + 0) * 68 + lr] = v.x;
            As[(lq * 4 + 1) * 68 + lr] = v.y;
            As[(lq * 4 + 2) * 68 + lr] = v.z;
            As[(lq * 4 + 3) * 68 + lr] = v.w;
        }
        // ---- stage W tile (transposed to Ws[k][n], pitch 68)
        {
            int ng = n0 + lr;
            float4 v = make_float4(0.f, 0.f, 0.f, 0.f);
            if (ng < N) v = *(const float4*)(W + (size_t)ng * K + k0 + lq * 4);
            Ws[(lq * 4 + 0) * 68 + lr] = v.x;
            Ws[(lq * 4 + 1) * 68 + lr] = v.y;
            Ws[(lq * 4 + 2) * 68 + lr] = v.z;
            Ws[(lq * 4 + 3) * 68 + lr] = v.w;
        }
        __syncthreads();
        #pragma unroll
        for (int k = 0; k < 16; k++) {
            float4 a = *(const float4*)(As + k * 68 + ty * 4);
            float4 w = *(const float4*)(Ws + k * 68 + tx * 4);
            float av[4] = {a.x, a.y, a.z, a.w};
            float wv[4] = {w.x, w.y, w.z, w.w};
            #pragma unroll
            for (int i = 0; i < 4; i++)
                #pragma unroll
                for (int j = 0; j < 4; j++)
                    acc[i][j] = fmaf(av[i], wv[j], acc[i][j]);
        }
        __syncthreads();
    }

    #pragma unroll
    for (int i = 0; i < 4; i++) {
        int m = m0 + ty * 4 + i;
        if (m >= M) continue;
        int mo = m;
        if (EPI == 3) { int b = m / LL, t = m % LL; mo = b * LL + (LL - 1 - t); }
        #pragma unroll
        for (int j = 0; j < 4; j++) {
            int n = n0 + tx * 4 + j;
            if (n >= N) continue;
            float v = acc[i][j];
            if (EPI == 1) {
                v += bias[n];
                v = (v > 20.f) ? v : log1pf(__expf(v));
            }
            if (EPI == 2) v += 2.0f * X[(size_t)m * ldc + n];
            if (EPI == 3) C[(size_t)mo * ldc + n] += v;
            else          C[(size_t)mo * ldc + n]  = v;
        }
    }
}

// ---------------------------------------------------- causal dwconv + silu --
__global__ __launch_bounds__(256)
void conv_silu_k(const float* __restrict__ xz0, const float* __restrict__ xz1,
                 const float* __restrict__ cw0, const float* __restrict__ cw1,
                 const float* __restrict__ cb0, const float* __restrict__ cb1,
                 float* __restrict__ xc0, float* __restrict__ xc1)
{
    int idx = blockIdx.x * 256 + threadIdx.x;     // < 2*2*1000*1024
    int d   = idx & 1023;
    int t   = (idx >> 10) % LL;
    int b   = (idx / (1024 * LL)) & 1;
    int dir = idx / (1024 * LL * BB);
    const float* in = dir ? xz1 : xz0;
    const float* cw = dir ? cw1 : cw0;
    const float* cb = dir ? cb1 : cb0;
    float*      out = dir ? xc1 : xc0;
    float acc = cb[d];
    #pragma unroll
    for (int k = 0; k < 4; k++) {
        int ts = t - 3 + k;
        if (ts >= 0)
            acc = fmaf(in[((size_t)(b * LL + ts)) * 2048 + d], cw[d * 4 + k], acc);
    }
    float s = acc / (1.f + __expf(-acc));         // silu
    out[((size_t)(b * LL + t)) * 1024 + d] = s;
}

// ------------------------------------------------------------ selective scan
// one wave per (dir,b,d); lane n = state n.  Writes gated y into xz lo half.
__global__ __launch_bounds__(256)
void scan_k(const float* __restrict__ dt0, const float* __restrict__ dt1,
            const float* __restrict__ xc0, const float* __restrict__ xc1,
            const float* __restrict__ xd0, const float* __restrict__ xd1,
            const float* __restrict__ Al0, const float* __restrict__ Al1,
            const float* __restrict__ Dc0, const float* __restrict__ Dc1,
            float* __restrict__ xz0, float* __restrict__ xz1)
{
    int gw   = (blockIdx.x * blockDim.x + threadIdx.x) >> 6;  // global wave id
    int lane = threadIdx.x & 63;
    int dir  = gw >> 11;          // / 2048
    int rem  = gw & 2047;
    int b    = rem >> 10;
    int d    = rem & 1023;

    const float* dt = dir ? dt1 : dt0;
    const float* xc = dir ? xc1 : xc0;
    const float* xd = dir ? xd1 : xd0;
    const float* Al = dir ? Al1 : Al0;
    const float* Dc = dir ? Dc1 : Dc0;
    float*       xz = dir ? xz1 : xz0;

    float a  = -__expf(Al[d * 64 + lane]) * 1.44269504f;   // A * log2(e)
    float Dp = Dc[d];
    float h  = 0.f;
    const size_t rowb = (size_t)b * LL;

    for (int t = 0; t < LL; t++) {
        size_t r = rowb + t;
        float dtv = dt[r * 1024 + d];
        float u   = xc[r * 1024 + d];
        float Bn  = xd[r * 160 + 32 + lane];
        float Cn  = xd[r * 160 + 96 + lane];
        float dA  = exp2f(dtv * a);                 // exp(dt*A)
        h = fmaf(dA, h, dtv * u * Bn);
        float p = h * Cn;
        #pragma unroll
        for (int off = 32; off; off >>= 1) p += __shfl_xor(p, off, 64);
        if (lane == 0) {
            float zv  = xz[r * 2048 + 1024 + d];
            float sig = 1.f / (1.f + __expf(-zv));
            xz[r * 2048 + d] = (p + u * Dp) * (zv * sig);
        }
    }
}

// -------------------------------------------------------------------- launch
extern "C" void kernel_launch(void* const* d_in, const int* in_sizes, int n_in,
                              void* d_out, int out_size, void* d_ws, size_t ws_size,
                              hipStream_t stream) {
    const float* x = (const float*)d_in[0];
    // per-direction params: [norm_w, in_proj, conv_w, conv_b, x_proj, dt_w, dt_b, A_log, D, out_proj]
    const float* P[2][10];
    for (int dir = 0; dir < 2; dir++)
        for (int i = 0; i < 10; i++)
            P[dir][i] = (const float*)d_in[1 + dir * 10 + i];

    float* ws = (float*)d_ws;
    float* xn      = ws;                                  // 1,024,000
    float* xz[2]   = { ws +  1024000, ws +  5120000 };    // 4,096,000 each
    float* xc[2]   = { ws +  9216000, ws + 11264000 };    // 2,048,000 each
    float* xdbl[2] = { ws + 13312000, ws + 13632000 };    //   320,000 each
    float* dtb[2]  = { ws + 13952000, ws + 16000000 };    // 2,048,000 each
    // total 18,048,000 floats = 72.2 MB

    float* out = (float*)d_out;

    // 1. rmsnorm (norm_w folded into GEMM1 load)
    rmsnorm_k<<<MROWS, 256, 0, stream>>>(x, xn);

    // 2. xz = (xn * norm_w) @ in_proj^T   (dir b reads time-flipped rows)
    for (int dir = 0; dir < 2; dir++)
        gemm_k<0><<<dim3(2048 / 64, 32), 256, 0, stream>>>(
            xn, DM, dir, P[dir][0], P[dir][1], xz[dir], 2048,
            nullptr, nullptr, MROWS, 2048, DM);

    // 3. causal depthwise conv + silu  (both dirs)
    conv_silu_k<<<(2 * BB * LL * DI) / 256, 256, 0, stream>>>(
        xz[0], xz[1], P[0][2], P[1][2], P[0][3], P[1][3], xc[0], xc[1]);

    // 4. x_dbl = xc @ x_proj^T   (N=160: dt_raw | B | C)
    for (int dir = 0; dir < 2; dir++)
        gemm_k<0><<<dim3(3, 32), 256, 0, stream>>>(
            xc[dir], DI, 0, nullptr, P[dir][4], xdbl[dir], 160,
            nullptr, nullptr, MROWS, 160, DI);

    // 5. dt = softplus(dt_raw @ dt_w^T + dt_b)
    for (int dir = 0; dir < 2; dir++)
        gemm_k<1><<<dim3(16, 32), 256, 0, stream>>>(
            xdbl[dir], 160, 0, nullptr, P[dir][5], dtb[dir], DI,
            P[dir][6], nullptr, MROWS, DI, RDT);

    // 6. selective scan + gate; writes yg into xz lo half
    scan_k<<<(2 * BB * DI) / 4, 256, 0, stream>>>(
        dtb[0], dtb[1], xc[0], xc[1], xdbl[0], xdbl[1],
        P[0][7], P[1][7], P[0][8], P[1][8], xz[0], xz[1]);

    // 7. out = 2*x + yg_f @ out_proj_f^T  ;  out[flip] += yg_b @ out_proj_b^T
    gemm_k<2><<<dim3(8, 32), 256, 0, stream>>>(
        xz[0], 2048, 0, nullptr, P[0][9], out, DM,
        nullptr, x, MROWS, DM, DI);
    gemm_k<3><<<dim3(8, 32), 256, 0, stream>>>(
        xz[1], 2048, 0, nullptr, P[1][9], out, DM,
        nullptr, nullptr, MROWS, DM, DI);
}

// Round 2
// 789.011 us; speedup vs baseline: 1.6205x; 1.6205x over previous
//
#include <hip/hip_runtime.h>
#include <hip/hip_bf16.h>
#include <math.h>

#define DM   512
#define DI   1024
#define NS   64
#define RDT  32
#define BB   2
#define LL   1000
#define MROWS (BB*LL)   // 2000

// ---------------------------------------------------------------- rmsnorm ---
__global__ __launch_bounds__(256)
void rmsnorm_k(const float* __restrict__ x, float* __restrict__ xn) {
    int row = blockIdx.x;
    int tid = threadIdx.x;
    const float* xr = x + (size_t)row * DM;
    float2 v = *(const float2*)(xr + tid * 2);
    float ss = v.x * v.x + v.y * v.y;
    #pragma unroll
    for (int off = 32; off; off >>= 1) ss += __shfl_xor(ss, off, 64);
    __shared__ float red[4];
    if ((tid & 63) == 0) red[tid >> 6] = ss;
    __syncthreads();
    float tot = red[0] + red[1] + red[2] + red[3];
    float scale = rsqrtf(tot / (float)DM + 1e-5f);
    float* o = xn + (size_t)row * DM;
    o[tid * 2]     = v.x * scale;
    o[tid * 2 + 1] = v.y * scale;
}

// ------------------------------------------------------------ generic GEMM --
// EPI: 0 = store; 2 = store acc + 2*X[m]; 3 = C[fliprow(m)] += acc
template<int EPI>
__global__ __launch_bounds__(256)
void gemm_k(const float* __restrict__ A, int lda, int flipA,
            const float* __restrict__ kscale,
            const float* __restrict__ W,
            float* __restrict__ C, int ldc,
            const float* __restrict__ X,
            int M, int N, int K)
{
    __shared__ float As[16 * 68];
    __shared__ float Ws[16 * 68];
    int tid = threadIdx.x;
    int tx = tid & 15, ty = tid >> 4;
    int m0 = blockIdx.y * 64, n0 = blockIdx.x * 64;
    int lr = tid >> 2;
    int lq = tid & 3;

    float acc[4][4] = {};

    for (int k0 = 0; k0 < K; k0 += 16) {
        {
            int rg = m0 + lr;
            float4 v = make_float4(0.f, 0.f, 0.f, 0.f);
            if (rg < M) {
                int rs = rg;
                if (flipA) { int b = rg / LL, t = rg % LL; rs = b * LL + (LL - 1 - t); }
                v = *(const float4*)(A + (size_t)rs * lda + k0 + lq * 4);
            }
            if (kscale) {
                const float* s = kscale + k0 + lq * 4;
                v.x *= s[0]; v.y *= s[1]; v.z *= s[2]; v.w *= s[3];
            }
            As[(lq * 4 + 0) * 68 + lr] = v.x;
            As[(lq * 4 + 1) * 68 + lr] = v.y;
            As[(lq * 4 + 2) * 68 + lr] = v.z;
            As[(lq * 4 + 3) * 68 + lr] = v.w;
        }
        {
            int ng = n0 + lr;
            float4 v = make_float4(0.f, 0.f, 0.f, 0.f);
            if (ng < N) v = *(const float4*)(W + (size_t)ng * K + k0 + lq * 4);
            Ws[(lq * 4 + 0) * 68 + lr] = v.x;
            Ws[(lq * 4 + 1) * 68 + lr] = v.y;
            Ws[(lq * 4 + 2) * 68 + lr] = v.z;
            Ws[(lq * 4 + 3) * 68 + lr] = v.w;
        }
        __syncthreads();
        #pragma unroll
        for (int k = 0; k < 16; k++) {
            float4 a = *(const float4*)(As + k * 68 + ty * 4);
            float4 w = *(const float4*)(Ws + k * 68 + tx * 4);
            float av[4] = {a.x, a.y, a.z, a.w};
            float wv[4] = {w.x, w.y, w.z, w.w};
            #pragma unroll
            for (int i = 0; i < 4; i++)
                #pragma unroll
                for (int j = 0; j < 4; j++)
                    acc[i][j] = fmaf(av[i], wv[j], acc[i][j]);
        }
        __syncthreads();
    }

    #pragma unroll
    for (int i = 0; i < 4; i++) {
        int m = m0 + ty * 4 + i;
        if (m >= M) continue;
        int mo = m;
        if (EPI == 3) { int b = m / LL, t = m % LL; mo = b * LL + (LL - 1 - t); }
        #pragma unroll
        for (int j = 0; j < 4; j++) {
            int n = n0 + tx * 4 + j;
            if (n >= N) continue;
            float v = acc[i][j];
            if (EPI == 2) v += 2.0f * X[(size_t)m * ldc + n];
            if (EPI == 3) C[(size_t)mo * ldc + n] += v;
            else          C[(size_t)mo * ldc + n]  = v;
        }
    }
}

// ------------------------- causal dwconv + silu -> TRANSPOSED xcT [b][d][t] --
__global__ __launch_bounds__(256)
void conv_silu_k(const float* __restrict__ xz0, const float* __restrict__ xz1,
                 const float* __restrict__ cw0, const float* __restrict__ cw1,
                 const float* __restrict__ cb0, const float* __restrict__ cb1,
                 float* __restrict__ xcT0, float* __restrict__ xcT1)
{
    __shared__ float Ls[64 * 65];
    int dirb = blockIdx.z;
    int dir = dirb >> 1, b = dirb & 1;
    int d0 = blockIdx.x * 64, t0 = blockIdx.y * 64;
    int tid = threadIdx.x;
    int dl = tid & 63, tg = tid >> 6;

    const float* in = (dir ? xz1 : xz0) + (size_t)b * LL * 2048;
    const float* cw = dir ? cw1 : cw0;
    const float* cb = dir ? cb1 : cb0;
    float*      xcT = dir ? xcT1 : xcT0;

    float4 w4 = ((const float4*)cw)[d0 + dl];
    float bias = cb[d0 + dl];

    int ts = t0 + tg * 16;
    float x3 = 0.f, x2 = 0.f, x1 = 0.f;
    if (ts - 3 >= 0 && ts - 3 < LL) x3 = in[(size_t)(ts - 3) * 2048 + d0 + dl];
    if (ts - 2 >= 0 && ts - 2 < LL) x2 = in[(size_t)(ts - 2) * 2048 + d0 + dl];
    if (ts - 1 >= 0 && ts - 1 < LL) x1 = in[(size_t)(ts - 1) * 2048 + d0 + dl];

    #pragma unroll
    for (int i = 0; i < 16; i++) {
        int t = ts + i;
        float x0v = (t < LL) ? in[(size_t)t * 2048 + d0 + dl] : 0.f;
        float a = bias + x3 * w4.x + x2 * w4.y + x1 * w4.z + x0v * w4.w;
        float s = a / (1.f + __expf(-a));
        Ls[dl * 65 + tg * 16 + i] = s;
        x3 = x2; x2 = x1; x1 = x0v;
    }
    __syncthreads();
    int tl = tid & 63, dg = tid >> 6;
    #pragma unroll
    for (int i = 0; i < 16; i++) {
        int dd = dg * 16 + i;
        int t = t0 + tl;
        if (t < LL)
            xcT[((size_t)(b * 1024) + d0 + dd) * LL + t] = Ls[dd * 65 + tl];
    }
}

// --------------------- x_proj GEMM: xdbl[b*L+t][160] = xcT^T @ x_proj^T -----
__global__ __launch_bounds__(256)
void gemm_xp_k(const float* __restrict__ xcT0, const float* __restrict__ xcT1,
               const float* __restrict__ xp0, const float* __restrict__ xp1,
               float* __restrict__ xd0, float* __restrict__ xd1)
{
    __shared__ float As[16 * 68];   // [k][m=t]
    __shared__ float Ws[16 * 68];   // [k][n]
    int dirb = blockIdx.z;
    int dir = dirb >> 1, b = dirb & 1;
    const float* xcT = (dir ? xcT1 : xcT0) + (size_t)b * 1024 * LL;
    const float* W   = dir ? xp1 : xp0;     // (160,1024)
    float*       C   = (dir ? xd1 : xd0) + (size_t)b * LL * 160;
    int n0 = blockIdx.x * 64, t0 = blockIdx.y * 64;
    int tid = threadIdx.x;
    int tx = tid & 15, ty = tid >> 4;

    float acc[4][4] = {};

    for (int k0 = 0; k0 < 1024; k0 += 16) {
        {   // A: 16k x 64t from transposed source (coalesced along t)
            int kk = tid & 15, mq = tid >> 4;
            float4 v = make_float4(0.f, 0.f, 0.f, 0.f);
            if (t0 + mq * 4 + 3 < LL)
                v = *(const float4*)(xcT + (size_t)(k0 + kk) * LL + t0 + mq * 4);
            *(float4*)(As + kk * 68 + mq * 4) = v;
        }
        {   // W: 64n x 16k, transposed into Ws[k][n]
            int row = tid >> 2, q = tid & 3;
            float4 v = make_float4(0.f, 0.f, 0.f, 0.f);
            if (n0 + row < 160)
                v = *(const float4*)(W + (size_t)(n0 + row) * 1024 + k0 + q * 4);
            Ws[(q * 4 + 0) * 68 + row] = v.x;
            Ws[(q * 4 + 1) * 68 + row] = v.y;
            Ws[(q * 4 + 2) * 68 + row] = v.z;
            Ws[(q * 4 + 3) * 68 + row] = v.w;
        }
        __syncthreads();
        #pragma unroll
        for (int k = 0; k < 16; k++) {
            float4 a = *(const float4*)(As + k * 68 + ty * 4);
            float4 w = *(const float4*)(Ws + k * 68 + tx * 4);
            float av[4] = {a.x, a.y, a.z, a.w};
            float wv[4] = {w.x, w.y, w.z, w.w};
            #pragma unroll
            for (int i = 0; i < 4; i++)
                #pragma unroll
                for (int j = 0; j < 4; j++)
                    acc[i][j] = fmaf(av[i], wv[j], acc[i][j]);
        }
        __syncthreads();
    }

    #pragma unroll
    for (int i = 0; i < 4; i++) {
        int t = t0 + ty * 4 + i;
        if (t >= LL) continue;
        #pragma unroll
        for (int j = 0; j < 4; j++) {
            int n = n0 + tx * 4 + j;
            if (n < 160) C[(size_t)t * 160 + n] = acc[i][j];
        }
    }
}

// ---- dt GEMM (K=32) + softplus, output TRANSPOSED dtT [b][d][t] ------------
__global__ __launch_bounds__(256)
void gemm_dt_k(const float* __restrict__ xd0, const float* __restrict__ xd1,
               const float* __restrict__ w0, const float* __restrict__ w1,
               const float* __restrict__ bb0, const float* __restrict__ bb1,
               float* __restrict__ dtT0, float* __restrict__ dtT1)
{
    __shared__ float As[64 * 33];   // [m=t][k]
    __shared__ float Ws[32 * 68];   // [k][n]
    __shared__ float T[64 * 67];    // [n][m] for transposed store
    int dirb = blockIdx.z;
    int dir = dirb >> 1, b = dirb & 1;
    const float* xd = (dir ? xd1 : xd0) + (size_t)b * LL * 160;
    const float* W  = dir ? w1 : w0;        // (1024,32)
    const float* bi = dir ? bb1 : bb0;
    float*      dtT = (dir ? dtT1 : dtT0) + (size_t)b * 1024 * LL;
    int n0 = blockIdx.x * 64, t0 = blockIdx.y * 64;
    int tid = threadIdx.x;
    int tx = tid & 15, ty = tid >> 4;

    #pragma unroll
    for (int i = 0; i < 2; i++) {
        int j = tid + 256 * i;          // 0..511
        int row = j >> 3, q = j & 7;
        float4 v = make_float4(0.f, 0.f, 0.f, 0.f);
        if (t0 + row < LL)
            v = *(const float4*)(xd + (size_t)(t0 + row) * 160 + q * 4);
        As[row * 33 + q * 4 + 0] = v.x;
        As[row * 33 + q * 4 + 1] = v.y;
        As[row * 33 + q * 4 + 2] = v.z;
        As[row * 33 + q * 4 + 3] = v.w;
        float4 wv = *(const float4*)(W + (size_t)(n0 + row) * 32 + q * 4);
        Ws[(q * 4 + 0) * 68 + row] = wv.x;
        Ws[(q * 4 + 1) * 68 + row] = wv.y;
        Ws[(q * 4 + 2) * 68 + row] = wv.z;
        Ws[(q * 4 + 3) * 68 + row] = wv.w;
    }
    __syncthreads();

    float acc[4][4] = {};
    #pragma unroll 8
    for (int k = 0; k < 32; k++) {
        float4 w = *(const float4*)(Ws + k * 68 + tx * 4);
        float wv[4] = {w.x, w.y, w.z, w.w};
        float av[4];
        #pragma unroll
        for (int i = 0; i < 4; i++) av[i] = As[(ty * 4 + i) * 33 + k];
        #pragma unroll
        for (int i = 0; i < 4; i++)
            #pragma unroll
            for (int j = 0; j < 4; j++)
                acc[i][j] = fmaf(av[i], wv[j], acc[i][j]);
    }
    __syncthreads();

    #pragma unroll
    for (int i = 0; i < 4; i++) {
        #pragma unroll
        for (int j = 0; j < 4; j++) {
            int n = tx * 4 + j;
            float v = acc[i][j] + bi[n0 + n];
            v = (v > 20.f) ? v : log1pf(__expf(v));
            T[n * 67 + ty * 4 + i] = v;
        }
    }
    __syncthreads();

    int tl = tid & 63, ng = tid >> 6;
    #pragma unroll
    for (int i = 0; i < 16; i++) {
        int nl = ng * 16 + i;
        int t = t0 + tl;
        if (t < LL)
            dtT[(size_t)(n0 + nl) * LL + t] = T[nl * 67 + tl];
    }
}

// ------------------------------------------------------------ selective scan
// wave = (dir,b,d); lane = state n. Inner loop: LDS + shuffles only.
// Writes y (incl. +u*D) IN PLACE over dtT.
__global__ __launch_bounds__(256)
void scan_k(float* __restrict__ dtT0, float* __restrict__ dtT1,
            const float* __restrict__ ucT0, const float* __restrict__ ucT1,
            const float* __restrict__ xd0, const float* __restrict__ xd1,
            const float* __restrict__ Al0, const float* __restrict__ Al1,
            const float* __restrict__ Dc0, const float* __restrict__ Dc1)
{
    __shared__ float Bs[64 * 68];
    __shared__ float Cs[64 * 68];
    int dirb = blockIdx.y;
    int dir = dirb >> 1, b = dirb & 1;
    int wid = threadIdx.x >> 6, lane = threadIdx.x & 63;
    int d = blockIdx.x * 4 + wid;

    float*       dtT = (dir ? dtT1 : dtT0);
    const float* ucT = (dir ? ucT1 : ucT0);
    const float* xd  = (dir ? xd1 : xd0) + (size_t)b * LL * 160;
    const float* Al  = dir ? Al1 : Al0;
    const float* Dc  = dir ? Dc1 : Dc0;

    float a  = -__expf(Al[d * 64 + lane]) * 1.44269504f;
    float Dp = Dc[d];
    float h  = 0.f;
    size_t chan = ((size_t)(b * 1024 + d)) * LL;

    for (int t0 = 0; t0 < LL; t0 += 64) {
        int rem = min(64, LL - t0);
        __syncthreads();
        #pragma unroll
        for (int i = 0; i < 8; i++) {
            int j = threadIdx.x + 256 * i;      // 0..2047
            int row = j >> 5, q = j & 31;
            float4 v = make_float4(0.f, 0.f, 0.f, 0.f);
            if (row < rem)
                v = *(const float4*)(xd + (size_t)(t0 + row) * 160 + 32 + q * 4);
            if (q < 16) *(float4*)(Bs + row * 68 + (q & 15) * 4) = v;
            else        *(float4*)(Cs + row * 68 + (q & 15) * 4) = v;
        }
        float dta = 0.f, ua = 0.f;
        if (lane < rem) {
            dta = dtT[chan + t0 + lane];
            ua  = ucT[chan + t0 + lane];
        }
        __syncthreads();

        float yv = 0.f;
        #define SCAN_STEP(tt) {                                   \
            float dtv = __shfl(dta, (tt), 64);                    \
            float u   = __shfl(ua,  (tt), 64);                    \
            float Bn  = Bs[(tt) * 68 + lane];                     \
            float Cn  = Cs[(tt) * 68 + lane];                     \
            float dA  = exp2f(dtv * a);                           \
            h = fmaf(dA, h, dtv * u * Bn);                        \
            float p = h * Cn;                                     \
            _Pragma("unroll")                                     \
            for (int off = 32; off; off >>= 1)                    \
                p += __shfl_xor(p, off, 64);                      \
            yv = (lane == (tt)) ? p : yv;                         \
        }
        if (rem == 64) {
            #pragma unroll 8
            for (int tt = 0; tt < 64; tt++) SCAN_STEP(tt);
        } else {
            for (int tt = 0; tt < rem; tt++) SCAN_STEP(tt);
        }
        #undef SCAN_STEP

        if (lane < rem)
            dtT[chan + t0 + lane] = yv + ua * Dp;
    }
}

// ---------------- gate: xz_lo[row][d] = yT[d][t] * silu(z[row][1024+d]) -----
__global__ __launch_bounds__(256)
void gate_k(const float* __restrict__ yT0, const float* __restrict__ yT1,
            float* __restrict__ xz0, float* __restrict__ xz1)
{
    __shared__ float Ls[64 * 65];
    int dirb = blockIdx.z;
    int dir = dirb >> 1, b = dirb & 1;
    int d0 = blockIdx.x * 64, t0 = blockIdx.y * 64;
    int tid = threadIdx.x;
    const float* yT = (dir ? yT1 : yT0) + (size_t)b * 1024 * LL;
    float*       xz = (dir ? xz1 : xz0) + (size_t)b * LL * 2048;

    int tl = tid & 63, dg = tid >> 6;
    #pragma unroll
    for (int i = 0; i < 16; i++) {
        int dd = dg * 16 + i;
        int t = t0 + tl;
        float v = (t < LL) ? yT[(size_t)(d0 + dd) * LL + t] : 0.f;
        Ls[dd * 65 + tl] = v;
    }
    __syncthreads();
    int dcol = tid & 63, tg = tid >> 6;
    #pragma unroll
    for (int i = 0; i < 16; i++) {
        int t = t0 + tg * 16 + i;
        if (t >= LL) continue;
        float z = xz[(size_t)t * 2048 + 1024 + d0 + dcol];
        float y = Ls[dcol * 65 + tg * 16 + i];
        float s = z / (1.f + __expf(-z));
        xz[(size_t)t * 2048 + d0 + dcol] = y * s;
    }
}

// -------------------------------------------------------------------- launch
extern "C" void kernel_launch(void* const* d_in, const int* in_sizes, int n_in,
                              void* d_out, int out_size, void* d_ws, size_t ws_size,
                              hipStream_t stream) {
    const float* x = (const float*)d_in[0];
    const float* P[2][10];
    for (int dir = 0; dir < 2; dir++)
        for (int i = 0; i < 10; i++)
            P[dir][i] = (const float*)d_in[1 + dir * 10 + i];

    float* ws = (float*)d_ws;
    float* xn      = ws;                                   // 1,024,000 (xdbl aliases after gemm1)
    float* xdbl[2] = { ws, ws + 320000 };
    float* xz[2]   = { ws + 1024000, ws + 5120000 };       // 4,096,000 each
    float* xcT[2]  = { ws + 9216000, ws + 11264000 };      // 2,048,000 each
    float* dtT[2]  = { ws + 13312000, ws + 15360000 };     // 2,048,000 each (y in-place)
    float* out = (float*)d_out;

    rmsnorm_k<<<MROWS, 256, 0, stream>>>(x, xn);

    for (int dir = 0; dir < 2; dir++)
        gemm_k<0><<<dim3(32, 32), 256, 0, stream>>>(
            xn, DM, dir, P[dir][0], P[dir][1], xz[dir], 2048,
            nullptr, MROWS, 2048, DM);

    conv_silu_k<<<dim3(16, 16, 4), 256, 0, stream>>>(
        xz[0], xz[1], P[0][2], P[1][2], P[0][3], P[1][3], xcT[0], xcT[1]);

    gemm_xp_k<<<dim3(3, 16, 4), 256, 0, stream>>>(
        xcT[0], xcT[1], P[0][4], P[1][4], xdbl[0], xdbl[1]);

    gemm_dt_k<<<dim3(16, 16, 4), 256, 0, stream>>>(
        xdbl[0], xdbl[1], P[0][5], P[1][5], P[0][6], P[1][6], dtT[0], dtT[1]);

    scan_k<<<dim3(256, 4), 256, 0, stream>>>(
        dtT[0], dtT[1], xcT[0], xcT[1], xdbl[0], xdbl[1],
        P[0][7], P[1][7], P[0][8], P[1][8]);

    gate_k<<<dim3(16, 16, 4), 256, 0, stream>>>(
        dtT[0], dtT[1], xz[0], xz[1]);

    gemm_k<2><<<dim3(8, 32), 256, 0, stream>>>(
        xz[0], 2048, 0, nullptr, P[0][9], out, DM,
        x, MROWS, DM, DI);
    gemm_k<3><<<dim3(8, 32), 256, 0, stream>>>(
        xz[1], 2048, 0, nullptr, P[1][9], out, DM,
        nullptr, MROWS, DM, DI);
}

// Round 3
// 640.367 us; speedup vs baseline: 1.9967x; 1.2321x over previous
//
#include <hip/hip_runtime.h>
#include <hip/hip_bf16.h>
#include <math.h>

#define DM   512
#define DI   1024
#define NS   64
#define RDT  32
#define BB   2
#define LL   1000
#define MROWS (BB*LL)   // 2000

// ---------------------------------------------------------------- rmsnorm ---
__global__ __launch_bounds__(256)
void rmsnorm_k(const float* __restrict__ x, float* __restrict__ xn) {
    int row = blockIdx.x;
    int tid = threadIdx.x;
    const float* xr = x + (size_t)row * DM;
    float2 v = *(const float2*)(xr + tid * 2);
    float ss = v.x * v.x + v.y * v.y;
    #pragma unroll
    for (int off = 32; off; off >>= 1) ss += __shfl_xor(ss, off, 64);
    __shared__ float red[4];
    if ((tid & 63) == 0) red[tid >> 6] = ss;
    __syncthreads();
    float tot = red[0] + red[1] + red[2] + red[3];
    float scale = rsqrtf(tot / (float)DM + 1e-5f);
    float* o = xn + (size_t)row * DM;
    o[tid * 2]     = v.x * scale;
    o[tid * 2 + 1] = v.y * scale;
}

// ------------------------------------------------------------ generic GEMM --
// EPI: 0 = store; 2 = store acc + 2*X[m]; 3 = C[fliprow(m)] += acc
template<int EPI>
__global__ __launch_bounds__(256)
void gemm_k(const float* __restrict__ A, int lda, int flipA,
            const float* __restrict__ kscale,
            const float* __restrict__ W,
            float* __restrict__ C, int ldc,
            const float* __restrict__ X,
            int M, int N, int K)
{
    __shared__ float As[16 * 68];
    __shared__ float Ws[16 * 68];
    int tid = threadIdx.x;
    int tx = tid & 15, ty = tid >> 4;
    int m0 = blockIdx.y * 64, n0 = blockIdx.x * 64;
    int lr = tid >> 2;
    int lq = tid & 3;

    float acc[4][4] = {};

    for (int k0 = 0; k0 < K; k0 += 16) {
        {
            int rg = m0 + lr;
            float4 v = make_float4(0.f, 0.f, 0.f, 0.f);
            if (rg < M) {
                int rs = rg;
                if (flipA) { int b = rg / LL, t = rg % LL; rs = b * LL + (LL - 1 - t); }
                v = *(const float4*)(A + (size_t)rs * lda + k0 + lq * 4);
            }
            if (kscale) {
                const float* s = kscale + k0 + lq * 4;
                v.x *= s[0]; v.y *= s[1]; v.z *= s[2]; v.w *= s[3];
            }
            As[(lq * 4 + 0) * 68 + lr] = v.x;
            As[(lq * 4 + 1) * 68 + lr] = v.y;
            As[(lq * 4 + 2) * 68 + lr] = v.z;
            As[(lq * 4 + 3) * 68 + lr] = v.w;
        }
        {
            int ng = n0 + lr;
            float4 v = make_float4(0.f, 0.f, 0.f, 0.f);
            if (ng < N) v = *(const float4*)(W + (size_t)ng * K + k0 + lq * 4);
            Ws[(lq * 4 + 0) * 68 + lr] = v.x;
            Ws[(lq * 4 + 1) * 68 + lr] = v.y;
            Ws[(lq * 4 + 2) * 68 + lr] = v.z;
            Ws[(lq * 4 + 3) * 68 + lr] = v.w;
        }
        __syncthreads();
        #pragma unroll
        for (int k = 0; k < 16; k++) {
            float4 a = *(const float4*)(As + k * 68 + ty * 4);
            float4 w = *(const float4*)(Ws + k * 68 + tx * 4);
            float av[4] = {a.x, a.y, a.z, a.w};
            float wv[4] = {w.x, w.y, w.z, w.w};
            #pragma unroll
            for (int i = 0; i < 4; i++)
                #pragma unroll
                for (int j = 0; j < 4; j++)
                    acc[i][j] = fmaf(av[i], wv[j], acc[i][j]);
        }
        __syncthreads();
    }

    #pragma unroll
    for (int i = 0; i < 4; i++) {
        int m = m0 + ty * 4 + i;
        if (m >= M) continue;
        int mo = m;
        if (EPI == 3) { int b = m / LL, t = m % LL; mo = b * LL + (LL - 1 - t); }
        #pragma unroll
        for (int j = 0; j < 4; j++) {
            int n = n0 + tx * 4 + j;
            if (n >= N) continue;
            float v = acc[i][j];
            if (EPI == 2) v += 2.0f * X[(size_t)m * ldc + n];
            if (EPI == 3) C[(size_t)mo * ldc + n] += v;
            else          C[(size_t)mo * ldc + n]  = v;
        }
    }
}

// ------------------------- causal dwconv + silu -> TRANSPOSED xcT [b][d][t] --
__global__ __launch_bounds__(256)
void conv_silu_k(const float* __restrict__ xz0, const float* __restrict__ xz1,
                 const float* __restrict__ cw0, const float* __restrict__ cw1,
                 const float* __restrict__ cb0, const float* __restrict__ cb1,
                 float* __restrict__ xcT0, float* __restrict__ xcT1)
{
    __shared__ float Ls[64 * 65];
    int dirb = blockIdx.z;
    int dir = dirb >> 1, b = dirb & 1;
    int d0 = blockIdx.x * 64, t0 = blockIdx.y * 64;
    int tid = threadIdx.x;
    int dl = tid & 63, tg = tid >> 6;

    const float* in = (dir ? xz1 : xz0) + (size_t)b * LL * 2048;
    const float* cw = dir ? cw1 : cw0;
    const float* cb = dir ? cb1 : cb0;
    float*      xcT = dir ? xcT1 : xcT0;

    float4 w4 = ((const float4*)cw)[d0 + dl];
    float bias = cb[d0 + dl];

    int ts = t0 + tg * 16;
    float x3 = 0.f, x2 = 0.f, x1 = 0.f;
    if (ts - 3 >= 0 && ts - 3 < LL) x3 = in[(size_t)(ts - 3) * 2048 + d0 + dl];
    if (ts - 2 >= 0 && ts - 2 < LL) x2 = in[(size_t)(ts - 2) * 2048 + d0 + dl];
    if (ts - 1 >= 0 && ts - 1 < LL) x1 = in[(size_t)(ts - 1) * 2048 + d0 + dl];

    #pragma unroll
    for (int i = 0; i < 16; i++) {
        int t = ts + i;
        float x0v = (t < LL) ? in[(size_t)t * 2048 + d0 + dl] : 0.f;
        float a = bias + x3 * w4.x + x2 * w4.y + x1 * w4.z + x0v * w4.w;
        float s = a / (1.f + __expf(-a));
        Ls[dl * 65 + tg * 16 + i] = s;
        x3 = x2; x2 = x1; x1 = x0v;
    }
    __syncthreads();
    int tl = tid & 63, dg = tid >> 6;
    #pragma unroll
    for (int i = 0; i < 16; i++) {
        int dd = dg * 16 + i;
        int t = t0 + tl;
        if (t < LL)
            xcT[((size_t)(b * 1024) + d0 + dd) * LL + t] = Ls[dd * 65 + tl];
    }
}

// --------------------- x_proj GEMM: xdbl[b*L+t][160] = xcT^T @ x_proj^T -----
__global__ __launch_bounds__(256)
void gemm_xp_k(const float* __restrict__ xcT0, const float* __restrict__ xcT1,
               const float* __restrict__ xp0, const float* __restrict__ xp1,
               float* __restrict__ xd0, float* __restrict__ xd1)
{
    __shared__ float As[16 * 68];   // [k][m=t]
    __shared__ float Ws[16 * 68];   // [k][n]
    int dirb = blockIdx.z;
    int dir = dirb >> 1, b = dirb & 1;
    const float* xcT = (dir ? xcT1 : xcT0) + (size_t)b * 1024 * LL;
    const float* W   = dir ? xp1 : xp0;     // (160,1024)
    float*       C   = (dir ? xd1 : xd0) + (size_t)b * LL * 160;
    int n0 = blockIdx.x * 64, t0 = blockIdx.y * 64;
    int tid = threadIdx.x;
    int tx = tid & 15, ty = tid >> 4;

    float acc[4][4] = {};

    for (int k0 = 0; k0 < 1024; k0 += 16) {
        {   // A: 16k x 64t from transposed source (coalesced along t)
            int kk = tid & 15, mq = tid >> 4;
            float4 v = make_float4(0.f, 0.f, 0.f, 0.f);
            if (t0 + mq * 4 + 3 < LL)
                v = *(const float4*)(xcT + (size_t)(k0 + kk) * LL + t0 + mq * 4);
            *(float4*)(As + kk * 68 + mq * 4) = v;
        }
        {   // W: 64n x 16k, transposed into Ws[k][n]
            int row = tid >> 2, q = tid & 3;
            float4 v = make_float4(0.f, 0.f, 0.f, 0.f);
            if (n0 + row < 160)
                v = *(const float4*)(W + (size_t)(n0 + row) * 1024 + k0 + q * 4);
            Ws[(q * 4 + 0) * 68 + row] = v.x;
            Ws[(q * 4 + 1) * 68 + row] = v.y;
            Ws[(q * 4 + 2) * 68 + row] = v.z;
            Ws[(q * 4 + 3) * 68 + row] = v.w;
        }
        __syncthreads();
        #pragma unroll
        for (int k = 0; k < 16; k++) {
            float4 a = *(const float4*)(As + k * 68 + ty * 4);
            float4 w = *(const float4*)(Ws + k * 68 + tx * 4);
            float av[4] = {a.x, a.y, a.z, a.w};
            float wv[4] = {w.x, w.y, w.z, w.w};
            #pragma unroll
            for (int i = 0; i < 4; i++)
                #pragma unroll
                for (int j = 0; j < 4; j++)
                    acc[i][j] = fmaf(av[i], wv[j], acc[i][j]);
        }
        __syncthreads();
    }

    #pragma unroll
    for (int i = 0; i < 4; i++) {
        int t = t0 + ty * 4 + i;
        if (t >= LL) continue;
        #pragma unroll
        for (int j = 0; j < 4; j++) {
            int n = n0 + tx * 4 + j;
            if (n < 160) C[(size_t)t * 160 + n] = acc[i][j];
        }
    }
}

// ---- dt GEMM (K=32) + softplus, output TRANSPOSED dtT [b][d][t] ------------
__global__ __launch_bounds__(256)
void gemm_dt_k(const float* __restrict__ xd0, const float* __restrict__ xd1,
               const float* __restrict__ w0, const float* __restrict__ w1,
               const float* __restrict__ bb0, const float* __restrict__ bb1,
               float* __restrict__ dtT0, float* __restrict__ dtT1)
{
    __shared__ float As[64 * 33];   // [m=t][k]
    __shared__ float Ws[32 * 68];   // [k][n]
    __shared__ float T[64 * 67];    // [n][m] for transposed store
    int dirb = blockIdx.z;
    int dir = dirb >> 1, b = dirb & 1;
    const float* xd = (dir ? xd1 : xd0) + (size_t)b * LL * 160;
    const float* W  = dir ? w1 : w0;        // (1024,32)
    const float* bi = dir ? bb1 : bb0;
    float*      dtT = (dir ? dtT1 : dtT0) + (size_t)b * 1024 * LL;
    int n0 = blockIdx.x * 64, t0 = blockIdx.y * 64;
    int tid = threadIdx.x;
    int tx = tid & 15, ty = tid >> 4;

    #pragma unroll
    for (int i = 0; i < 2; i++) {
        int j = tid + 256 * i;          // 0..511
        int row = j >> 3, q = j & 7;
        float4 v = make_float4(0.f, 0.f, 0.f, 0.f);
        if (t0 + row < LL)
            v = *(const float4*)(xd + (size_t)(t0 + row) * 160 + q * 4);
        As[row * 33 + q * 4 + 0] = v.x;
        As[row * 33 + q * 4 + 1] = v.y;
        As[row * 33 + q * 4 + 2] = v.z;
        As[row * 33 + q * 4 + 3] = v.w;
        float4 wv = *(const float4*)(W + (size_t)(n0 + row) * 32 + q * 4);
        Ws[(q * 4 + 0) * 68 + row] = wv.x;
        Ws[(q * 4 + 1) * 68 + row] = wv.y;
        Ws[(q * 4 + 2) * 68 + row] = wv.z;
        Ws[(q * 4 + 3) * 68 + row] = wv.w;
    }
    __syncthreads();

    float acc[4][4] = {};
    #pragma unroll 8
    for (int k = 0; k < 32; k++) {
        float4 w = *(const float4*)(Ws + k * 68 + tx * 4);
        float wv[4] = {w.x, w.y, w.z, w.w};
        float av[4];
        #pragma unroll
        for (int i = 0; i < 4; i++) av[i] = As[(ty * 4 + i) * 33 + k];
        #pragma unroll
        for (int i = 0; i < 4; i++)
            #pragma unroll
            for (int j = 0; j < 4; j++)
                acc[i][j] = fmaf(av[i], wv[j], acc[i][j]);
    }
    __syncthreads();

    #pragma unroll
    for (int i = 0; i < 4; i++) {
        #pragma unroll
        for (int j = 0; j < 4; j++) {
            int n = tx * 4 + j;
            float v = acc[i][j] + bi[n0 + n];
            v = (v > 20.f) ? v : log1pf(__expf(v));
            T[n * 67 + ty * 4 + i] = v;
        }
    }
    __syncthreads();

    int tl = tid & 63, ng = tid >> 6;
    #pragma unroll
    for (int i = 0; i < 16; i++) {
        int nl = ng * 16 + i;
        int t = t0 + tl;
        if (t < LL)
            dtT[(size_t)(n0 + nl) * LL + t] = T[nl * 67 + tl];
    }
}

// ------------------------------------------- wave-wide sum, VALU-only -------
template<int CTRL>
__device__ __forceinline__ float dpp_add(float v) {
    int iv = __builtin_bit_cast(int, v);
    int mv = __builtin_amdgcn_update_dpp(iv, iv, CTRL, 0xf, 0xf, false);
    return v + __builtin_bit_cast(float, mv);
}

__device__ __forceinline__ float wave_sum64(float p) {
    p = dpp_add<0x121>(p);   // row_ror:1
    p = dpp_add<0x122>(p);   // row_ror:2
    p = dpp_add<0x124>(p);   // row_ror:4
    p = dpp_add<0x128>(p);   // row_ror:8  -> each 16-lane row holds its sum
#if __has_builtin(__builtin_amdgcn_permlane16_swap)
    {
        unsigned a = __builtin_bit_cast(unsigned, p);
        auto r = __builtin_amdgcn_permlane16_swap(a, a, false, false);
        p = __builtin_bit_cast(float, (unsigned)r[0]) +
            __builtin_bit_cast(float, (unsigned)r[1]);
    }
#else
    p += __shfl_xor(p, 16, 64);
#endif
#if __has_builtin(__builtin_amdgcn_permlane32_swap)
    {
        unsigned a = __builtin_bit_cast(unsigned, p);
        auto r = __builtin_amdgcn_permlane32_swap(a, a, false, false);
        p = __builtin_bit_cast(float, (unsigned)r[0]) +
            __builtin_bit_cast(float, (unsigned)r[1]);
    }
#else
    p += __shfl_xor(p, 32, 64);
#endif
    return p;
}

__device__ __forceinline__ float bcast_lane(float v, int lane) {
    return __builtin_bit_cast(float,
        __builtin_amdgcn_readlane(__builtin_bit_cast(int, v), lane));
}

// ------------------------------------------------------------ selective scan
// wave = (dir,b,d); lane = state n. Inner loop: 2 imm-offset LDS reads +
// VALU-only reduce (DPP + permlane swaps). Writes y in place over dtT.
__global__ __launch_bounds__(256)
void scan_k(float* __restrict__ dtT0, float* __restrict__ dtT1,
            const float* __restrict__ ucT0, const float* __restrict__ ucT1,
            const float* __restrict__ xd0, const float* __restrict__ xd1,
            const float* __restrict__ Al0, const float* __restrict__ Al1,
            const float* __restrict__ Dc0, const float* __restrict__ Dc1)
{
    __shared__ float Bs[64 * 64];
    __shared__ float Cs[64 * 64];
    int dirb = blockIdx.y;
    int dir = dirb >> 1, b = dirb & 1;
    int wid = threadIdx.x >> 6, lane = threadIdx.x & 63;
    int d = blockIdx.x * 4 + wid;

    float*       dtT = (dir ? dtT1 : dtT0);
    const float* ucT = (dir ? ucT1 : ucT0);
    const float* xd  = (dir ? xd1 : xd0) + (size_t)b * LL * 160;
    const float* Al  = dir ? Al1 : Al0;
    const float* Dc  = dir ? Dc1 : Dc0;

    float a  = -__expf(Al[d * 64 + lane]) * 1.44269504f;
    float Dp = Dc[d];
    float h  = 0.f;
    size_t chan = ((size_t)(b * 1024 + d)) * LL;

    for (int t0 = 0; t0 < LL; t0 += 64) {
        int rem = min(64, LL - t0);
        __syncthreads();
        #pragma unroll
        for (int i = 0; i < 8; i++) {
            int j = threadIdx.x + 256 * i;      // 0..2047
            int row = j >> 5, q = j & 31;
            float4 v = make_float4(0.f, 0.f, 0.f, 0.f);
            if (row < rem)
                v = *(const float4*)(xd + (size_t)(t0 + row) * 160 + 32 + q * 4);
            if (q < 16) *(float4*)(Bs + row * 64 + (q & 15) * 4) = v;
            else        *(float4*)(Cs + row * 64 + (q & 15) * 4) = v;
        }
        float dta = 0.f, ua = 0.f;
        if (lane < rem) {
            dta = dtT[chan + t0 + lane];
            ua  = ucT[chan + t0 + lane];
        }
        __syncthreads();

        float yv = 0.f;
        #define SCAN_STEP(tt) {                                   \
            float dtv = bcast_lane(dta, (tt));                    \
            float u   = bcast_lane(ua,  (tt));                    \
            float Bn  = Bs[(tt) * 64 + lane];                     \
            float Cn  = Cs[(tt) * 64 + lane];                     \
            float dA  = exp2f(dtv * a);                           \
            h = fmaf(dA, h, dtv * u * Bn);                        \
            float p = wave_sum64(h * Cn);                         \
            yv = (lane == (tt)) ? p : yv;                         \
        }
        if (rem == 64) {
            #pragma unroll
            for (int tt = 0; tt < 64; tt++) SCAN_STEP(tt);
        } else {
            for (int tt = 0; tt < rem; tt++) SCAN_STEP(tt);
        }
        #undef SCAN_STEP

        if (lane < rem)
            dtT[chan + t0 + lane] = yv + ua * Dp;
    }
}

// ---------------- gate: xz_lo[row][d] = yT[d][t] * silu(z[row][1024+d]) -----
__global__ __launch_bounds__(256)
void gate_k(const float* __restrict__ yT0, const float* __restrict__ yT1,
            float* __restrict__ xz0, float* __restrict__ xz1)
{
    __shared__ float Ls[64 * 65];
    int dirb = blockIdx.z;
    int dir = dirb >> 1, b = dirb & 1;
    int d0 = blockIdx.x * 64, t0 = blockIdx.y * 64;
    int tid = threadIdx.x;
    const float* yT = (dir ? yT1 : yT0) + (size_t)b * 1024 * LL;
    float*       xz = (dir ? xz1 : xz0) + (size_t)b * LL * 2048;

    int tl = tid & 63, dg = tid >> 6;
    #pragma unroll
    for (int i = 0; i < 16; i++) {
        int dd = dg * 16 + i;
        int t = t0 + tl;
        float v = (t < LL) ? yT[(size_t)(d0 + dd) * LL + t] : 0.f;
        Ls[dd * 65 + tl] = v;
    }
    __syncthreads();
    int dcol = tid & 63, tg = tid >> 6;
    #pragma unroll
    for (int i = 0; i < 16; i++) {
        int t = t0 + tg * 16 + i;
        if (t >= LL) continue;
        float z = xz[(size_t)t * 2048 + 1024 + d0 + dcol];
        float y = Ls[dcol * 65 + tg * 16 + i];
        float s = z / (1.f + __expf(-z));
        xz[(size_t)t * 2048 + d0 + dcol] = y * s;
    }
}

// -------------------------------------------------------------------- launch
extern "C" void kernel_launch(void* const* d_in, const int* in_sizes, int n_in,
                              void* d_out, int out_size, void* d_ws, size_t ws_size,
                              hipStream_t stream) {
    const float* x = (const float*)d_in[0];
    const float* P[2][10];
    for (int dir = 0; dir < 2; dir++)
        for (int i = 0; i < 10; i++)
            P[dir][i] = (const float*)d_in[1 + dir * 10 + i];

    float* ws = (float*)d_ws;
    float* xn      = ws;                                   // 1,024,000 (xdbl aliases after gemm1)
    float* xdbl[2] = { ws, ws + 320000 };
    float* xz[2]   = { ws + 1024000, ws + 5120000 };       // 4,096,000 each
    float* xcT[2]  = { ws + 9216000, ws + 11264000 };      // 2,048,000 each
    float* dtT[2]  = { ws + 13312000, ws + 15360000 };     // 2,048,000 each (y in-place)
    float* out = (float*)d_out;

    rmsnorm_k<<<MROWS, 256, 0, stream>>>(x, xn);

    for (int dir = 0; dir < 2; dir++)
        gemm_k<0><<<dim3(32, 32), 256, 0, stream>>>(
            xn, DM, dir, P[dir][0], P[dir][1], xz[dir], 2048,
            nullptr, MROWS, 2048, DM);

    conv_silu_k<<<dim3(16, 16, 4), 256, 0, stream>>>(
        xz[0], xz[1], P[0][2], P[1][2], P[0][3], P[1][3], xcT[0], xcT[1]);

    gemm_xp_k<<<dim3(3, 16, 4), 256, 0, stream>>>(
        xcT[0], xcT[1], P[0][4], P[1][4], xdbl[0], xdbl[1]);

    gemm_dt_k<<<dim3(16, 16, 4), 256, 0, stream>>>(
        xdbl[0], xdbl[1], P[0][5], P[1][5], P[0][6], P[1][6], dtT[0], dtT[1]);

    scan_k<<<dim3(256, 4), 256, 0, stream>>>(
        dtT[0], dtT[1], xcT[0], xcT[1], xdbl[0], xdbl[1],
        P[0][7], P[1][7], P[0][8], P[1][8]);

    gate_k<<<dim3(16, 16, 4), 256, 0, stream>>>(
        dtT[0], dtT[1], xz[0], xz[1]);

    gemm_k<2><<<dim3(8, 32), 256, 0, stream>>>(
        xz[0], 2048, 0, nullptr, P[0][9], out, DM,
        x, MROWS, DM, DI);
    gemm_k<3><<<dim3(8, 32), 256, 0, stream>>>(
        xz[1], 2048, 0, nullptr, P[1][9], out, DM,
        nullptr, MROWS, DM, DI);
}

// Round 4
// 484.964 us; speedup vs baseline: 2.6365x; 1.3204x over previous
//
#include <hip/hip_runtime.h>
#include <hip/hip_bf16.h>
#include <math.h>

#define DM   512
#define DI   1024
#define NS   64
#define RDT  32
#define BB   2
#define LL   1000
#define MROWS (BB*LL)   // 2000

typedef __attribute__((ext_vector_type(8))) short bf16x8;
typedef __attribute__((ext_vector_type(4))) float f32x4;

// f32 -> bf16 RNE (finite inputs)
__device__ __forceinline__ unsigned short f2bf(float f) {
    unsigned u = __builtin_bit_cast(unsigned, f);
    u = (u + 0x7FFF + ((u >> 16) & 1)) >> 16;
    return (unsigned short)u;
}

// ------------------- rmsnorm -> per-dir bf16 (norm_w folded) ----------------
__global__ __launch_bounds__(256)
void rmsnorm_k(const float* __restrict__ x,
               const float* __restrict__ nw0, const float* __restrict__ nw1,
               unsigned short* __restrict__ xnb0, unsigned short* __restrict__ xnb1) {
    int row = blockIdx.x;
    int tid = threadIdx.x;
    const float* xr = x + (size_t)row * DM;
    float2 v = *(const float2*)(xr + tid * 2);
    float ss = v.x * v.x + v.y * v.y;
    #pragma unroll
    for (int off = 32; off; off >>= 1) ss += __shfl_xor(ss, off, 64);
    __shared__ float red[4];
    if ((tid & 63) == 0) red[tid >> 6] = ss;
    __syncthreads();
    float tot = red[0] + red[1] + red[2] + red[3];
    float scale = rsqrtf(tot / (float)DM + 1e-5f);
    float2 w0 = *(const float2*)(nw0 + tid * 2);
    float2 w1 = *(const float2*)(nw1 + tid * 2);
    short2 o0, o1;
    o0.x = (short)f2bf(v.x * scale * w0.x);
    o0.y = (short)f2bf(v.y * scale * w0.y);
    o1.x = (short)f2bf(v.x * scale * w1.x);
    o1.y = (short)f2bf(v.y * scale * w1.y);
    *(short2*)(xnb0 + (size_t)row * DM + tid * 2) = o0;
    *(short2*)(xnb1 + (size_t)row * DM + tid * 2) = o1;
}

// ------------------------------------------------ f32 -> bf16 convert ------
__global__ __launch_bounds__(256)
void cvt_k(const float* __restrict__ in, unsigned short* __restrict__ out, int n4) {
    int idx = blockIdx.x * 256 + threadIdx.x;
    if (idx >= n4) return;
    float4 v = *(const float4*)(in + (size_t)idx * 4);
    short4 o;
    o.x = (short)f2bf(v.x); o.y = (short)f2bf(v.y);
    o.z = (short)f2bf(v.z); o.w = (short)f2bf(v.w);
    *(short4*)(out + (size_t)idx * 4) = o;
}

// ------------- GEMM1 (in_proj) bf16 MFMA: xz[dir] = xn_dir @ W^T ------------
// A: xnb[dir] (2000,512) bf16 (dir b: rows time-flipped at load)
// W: wib[dir] (2048,512) bf16 row-major = B[k][n] with n=row
__global__ __launch_bounds__(256, 2)
void gemm1_mfma(const unsigned short* __restrict__ xnb0,
                const unsigned short* __restrict__ xnb1,
                const unsigned short* __restrict__ wib0,
                const unsigned short* __restrict__ wib1,
                float* __restrict__ xz0, float* __restrict__ xz1)
{
    __shared__ __align__(16) unsigned short As[128 * 40];
    __shared__ __align__(16) unsigned short Bs[128 * 40];
    int dir = blockIdx.z;
    const unsigned short* A = dir ? xnb1 : xnb0;
    const unsigned short* W = dir ? wib1 : wib0;
    float* C = dir ? xz1 : xz0;
    int n0 = blockIdx.x * 128, m0 = blockIdx.y * 128;
    int tid = threadIdx.x;
    int wv = tid >> 6, lane = tid & 63;
    int wr = wv >> 1, wc = wv & 1;      // wave quadrant (2x2 of 64x64)
    int fl = lane & 15, kg = lane >> 4;

    f32x4 acc[4][4];
    #pragma unroll
    for (int i = 0; i < 4; i++)
        #pragma unroll
        for (int j = 0; j < 4; j++) acc[i][j] = (f32x4){0.f, 0.f, 0.f, 0.f};

    int sr = tid >> 2, cg = tid & 3;
    for (int k0 = 0; k0 < 512; k0 += 32) {
        #pragma unroll
        for (int i = 0; i < 2; i++) {
            int row = sr + i * 64;
            int m = m0 + row;
            float4 av = make_float4(0.f, 0.f, 0.f, 0.f);
            if (m < MROWS) {
                int rs = m;
                if (dir) { int b = m / LL, t = m % LL; rs = b * LL + (LL - 1 - t); }
                av = *(const float4*)(A + (size_t)rs * 512 + k0 + cg * 8);
            }
            *(float4*)(&As[row * 40 + cg * 8]) = av;
            float4 wv4 = *(const float4*)(W + (size_t)(n0 + row) * 512 + k0 + cg * 8);
            *(float4*)(&Bs[row * 40 + cg * 8]) = wv4;
        }
        __syncthreads();
        bf16x8 af[4], bf[4];
        #pragma unroll
        for (int fr = 0; fr < 4; fr++)
            af[fr] = *(const bf16x8*)(&As[(wr * 64 + fr * 16 + fl) * 40 + kg * 8]);
        #pragma unroll
        for (int fc = 0; fc < 4; fc++)
            bf[fc] = *(const bf16x8*)(&Bs[(wc * 64 + fc * 16 + fl) * 40 + kg * 8]);
        #pragma unroll
        for (int fr = 0; fr < 4; fr++)
            #pragma unroll
            for (int fc = 0; fc < 4; fc++)
                acc[fr][fc] = __builtin_amdgcn_mfma_f32_16x16x32_bf16(
                    af[fr], bf[fc], acc[fr][fc], 0, 0, 0);
        __syncthreads();
    }
    #pragma unroll
    for (int fr = 0; fr < 4; fr++)
        #pragma unroll
        for (int fc = 0; fc < 4; fc++)
            #pragma unroll
            for (int j = 0; j < 4; j++) {
                int m = m0 + wr * 64 + fr * 16 + kg * 4 + j;
                if (m < MROWS) {
                    int n = n0 + wc * 64 + fc * 16 + fl;
                    C[(size_t)m * 2048 + n] = acc[fr][fc][j];
                }
            }
}

// -------- out_proj bf16 MFMA, split (dir,kslice) -> f32 partials ------------
// A: ygb[dir] (2000,1024); W: wob[dir] (512,1024); z = dir*2 + ks
__global__ __launch_bounds__(256, 2)
void gemm_out_mfma(const unsigned short* __restrict__ ygb0,
                   const unsigned short* __restrict__ ygb1,
                   const unsigned short* __restrict__ wob0,
                   const unsigned short* __restrict__ wob1,
                   float* __restrict__ partial)
{
    __shared__ __align__(16) unsigned short As[64 * 40];
    __shared__ __align__(16) unsigned short Bs[64 * 40];
    int z = blockIdx.z;
    int dir = z >> 1, ks = z & 1;
    const unsigned short* A = dir ? ygb1 : ygb0;
    const unsigned short* W = dir ? wob1 : wob0;
    float* P = partial + (size_t)z * MROWS * 512;
    int n0 = blockIdx.x * 64, m0 = blockIdx.y * 64;
    int kbase = ks * 512;
    int tid = threadIdx.x;
    int wv = tid >> 6, lane = tid & 63;
    int wr = wv >> 1, wc = wv & 1;      // 2x2 quadrants of 32x32
    int fl = lane & 15, kg = lane >> 4;

    f32x4 acc[2][2];
    #pragma unroll
    for (int i = 0; i < 2; i++)
        #pragma unroll
        for (int j = 0; j < 2; j++) acc[i][j] = (f32x4){0.f, 0.f, 0.f, 0.f};

    int sr = tid >> 2, cg = tid & 3;
    for (int k0 = 0; k0 < 512; k0 += 32) {
        int m = m0 + sr;
        float4 av = make_float4(0.f, 0.f, 0.f, 0.f);
        if (m < MROWS)
            av = *(const float4*)(A + (size_t)m * 1024 + kbase + k0 + cg * 8);
        *(float4*)(&As[sr * 40 + cg * 8]) = av;
        float4 wv4 = *(const float4*)(W + (size_t)(n0 + sr) * 1024 + kbase + k0 + cg * 8);
        *(float4*)(&Bs[sr * 40 + cg * 8]) = wv4;
        __syncthreads();
        bf16x8 af[2], bf[2];
        #pragma unroll
        for (int fr = 0; fr < 2; fr++)
            af[fr] = *(const bf16x8*)(&As[(wr * 32 + fr * 16 + fl) * 40 + kg * 8]);
        #pragma unroll
        for (int fc = 0; fc < 2; fc++)
            bf[fc] = *(const bf16x8*)(&Bs[(wc * 32 + fc * 16 + fl) * 40 + kg * 8]);
        #pragma unroll
        for (int fr = 0; fr < 2; fr++)
            #pragma unroll
            for (int fc = 0; fc < 2; fc++)
                acc[fr][fc] = __builtin_amdgcn_mfma_f32_16x16x32_bf16(
                    af[fr], bf[fc], acc[fr][fc], 0, 0, 0);
        __syncthreads();
    }
    #pragma unroll
    for (int fr = 0; fr < 2; fr++)
        #pragma unroll
        for (int fc = 0; fc < 2; fc++)
            #pragma unroll
            for (int j = 0; j < 4; j++) {
                int m = m0 + wr * 32 + fr * 16 + kg * 4 + j;
                if (m < MROWS) {
                    int n = n0 + wc * 32 + fc * 16 + fl;
                    P[(size_t)m * 512 + n] = acc[fr][fc][j];
                }
            }
}

// out[m] = 2x[m] + pf0[m] + pf1[m] + pb0[flip(m)] + pb1[flip(m)]
__global__ __launch_bounds__(256)
void reduce_out_k(const float* __restrict__ x, const float* __restrict__ partial,
                  float* __restrict__ out)
{
    int idx = blockIdx.x * 256 + threadIdx.x;   // 2000*128
    if (idx >= MROWS * 128) return;
    int m = idx >> 7, q = idx & 127;
    int b = m / LL, t = m % LL;
    int fm = b * LL + (LL - 1 - t);
    const float* p0 = partial;
    const float* p1 = partial + (size_t)MROWS * 512;
    const float* p2 = partial + (size_t)2 * MROWS * 512;
    const float* p3 = partial + (size_t)3 * MROWS * 512;
    float4 xv = *(const float4*)(x  + (size_t)m  * 512 + q * 4);
    float4 a  = *(const float4*)(p0 + (size_t)m  * 512 + q * 4);
    float4 bv = *(const float4*)(p1 + (size_t)m  * 512 + q * 4);
    float4 c  = *(const float4*)(p2 + (size_t)fm * 512 + q * 4);
    float4 d  = *(const float4*)(p3 + (size_t)fm * 512 + q * 4);
    float4 o;
    o.x = 2.f * xv.x + a.x + bv.x + c.x + d.x;
    o.y = 2.f * xv.y + a.y + bv.y + c.y + d.y;
    o.z = 2.f * xv.z + a.z + bv.z + c.z + d.z;
    o.w = 2.f * xv.w + a.w + bv.w + c.w + d.w;
    *(float4*)(out + (size_t)m * 512 + q * 4) = o;
}

// ------------------------- causal dwconv + silu -> TRANSPOSED xcT [b][d][t] --
__global__ __launch_bounds__(256)
void conv_silu_k(const float* __restrict__ xz0, const float* __restrict__ xz1,
                 const float* __restrict__ cw0, const float* __restrict__ cw1,
                 const float* __restrict__ cb0, const float* __restrict__ cb1,
                 float* __restrict__ xcT0, float* __restrict__ xcT1)
{
    __shared__ float Ls[64 * 65];
    int dirb = blockIdx.z;
    int dir = dirb >> 1, b = dirb & 1;
    int d0 = blockIdx.x * 64, t0 = blockIdx.y * 64;
    int tid = threadIdx.x;
    int dl = tid & 63, tg = tid >> 6;

    const float* in = (dir ? xz1 : xz0) + (size_t)b * LL * 2048;
    const float* cw = dir ? cw1 : cw0;
    const float* cb = dir ? cb1 : cb0;
    float*      xcT = dir ? xcT1 : xcT0;

    float4 w4 = ((const float4*)cw)[d0 + dl];
    float bias = cb[d0 + dl];

    int ts = t0 + tg * 16;
    float x3 = 0.f, x2 = 0.f, x1 = 0.f;
    if (ts - 3 >= 0 && ts - 3 < LL) x3 = in[(size_t)(ts - 3) * 2048 + d0 + dl];
    if (ts - 2 >= 0 && ts - 2 < LL) x2 = in[(size_t)(ts - 2) * 2048 + d0 + dl];
    if (ts - 1 >= 0 && ts - 1 < LL) x1 = in[(size_t)(ts - 1) * 2048 + d0 + dl];

    #pragma unroll
    for (int i = 0; i < 16; i++) {
        int t = ts + i;
        float x0v = (t < LL) ? in[(size_t)t * 2048 + d0 + dl] : 0.f;
        float a = bias + x3 * w4.x + x2 * w4.y + x1 * w4.z + x0v * w4.w;
        float s = a / (1.f + __expf(-a));
        Ls[dl * 65 + tg * 16 + i] = s;
        x3 = x2; x2 = x1; x1 = x0v;
    }
    __syncthreads();
    int tl = tid & 63, dg = tid >> 6;
    #pragma unroll
    for (int i = 0; i < 16; i++) {
        int dd = dg * 16 + i;
        int t = t0 + tl;
        if (t < LL)
            xcT[((size_t)(b * 1024) + d0 + dd) * LL + t] = Ls[dd * 65 + tl];
    }
}

// --------------------- x_proj GEMM: xdbl[b*L+t][160] = xcT^T @ x_proj^T -----
__global__ __launch_bounds__(256)
void gemm_xp_k(const float* __restrict__ xcT0, const float* __restrict__ xcT1,
               const float* __restrict__ xp0, const float* __restrict__ xp1,
               float* __restrict__ xd0, float* __restrict__ xd1)
{
    __shared__ float As[16 * 68];   // [k][m=t]
    __shared__ float Ws[16 * 68];   // [k][n]
    int dirb = blockIdx.z;
    int dir = dirb >> 1, b = dirb & 1;
    const float* xcT = (dir ? xcT1 : xcT0) + (size_t)b * 1024 * LL;
    const float* W   = dir ? xp1 : xp0;     // (160,1024)
    float*       C   = (dir ? xd1 : xd0) + (size_t)b * LL * 160;
    int n0 = blockIdx.x * 64, t0 = blockIdx.y * 64;
    int tid = threadIdx.x;
    int tx = tid & 15, ty = tid >> 4;

    float acc[4][4] = {};

    for (int k0 = 0; k0 < 1024; k0 += 16) {
        {
            int kk = tid & 15, mq = tid >> 4;
            float4 v = make_float4(0.f, 0.f, 0.f, 0.f);
            if (t0 + mq * 4 + 3 < LL)
                v = *(const float4*)(xcT + (size_t)(k0 + kk) * LL + t0 + mq * 4);
            *(float4*)(As + kk * 68 + mq * 4) = v;
        }
        {
            int row = tid >> 2, q = tid & 3;
            float4 v = make_float4(0.f, 0.f, 0.f, 0.f);
            if (n0 + row < 160)
                v = *(const float4*)(W + (size_t)(n0 + row) * 1024 + k0 + q * 4);
            Ws[(q * 4 + 0) * 68 + row] = v.x;
            Ws[(q * 4 + 1) * 68 + row] = v.y;
            Ws[(q * 4 + 2) * 68 + row] = v.z;
            Ws[(q * 4 + 3) * 68 + row] = v.w;
        }
        __syncthreads();
        #pragma unroll
        for (int k = 0; k < 16; k++) {
            float4 a = *(const float4*)(As + k * 68 + ty * 4);
            float4 w = *(const float4*)(Ws + k * 68 + tx * 4);
            float av[4] = {a.x, a.y, a.z, a.w};
            float wvv[4] = {w.x, w.y, w.z, w.w};
            #pragma unroll
            for (int i = 0; i < 4; i++)
                #pragma unroll
                for (int j = 0; j < 4; j++)
                    acc[i][j] = fmaf(av[i], wvv[j], acc[i][j]);
        }
        __syncthreads();
    }

    #pragma unroll
    for (int i = 0; i < 4; i++) {
        int t = t0 + ty * 4 + i;
        if (t >= LL) continue;
        #pragma unroll
        for (int j = 0; j < 4; j++) {
            int n = n0 + tx * 4 + j;
            if (n < 160) C[(size_t)t * 160 + n] = acc[i][j];
        }
    }
}

// ---- dt GEMM (K=32) + softplus, output TRANSPOSED dtT [b][d][t] ------------
__global__ __launch_bounds__(256)
void gemm_dt_k(const float* __restrict__ xd0, const float* __restrict__ xd1,
               const float* __restrict__ w0, const float* __restrict__ w1,
               const float* __restrict__ bb0, const float* __restrict__ bb1,
               float* __restrict__ dtT0, float* __restrict__ dtT1)
{
    __shared__ float As[64 * 33];   // [m=t][k]
    __shared__ float Ws[32 * 68];   // [k][n]
    __shared__ float T[64 * 67];    // [n][m] for transposed store
    int dirb = blockIdx.z;
    int dir = dirb >> 1, b = dirb & 1;
    const float* xd = (dir ? xd1 : xd0) + (size_t)b * LL * 160;
    const float* W  = dir ? w1 : w0;        // (1024,32)
    const float* bi = dir ? bb1 : bb0;
    float*      dtT = (dir ? dtT1 : dtT0) + (size_t)b * 1024 * LL;
    int n0 = blockIdx.x * 64, t0 = blockIdx.y * 64;
    int tid = threadIdx.x;
    int tx = tid & 15, ty = tid >> 4;

    #pragma unroll
    for (int i = 0; i < 2; i++) {
        int j = tid + 256 * i;
        int row = j >> 3, q = j & 7;
        float4 v = make_float4(0.f, 0.f, 0.f, 0.f);
        if (t0 + row < LL)
            v = *(const float4*)(xd + (size_t)(t0 + row) * 160 + q * 4);
        As[row * 33 + q * 4 + 0] = v.x;
        As[row * 33 + q * 4 + 1] = v.y;
        As[row * 33 + q * 4 + 2] = v.z;
        As[row * 33 + q * 4 + 3] = v.w;
        float4 wv = *(const float4*)(W + (size_t)(n0 + row) * 32 + q * 4);
        Ws[(q * 4 + 0) * 68 + row] = wv.x;
        Ws[(q * 4 + 1) * 68 + row] = wv.y;
        Ws[(q * 4 + 2) * 68 + row] = wv.z;
        Ws[(q * 4 + 3) * 68 + row] = wv.w;
    }
    __syncthreads();

    float acc[4][4] = {};
    #pragma unroll 8
    for (int k = 0; k < 32; k++) {
        float4 w = *(const float4*)(Ws + k * 68 + tx * 4);
        float wvv[4] = {w.x, w.y, w.z, w.w};
        float av[4];
        #pragma unroll
        for (int i = 0; i < 4; i++) av[i] = As[(ty * 4 + i) * 33 + k];
        #pragma unroll
        for (int i = 0; i < 4; i++)
            #pragma unroll
            for (int j = 0; j < 4; j++)
                acc[i][j] = fmaf(av[i], wvv[j], acc[i][j]);
    }
    __syncthreads();

    #pragma unroll
    for (int i = 0; i < 4; i++) {
        #pragma unroll
        for (int j = 0; j < 4; j++) {
            int n = tx * 4 + j;
            float v = acc[i][j] + bi[n0 + n];
            v = (v > 20.f) ? v : log1pf(__expf(v));
            T[n * 67 + ty * 4 + i] = v;
        }
    }
    __syncthreads();

    int tl = tid & 63, ng = tid >> 6;
    #pragma unroll
    for (int i = 0; i < 16; i++) {
        int nl = ng * 16 + i;
        int t = t0 + tl;
        if (t < LL)
            dtT[(size_t)(n0 + nl) * LL + t] = T[nl * 67 + tl];
    }
}

// ------------------------------------------- wave-wide sum, VALU-only -------
template<int CTRL>
__device__ __forceinline__ float dpp_add(float v) {
    int iv = __builtin_bit_cast(int, v);
    int mv = __builtin_amdgcn_update_dpp(iv, iv, CTRL, 0xf, 0xf, false);
    return v + __builtin_bit_cast(float, mv);
}

__device__ __forceinline__ float wave_sum64(float p) {
    p = dpp_add<0x121>(p);
    p = dpp_add<0x122>(p);
    p = dpp_add<0x124>(p);
    p = dpp_add<0x128>(p);
#if __has_builtin(__builtin_amdgcn_permlane16_swap)
    {
        unsigned a = __builtin_bit_cast(unsigned, p);
        auto r = __builtin_amdgcn_permlane16_swap(a, a, false, false);
        p = __builtin_bit_cast(float, (unsigned)r[0]) +
            __builtin_bit_cast(float, (unsigned)r[1]);
    }
#else
    p += __shfl_xor(p, 16, 64);
#endif
#if __has_builtin(__builtin_amdgcn_permlane32_swap)
    {
        unsigned a = __builtin_bit_cast(unsigned, p);
        auto r = __builtin_amdgcn_permlane32_swap(a, a, false, false);
        p = __builtin_bit_cast(float, (unsigned)r[0]) +
            __builtin_bit_cast(float, (unsigned)r[1]);
    }
#else
    p += __shfl_xor(p, 32, 64);
#endif
    return p;
}

__device__ __forceinline__ float bcast_lane(float v, int lane) {
    return __builtin_bit_cast(float,
        __builtin_amdgcn_readlane(__builtin_bit_cast(int, v), lane));
}

// ------------------------------------------------------------ selective scan
// wave = (dir,b,d); lane = state n. 8-step batches: broadcasts+exp up front,
// serial h-chain, then 8 INDEPENDENT reductions (ILP). y in place over dtT.
__global__ __launch_bounds__(256, 4)
void scan_k(float* __restrict__ dtT0, float* __restrict__ dtT1,
            const float* __restrict__ ucT0, const float* __restrict__ ucT1,
            const float* __restrict__ xd0, const float* __restrict__ xd1,
            const float* __restrict__ Al0, const float* __restrict__ Al1,
            const float* __restrict__ Dc0, const float* __restrict__ Dc1)
{
    __shared__ float Bsm[64 * 64];
    __shared__ float Csm[64 * 64];
    int dirb = blockIdx.y;
    int dir = dirb >> 1, b = dirb & 1;
    int wid = threadIdx.x >> 6, lane = threadIdx.x & 63;
    int d = blockIdx.x * 4 + wid;

    float*       dtT = (dir ? dtT1 : dtT0);
    const float* ucT = (dir ? ucT1 : ucT0);
    const float* xd  = (dir ? xd1 : xd0) + (size_t)b * LL * 160;
    const float* Al  = dir ? Al1 : Al0;
    const float* Dc  = dir ? Dc1 : Dc0;

    float a  = -__expf(Al[d * 64 + lane]) * 1.44269504f;
    float Dp = Dc[d];
    float h  = 0.f;
    size_t chan = ((size_t)(b * 1024 + d)) * LL;

    for (int t0 = 0; t0 < LL; t0 += 64) {
        int rem = min(64, LL - t0);
        __syncthreads();
        #pragma unroll
        for (int i = 0; i < 8; i++) {
            int j = threadIdx.x + 256 * i;
            int row = j >> 5, q = j & 31;
            float4 v = make_float4(0.f, 0.f, 0.f, 0.f);
            if (row < rem)
                v = *(const float4*)(xd + (size_t)(t0 + row) * 160 + 32 + q * 4);
            if (q < 16) *(float4*)(Bsm + row * 64 + (q & 15) * 4) = v;
            else        *(float4*)(Csm + row * 64 + (q & 15) * 4) = v;
        }
        float dta = 0.f, ua = 0.f;
        if (lane < rem) {
            dta = dtT[chan + t0 + lane];
            ua  = ucT[chan + t0 + lane];
        }
        __syncthreads();

        float yv = 0.f;
        int ngrp = rem >> 3;            // rem is 64 or 40 -> 8 or 5 groups
        for (int g = 0; g < ngrp; g++) {
            int base = g * 8;
            float dtv[8], wsc[8];
            #pragma unroll
            for (int i = 0; i < 8; i++) {
                dtv[i] = bcast_lane(dta, base + i);
                wsc[i] = dtv[i] * bcast_lane(ua, base + i);
            }
            float dAv[8];
            #pragma unroll
            for (int i = 0; i < 8; i++) dAv[i] = exp2f(dtv[i] * a);
            float Bn[8], Cn[8];
            #pragma unroll
            for (int i = 0; i < 8; i++) {
                Bn[i] = Bsm[(base + i) * 64 + lane];
                Cn[i] = Csm[(base + i) * 64 + lane];
            }
            float p[8];
            #pragma unroll
            for (int i = 0; i < 8; i++) {       // serial h-chain (short)
                h = fmaf(dAv[i], h, wsc[i] * Bn[i]);
                p[i] = h * Cn[i];
            }
            #pragma unroll
            for (int i = 0; i < 8; i++) p[i] = wave_sum64(p[i]);  // 8 indep chains
            #pragma unroll
            for (int i = 0; i < 8; i++)
                yv = (lane == base + i) ? p[i] : yv;
        }

        if (lane < rem)
            dtT[chan + t0 + lane] = yv + ua * Dp;
    }
}

// ---------------- gate: xz_lo[row][d] = yT[d][t] * silu(z[row][1024+d]) -----
__global__ __launch_bounds__(256)
void gate_k(const float* __restrict__ yT0, const float* __restrict__ yT1,
            float* __restrict__ xz0, float* __restrict__ xz1)
{
    __shared__ float Ls[64 * 65];
    int dirb = blockIdx.z;
    int dir = dirb >> 1, b = dirb & 1;
    int d0 = blockIdx.x * 64, t0 = blockIdx.y * 64;
    int tid = threadIdx.x;
    const float* yT = (dir ? yT1 : yT0) + (size_t)b * 1024 * LL;
    float*       xz = (dir ? xz1 : xz0) + (size_t)b * LL * 2048;

    int tl = tid & 63, dg = tid >> 6;
    #pragma unroll
    for (int i = 0; i < 16; i++) {
        int dd = dg * 16 + i;
        int t = t0 + tl;
        float v = (t < LL) ? yT[(size_t)(d0 + dd) * LL + t] : 0.f;
        Ls[dd * 65 + tl] = v;
    }
    __syncthreads();
    int dcol = tid & 63, tg = tid >> 6;
    #pragma unroll
    for (int i = 0; i < 16; i++) {
        int t = t0 + tg * 16 + i;
        if (t >= LL) continue;
        float z = xz[(size_t)t * 2048 + 1024 + d0 + dcol];
        float y = Ls[dcol * 65 + tg * 16 + i];
        float s = z / (1.f + __expf(-z));
        xz[(size_t)t * 2048 + d0 + dcol] = y * s;
    }
}

// ---------------- yg (xz lo half, strided) -> bf16 ygb [t][1024] ------------
__global__ __launch_bounds__(256)
void cvt_yg_k(const float* __restrict__ xz0, const float* __restrict__ xz1,
              unsigned short* __restrict__ y0, unsigned short* __restrict__ y1)
{
    int idx = blockIdx.x * 256 + threadIdx.x;   // 2000*256
    if (idx >= MROWS * 256) return;
    int dir = blockIdx.y;
    int t = idx >> 8, dq = idx & 255;
    const float* xz = dir ? xz1 : xz0;
    unsigned short* y = dir ? y1 : y0;
    float4 v = *(const float4*)(xz + (size_t)t * 2048 + dq * 4);
    short4 o;
    o.x = (short)f2bf(v.x); o.y = (short)f2bf(v.y);
    o.z = (short)f2bf(v.z); o.w = (short)f2bf(v.w);
    *(short4*)(y + (size_t)t * 1024 + dq * 4) = o;
}

// -------------------------------------------------------------------- launch
extern "C" void kernel_launch(void* const* d_in, const int* in_sizes, int n_in,
                              void* d_out, int out_size, void* d_ws, size_t ws_size,
                              hipStream_t stream) {
    const float* x = (const float*)d_in[0];
    const float* P[2][10];
    for (int dir = 0; dir < 2; dir++)
        for (int i = 0; i < 10; i++)
            P[dir][i] = (const float*)d_in[1 + dir * 10 + i];

    float* ws = (float*)d_ws;
    float* xz0   = ws;                    // 4,096,000
    float* xz1   = ws + 4096000;          // 4,096,000
    float* xcT0  = ws + 8192000;          // 2,048,000
    float* xcT1  = ws + 10240000;         // 2,048,000
    float* dtT0  = ws + 12288000;         // 2,048,000
    float* dtT1  = ws + 14336000;         // 2,048,000
    float* xdbl0 = ws + 16384000;         //   320,000
    float* xdbl1 = ws + 16704000;         //   320,000
    unsigned short* xnb0 = (unsigned short*)(ws + 17024000);  // 256,000 fl
    unsigned short* xnb1 = (unsigned short*)(ws + 17280000);  // 256,000 fl
    // aliases (lifetimes disjoint, stream-ordered):
    unsigned short* wib0 = (unsigned short*)dtT0;  // dead once gemm_dt writes
    unsigned short* wib1 = (unsigned short*)dtT1;
    unsigned short* ygb0 = (unsigned short*)xcT0;  // xcT dead after scan
    unsigned short* ygb1 = (unsigned short*)xcT1;
    unsigned short* wob0 = (unsigned short*)dtT0;  // dtT dead after gate
    unsigned short* wob1 = (unsigned short*)dtT1;
    float* partial = xz0;                          // xz dead after cvt_yg
    float* out = (float*)d_out;

    rmsnorm_k<<<MROWS, 256, 0, stream>>>(x, P[0][0], P[1][0], xnb0, xnb1);

    cvt_k<<<1024, 256, 0, stream>>>(P[0][1], wib0, 262144);
    cvt_k<<<1024, 256, 0, stream>>>(P[1][1], wib1, 262144);

    gemm1_mfma<<<dim3(16, 16, 2), 256, 0, stream>>>(
        xnb0, xnb1, wib0, wib1, xz0, xz1);

    conv_silu_k<<<dim3(16, 16, 4), 256, 0, stream>>>(
        xz0, xz1, P[0][2], P[1][2], P[0][3], P[1][3], xcT0, xcT1);

    gemm_xp_k<<<dim3(3, 16, 4), 256, 0, stream>>>(
        xcT0, xcT1, P[0][4], P[1][4], xdbl0, xdbl1);

    gemm_dt_k<<<dim3(16, 16, 4), 256, 0, stream>>>(
        xdbl0, xdbl1, P[0][5], P[1][5], P[0][6], P[1][6], dtT0, dtT1);

    scan_k<<<dim3(256, 4), 256, 0, stream>>>(
        dtT0, dtT1, xcT0, xcT1, xdbl0, xdbl1,
        P[0][7], P[1][7], P[0][8], P[1][8]);

    gate_k<<<dim3(16, 16, 4), 256, 0, stream>>>(
        dtT0, dtT1, xz0, xz1);

    cvt_yg_k<<<dim3(2000, 2), 256, 0, stream>>>(xz0, xz1, ygb0, ygb1);

    cvt_k<<<512, 256, 0, stream>>>(P[0][9], wob0, 131072);
    cvt_k<<<512, 256, 0, stream>>>(P[1][9], wob1, 131072);

    gemm_out_mfma<<<dim3(8, 32, 4), 256, 0, stream>>>(
        ygb0, ygb1, wob0, wob1, partial);

    reduce_out_k<<<1000, 256, 0, stream>>>(x, partial, out);
}

// Round 5
// 394.020 us; speedup vs baseline: 3.2450x; 1.2308x over previous
//
#include <hip/hip_runtime.h>
#include <hip/hip_bf16.h>
#include <math.h>

#define DM   512
#define DI   1024
#define NS   64
#define RDT  32
#define BB   2
#define LL   1000
#define MROWS (BB*LL)   // 2000

typedef __attribute__((ext_vector_type(8))) short bf16x8;
typedef __attribute__((ext_vector_type(4))) float f32x4;

// f32 -> bf16 RNE (finite inputs)
__device__ __forceinline__ unsigned short f2bf(float f) {
    unsigned u = __builtin_bit_cast(unsigned, f);
    u = (u + 0x7FFF + ((u >> 16) & 1)) >> 16;
    return (unsigned short)u;
}

__device__ __forceinline__ float bcast_lane(float v, int lane) {
    return __builtin_bit_cast(float,
        __builtin_amdgcn_readlane(__builtin_bit_cast(int, v), lane));
}

// ------------------- rmsnorm -> per-dir bf16 (norm_w folded) ----------------
__global__ __launch_bounds__(256)
void rmsnorm_k(const float* __restrict__ x,
               const float* __restrict__ nw0, const float* __restrict__ nw1,
               unsigned short* __restrict__ xnb0, unsigned short* __restrict__ xnb1) {
    int row = blockIdx.x;
    int tid = threadIdx.x;
    const float* xr = x + (size_t)row * DM;
    float2 v = *(const float2*)(xr + tid * 2);
    float ss = v.x * v.x + v.y * v.y;
    #pragma unroll
    for (int off = 32; off; off >>= 1) ss += __shfl_xor(ss, off, 64);
    __shared__ float red[4];
    if ((tid & 63) == 0) red[tid >> 6] = ss;
    __syncthreads();
    float tot = red[0] + red[1] + red[2] + red[3];
    float scale = rsqrtf(tot / (float)DM + 1e-5f);
    float2 w0 = *(const float2*)(nw0 + tid * 2);
    float2 w1 = *(const float2*)(nw1 + tid * 2);
    short2 o0, o1;
    o0.x = (short)f2bf(v.x * scale * w0.x);
    o0.y = (short)f2bf(v.y * scale * w0.y);
    o1.x = (short)f2bf(v.x * scale * w1.x);
    o1.y = (short)f2bf(v.y * scale * w1.y);
    *(short2*)(xnb0 + (size_t)row * DM + tid * 2) = o0;
    *(short2*)(xnb1 + (size_t)row * DM + tid * 2) = o1;
}

// ------------------------------------------------ f32 -> bf16 convert ------
__global__ __launch_bounds__(256)
void cvt_k(const float* __restrict__ in, unsigned short* __restrict__ out, int n4) {
    int idx = blockIdx.x * 256 + threadIdx.x;
    if (idx >= n4) return;
    float4 v = *(const float4*)(in + (size_t)idx * 4);
    short4 o;
    o.x = (short)f2bf(v.x); o.y = (short)f2bf(v.y);
    o.z = (short)f2bf(v.z); o.w = (short)f2bf(v.w);
    *(short4*)(out + (size_t)idx * 4) = o;
}

// ------------- GEMM1 (in_proj) bf16 MFMA: xz[dir] = xn_dir @ W^T ------------
__global__ __launch_bounds__(256, 2)
void gemm1_mfma(const unsigned short* __restrict__ xnb0,
                const unsigned short* __restrict__ xnb1,
                const unsigned short* __restrict__ wib0,
                const unsigned short* __restrict__ wib1,
                float* __restrict__ xz0, float* __restrict__ xz1)
{
    __shared__ __align__(16) unsigned short As[128 * 40];
    __shared__ __align__(16) unsigned short Bs[128 * 40];
    int dir = blockIdx.z;
    const unsigned short* A = dir ? xnb1 : xnb0;
    const unsigned short* W = dir ? wib1 : wib0;
    float* C = dir ? xz1 : xz0;
    int n0 = blockIdx.x * 128, m0 = blockIdx.y * 128;
    int tid = threadIdx.x;
    int wv = tid >> 6, lane = tid & 63;
    int wr = wv >> 1, wc = wv & 1;
    int fl = lane & 15, kg = lane >> 4;

    f32x4 acc[4][4];
    #pragma unroll
    for (int i = 0; i < 4; i++)
        #pragma unroll
        for (int j = 0; j < 4; j++) acc[i][j] = (f32x4){0.f, 0.f, 0.f, 0.f};

    int sr = tid >> 2, cg = tid & 3;
    for (int k0 = 0; k0 < 512; k0 += 32) {
        #pragma unroll
        for (int i = 0; i < 2; i++) {
            int row = sr + i * 64;
            int m = m0 + row;
            float4 av = make_float4(0.f, 0.f, 0.f, 0.f);
            if (m < MROWS) {
                int rs = m;
                if (dir) { int b = m / LL, t = m % LL; rs = b * LL + (LL - 1 - t); }
                av = *(const float4*)(A + (size_t)rs * 512 + k0 + cg * 8);
            }
            *(float4*)(&As[row * 40 + cg * 8]) = av;
            float4 wv4 = *(const float4*)(W + (size_t)(n0 + row) * 512 + k0 + cg * 8);
            *(float4*)(&Bs[row * 40 + cg * 8]) = wv4;
        }
        __syncthreads();
        bf16x8 af[4], bf[4];
        #pragma unroll
        for (int fr = 0; fr < 4; fr++)
            af[fr] = *(const bf16x8*)(&As[(wr * 64 + fr * 16 + fl) * 40 + kg * 8]);
        #pragma unroll
        for (int fc = 0; fc < 4; fc++)
            bf[fc] = *(const bf16x8*)(&Bs[(wc * 64 + fc * 16 + fl) * 40 + kg * 8]);
        #pragma unroll
        for (int fr = 0; fr < 4; fr++)
            #pragma unroll
            for (int fc = 0; fc < 4; fc++)
                acc[fr][fc] = __builtin_amdgcn_mfma_f32_16x16x32_bf16(
                    af[fr], bf[fc], acc[fr][fc], 0, 0, 0);
        __syncthreads();
    }
    #pragma unroll
    for (int fr = 0; fr < 4; fr++)
        #pragma unroll
        for (int fc = 0; fc < 4; fc++)
            #pragma unroll
            for (int j = 0; j < 4; j++) {
                int m = m0 + wr * 64 + fr * 16 + kg * 4 + j;
                if (m < MROWS) {
                    int n = n0 + wc * 64 + fc * 16 + fl;
                    C[(size_t)m * 2048 + n] = acc[fr][fc][j];
                }
            }
}

// -------- out_proj bf16 MFMA, split (dir,kslice) -> f32 partials ------------
__global__ __launch_bounds__(256, 2)
void gemm_out_mfma(const unsigned short* __restrict__ ygb0,
                   const unsigned short* __restrict__ ygb1,
                   const unsigned short* __restrict__ wob0,
                   const unsigned short* __restrict__ wob1,
                   float* __restrict__ partial)
{
    __shared__ __align__(16) unsigned short As[64 * 40];
    __shared__ __align__(16) unsigned short Bs[64 * 40];
    int z = blockIdx.z;
    int dir = z >> 1, ks = z & 1;
    const unsigned short* A = dir ? ygb1 : ygb0;
    const unsigned short* W = dir ? wob1 : wob0;
    float* P = partial + (size_t)z * MROWS * 512;
    int n0 = blockIdx.x * 64, m0 = blockIdx.y * 64;
    int kbase = ks * 512;
    int tid = threadIdx.x;
    int wv = tid >> 6, lane = tid & 63;
    int wr = wv >> 1, wc = wv & 1;
    int fl = lane & 15, kg = lane >> 4;

    f32x4 acc[2][2];
    #pragma unroll
    for (int i = 0; i < 2; i++)
        #pragma unroll
        for (int j = 0; j < 2; j++) acc[i][j] = (f32x4){0.f, 0.f, 0.f, 0.f};

    int sr = tid >> 2, cg = tid & 3;
    for (int k0 = 0; k0 < 512; k0 += 32) {
        int m = m0 + sr;
        float4 av = make_float4(0.f, 0.f, 0.f, 0.f);
        if (m < MROWS)
            av = *(const float4*)(A + (size_t)m * 1024 + kbase + k0 + cg * 8);
        *(float4*)(&As[sr * 40 + cg * 8]) = av;
        float4 wv4 = *(const float4*)(W + (size_t)(n0 + sr) * 1024 + kbase + k0 + cg * 8);
        *(float4*)(&Bs[sr * 40 + cg * 8]) = wv4;
        __syncthreads();
        bf16x8 af[2], bf[2];
        #pragma unroll
        for (int fr = 0; fr < 2; fr++)
            af[fr] = *(const bf16x8*)(&As[(wr * 32 + fr * 16 + fl) * 40 + kg * 8]);
        #pragma unroll
        for (int fc = 0; fc < 2; fc++)
            bf[fc] = *(const bf16x8*)(&Bs[(wc * 32 + fc * 16 + fl) * 40 + kg * 8]);
        #pragma unroll
        for (int fr = 0; fr < 2; fr++)
            #pragma unroll
            for (int fc = 0; fc < 2; fc++)
                acc[fr][fc] = __builtin_amdgcn_mfma_f32_16x16x32_bf16(
                    af[fr], bf[fc], acc[fr][fc], 0, 0, 0);
        __syncthreads();
    }
    #pragma unroll
    for (int fr = 0; fr < 2; fr++)
        #pragma unroll
        for (int fc = 0; fc < 2; fc++)
            #pragma unroll
            for (int j = 0; j < 4; j++) {
                int m = m0 + wr * 32 + fr * 16 + kg * 4 + j;
                if (m < MROWS) {
                    int n = n0 + wc * 32 + fc * 16 + fl;
                    P[(size_t)m * 512 + n] = acc[fr][fc][j];
                }
            }
}

// out[m] = 2x[m] + pf0[m] + pf1[m] + pb0[flip(m)] + pb1[flip(m)]
__global__ __launch_bounds__(256)
void reduce_out_k(const float* __restrict__ x, const float* __restrict__ partial,
                  float* __restrict__ out)
{
    int idx = blockIdx.x * 256 + threadIdx.x;
    if (idx >= MROWS * 128) return;
    int m = idx >> 7, q = idx & 127;
    int b = m / LL, t = m % LL;
    int fm = b * LL + (LL - 1 - t);
    const float* p0 = partial;
    const float* p1 = partial + (size_t)MROWS * 512;
    const float* p2 = partial + (size_t)2 * MROWS * 512;
    const float* p3 = partial + (size_t)3 * MROWS * 512;
    float4 xv = *(const float4*)(x  + (size_t)m  * 512 + q * 4);
    float4 a  = *(const float4*)(p0 + (size_t)m  * 512 + q * 4);
    float4 bv = *(const float4*)(p1 + (size_t)m  * 512 + q * 4);
    float4 c  = *(const float4*)(p2 + (size_t)fm * 512 + q * 4);
    float4 d  = *(const float4*)(p3 + (size_t)fm * 512 + q * 4);
    float4 o;
    o.x = 2.f * xv.x + a.x + bv.x + c.x + d.x;
    o.y = 2.f * xv.y + a.y + bv.y + c.y + d.y;
    o.z = 2.f * xv.z + a.z + bv.z + c.z + d.z;
    o.w = 2.f * xv.w + a.w + bv.w + c.w + d.w;
    *(float4*)(out + (size_t)m * 512 + q * 4) = o;
}

// ------------------------- causal dwconv + silu -> TRANSPOSED xcT [b][d][t] --
__global__ __launch_bounds__(256)
void conv_silu_k(const float* __restrict__ xz0, const float* __restrict__ xz1,
                 const float* __restrict__ cw0, const float* __restrict__ cw1,
                 const float* __restrict__ cb0, const float* __restrict__ cb1,
                 float* __restrict__ xcT0, float* __restrict__ xcT1)
{
    __shared__ float Ls[64 * 65];
    int dirb = blockIdx.z;
    int dir = dirb >> 1, b = dirb & 1;
    int d0 = blockIdx.x * 64, t0 = blockIdx.y * 64;
    int tid = threadIdx.x;
    int dl = tid & 63, tg = tid >> 6;

    const float* in = (dir ? xz1 : xz0) + (size_t)b * LL * 2048;
    const float* cw = dir ? cw1 : cw0;
    const float* cb = dir ? cb1 : cb0;
    float*      xcT = dir ? xcT1 : xcT0;

    float4 w4 = ((const float4*)cw)[d0 + dl];
    float bias = cb[d0 + dl];

    int ts = t0 + tg * 16;
    float x3 = 0.f, x2 = 0.f, x1 = 0.f;
    if (ts - 3 >= 0 && ts - 3 < LL) x3 = in[(size_t)(ts - 3) * 2048 + d0 + dl];
    if (ts - 2 >= 0 && ts - 2 < LL) x2 = in[(size_t)(ts - 2) * 2048 + d0 + dl];
    if (ts - 1 >= 0 && ts - 1 < LL) x1 = in[(size_t)(ts - 1) * 2048 + d0 + dl];

    #pragma unroll
    for (int i = 0; i < 16; i++) {
        int t = ts + i;
        float x0v = (t < LL) ? in[(size_t)t * 2048 + d0 + dl] : 0.f;
        float a = bias + x3 * w4.x + x2 * w4.y + x1 * w4.z + x0v * w4.w;
        float s = a / (1.f + __expf(-a));
        Ls[dl * 65 + tg * 16 + i] = s;
        x3 = x2; x2 = x1; x1 = x0v;
    }
    __syncthreads();
    int tl = tid & 63, dg = tid >> 6;
    #pragma unroll
    for (int i = 0; i < 16; i++) {
        int dd = dg * 16 + i;
        int t = t0 + tl;
        if (t < LL)
            xcT[((size_t)(b * 1024) + d0 + dd) * LL + t] = Ls[dd * 65 + tl];
    }
}

// --------------------- x_proj GEMM + BCT transposed epilogue ----------------
// xdbl[t][160] row-major (dt cols) AND bct[dirb][n-32][t] for cols 32..159
__global__ __launch_bounds__(256)
void gemm_xp_k(const float* __restrict__ xcT0, const float* __restrict__ xcT1,
               const float* __restrict__ xp0, const float* __restrict__ xp1,
               float* __restrict__ xd0, float* __restrict__ xd1,
               float* __restrict__ bct)
{
    __shared__ float As[16 * 68];   // [k][m=t]
    __shared__ float Ws[16 * 68];   // [k][n]
    __shared__ float T[64 * 67];    // [n][m] transposed staging
    int dirb = blockIdx.z;
    int dir = dirb >> 1, b = dirb & 1;
    const float* xcT = (dir ? xcT1 : xcT0) + (size_t)b * 1024 * LL;
    const float* W   = dir ? xp1 : xp0;     // (160,1024)
    float*       C   = (dir ? xd1 : xd0) + (size_t)b * LL * 160;
    int n0 = blockIdx.x * 64, t0 = blockIdx.y * 64;
    int tid = threadIdx.x;
    int tx = tid & 15, ty = tid >> 4;

    float acc[4][4] = {};

    for (int k0 = 0; k0 < 1024; k0 += 16) {
        {
            int kk = tid & 15, mq = tid >> 4;
            float4 v = make_float4(0.f, 0.f, 0.f, 0.f);
            if (t0 + mq * 4 + 3 < LL)
                v = *(const float4*)(xcT + (size_t)(k0 + kk) * LL + t0 + mq * 4);
            *(float4*)(As + kk * 68 + mq * 4) = v;
        }
        {
            int row = tid >> 2, q = tid & 3;
            float4 v = make_float4(0.f, 0.f, 0.f, 0.f);
            if (n0 + row < 160)
                v = *(const float4*)(W + (size_t)(n0 + row) * 1024 + k0 + q * 4);
            Ws[(q * 4 + 0) * 68 + row] = v.x;
            Ws[(q * 4 + 1) * 68 + row] = v.y;
            Ws[(q * 4 + 2) * 68 + row] = v.z;
            Ws[(q * 4 + 3) * 68 + row] = v.w;
        }
        __syncthreads();
        #pragma unroll
        for (int k = 0; k < 16; k++) {
            float4 a = *(const float4*)(As + k * 68 + ty * 4);
            float4 w = *(const float4*)(Ws + k * 68 + tx * 4);
            float av[4] = {a.x, a.y, a.z, a.w};
            float wvv[4] = {w.x, w.y, w.z, w.w};
            #pragma unroll
            for (int i = 0; i < 4; i++)
                #pragma unroll
                for (int j = 0; j < 4; j++)
                    acc[i][j] = fmaf(av[i], wvv[j], acc[i][j]);
        }
        __syncthreads();
    }

    // row-major store (dt GEMM consumes cols 0..31; only n0==0 block has them)
    if (n0 == 0) {
        #pragma unroll
        for (int i = 0; i < 4; i++) {
            int t = t0 + ty * 4 + i;
            if (t >= LL) continue;
            #pragma unroll
            for (int j = 0; j < 4; j++) {
                int n = tx * 4 + j;
                C[(size_t)t * 160 + n] = acc[i][j];
            }
        }
    }

    // transposed store of B/C columns into bct[dirb][n-32][t]
    #pragma unroll
    for (int i = 0; i < 4; i++)
        #pragma unroll
        for (int j = 0; j < 4; j++)
            T[(tx * 4 + j) * 67 + ty * 4 + i] = acc[i][j];
    __syncthreads();
    int tl = tid & 63, ng = tid >> 6;
    #pragma unroll
    for (int i = 0; i < 16; i++) {
        int nl = ng * 16 + i;
        int n = n0 + nl;
        int t = t0 + tl;
        if (n >= 32 && n < 160 && t < LL)
            bct[((size_t)dirb * 128 + (n - 32)) * LL + t] = T[nl * 67 + tl];
    }
}

// ---- dt GEMM (K=32) + softplus, output TRANSPOSED dtT [b][d][t] ------------
__global__ __launch_bounds__(256)
void gemm_dt_k(const float* __restrict__ xd0, const float* __restrict__ xd1,
               const float* __restrict__ w0, const float* __restrict__ w1,
               const float* __restrict__ bb0, const float* __restrict__ bb1,
               float* __restrict__ dtT0, float* __restrict__ dtT1)
{
    __shared__ float As[64 * 33];
    __shared__ float Ws[32 * 68];
    __shared__ float T[64 * 67];
    int dirb = blockIdx.z;
    int dir = dirb >> 1, b = dirb & 1;
    const float* xd = (dir ? xd1 : xd0) + (size_t)b * LL * 160;
    const float* W  = dir ? w1 : w0;
    const float* bi = dir ? bb1 : bb0;
    float*      dtT = (dir ? dtT1 : dtT0) + (size_t)b * 1024 * LL;
    int n0 = blockIdx.x * 64, t0 = blockIdx.y * 64;
    int tid = threadIdx.x;
    int tx = tid & 15, ty = tid >> 4;

    #pragma unroll
    for (int i = 0; i < 2; i++) {
        int j = tid + 256 * i;
        int row = j >> 3, q = j & 7;
        float4 v = make_float4(0.f, 0.f, 0.f, 0.f);
        if (t0 + row < LL)
            v = *(const float4*)(xd + (size_t)(t0 + row) * 160 + q * 4);
        As[row * 33 + q * 4 + 0] = v.x;
        As[row * 33 + q * 4 + 1] = v.y;
        As[row * 33 + q * 4 + 2] = v.z;
        As[row * 33 + q * 4 + 3] = v.w;
        float4 wv = *(const float4*)(W + (size_t)(n0 + row) * 32 + q * 4);
        Ws[(q * 4 + 0) * 68 + row] = wv.x;
        Ws[(q * 4 + 1) * 68 + row] = wv.y;
        Ws[(q * 4 + 2) * 68 + row] = wv.z;
        Ws[(q * 4 + 3) * 68 + row] = wv.w;
    }
    __syncthreads();

    float acc[4][4] = {};
    #pragma unroll 8
    for (int k = 0; k < 32; k++) {
        float4 w = *(const float4*)(Ws + k * 68 + tx * 4);
        float wvv[4] = {w.x, w.y, w.z, w.w};
        float av[4];
        #pragma unroll
        for (int i = 0; i < 4; i++) av[i] = As[(ty * 4 + i) * 33 + k];
        #pragma unroll
        for (int i = 0; i < 4; i++)
            #pragma unroll
            for (int j = 0; j < 4; j++)
                acc[i][j] = fmaf(av[i], wvv[j], acc[i][j]);
    }
    __syncthreads();

    #pragma unroll
    for (int i = 0; i < 4; i++) {
        #pragma unroll
        for (int j = 0; j < 4; j++) {
            int n = tx * 4 + j;
            float v = acc[i][j] + bi[n0 + n];
            v = (v > 20.f) ? v : log1pf(__expf(v));
            T[n * 67 + ty * 4 + i] = v;
        }
    }
    __syncthreads();

    int tl = tid & 63, ng = tid >> 6;
    #pragma unroll
    for (int i = 0; i < 16; i++) {
        int nl = ng * 16 + i;
        int t = t0 + tl;
        if (t < LL)
            dtT[(size_t)(n0 + nl) * LL + t] = T[nl * 67 + tl];
    }
}

// ------------------------------------------------------------ selective scan
// wave = (dir,b,d); lane = state n. No barriers, no per-step cross-lane ops:
// p values go to a per-wave LDS tile; every 32 steps a transpose-sum + one
// permlane32_swap produces 32 y values. B/C stream from global (L1-resident).
__global__ __launch_bounds__(256, 4)
void scan_k(float* __restrict__ dtT0, float* __restrict__ dtT1,
            const float* __restrict__ ucT0, const float* __restrict__ ucT1,
            const float* __restrict__ bct,
            const float* __restrict__ Al0, const float* __restrict__ Al1,
            const float* __restrict__ Dc0, const float* __restrict__ Dc1)
{
    __shared__ float P[4 * 32 * 66];
    int dirb = blockIdx.y;
    int dir = dirb >> 1, b = dirb & 1;
    int wid = threadIdx.x >> 6, lane = threadIdx.x & 63;
    int d = blockIdx.x * 4 + wid;
    float* Pw = P + wid * (32 * 66);

    float*       dtT = (dir ? dtT1 : dtT0);
    const float* ucT = (dir ? ucT1 : ucT0);
    const float* Al  = dir ? Al1 : Al0;
    const float* Dc  = dir ? Dc1 : Dc0;

    float a    = -__expf(Al[d * 64 + lane]) * 1.44269504f;
    float Dp64 = Dc[d] * (1.f / 64.f);
    float h    = 0.f;
    size_t chan = ((size_t)(b * 1024 + d)) * LL;
    const float* Brow = bct + ((size_t)dirb * 128 + lane) * LL;
    const float* Crow = Brow + (size_t)64 * LL;

    int tl = lane & 31, hh = lane >> 5;
    const float* Prow = Pw + tl * 66 + hh * 32;

    for (int t0 = 0; t0 < LL; t0 += 64) {
        int rem = min(64, LL - t0);
        float dta = 0.f, ua = 0.f;
        if (lane < rem) {
            dta = dtT[chan + t0 + lane];
            ua  = ucT[chan + t0 + lane];
        }

        for (int half = 0; half < 2; half++) {
            int hbase = t0 + half * 32;
            int hrem = rem - half * 32;
            if (hrem > 32) hrem = 32;
            if (hrem <= 0) continue;
            int ng = hrem >> 3;             // 4 or 1

            // prologue: load group 0
            float4 nB0 = *(const float4*)(Brow + hbase);
            float4 nB1 = *(const float4*)(Brow + hbase + 4);
            float4 nC0 = *(const float4*)(Crow + hbase);
            float4 nC1 = *(const float4*)(Crow + hbase + 4);

            #pragma unroll
            for (int g = 0; g < 4; g++) {
                if (g >= ng) break;
                float4 B0 = nB0, B1 = nB1, C0 = nC0, C1 = nC1;
                if (g + 1 < ng) {           // prefetch next group
                    nB0 = *(const float4*)(Brow + hbase + g * 8 + 8);
                    nB1 = *(const float4*)(Brow + hbase + g * 8 + 12);
                    nC0 = *(const float4*)(Crow + hbase + g * 8 + 8);
                    nC1 = *(const float4*)(Crow + hbase + g * 8 + 12);
                }
                int lb = half * 32 + g * 8;
                #pragma unroll
                for (int i = 0; i < 8; i++) {
                    float dtv = bcast_lane(dta, lb + i);
                    float u   = bcast_lane(ua,  lb + i);
                    float dA  = exp2f(dtv * a);
                    float Bn  = (i < 4) ? B0[i] : B1[i - 4];
                    float Cn  = (i < 4) ? C0[i] : C1[i - 4];
                    h = fmaf(dA, h, dtv * u * Bn);
                    Pw[(g * 8 + i) * 66 + lane] = fmaf(u, Dp64, h * Cn);
                }
            }

            // transpose-sum: lane (tl,hh) sums its half-row of P
            float s = 0.f;
            #pragma unroll
            for (int j = 0; j < 16; j++) {
                float2 v = *(const float2*)(Prow + j * 2);
                s += v.x + v.y;
            }
            // combine wave halves
            unsigned aa = __builtin_bit_cast(unsigned, s);
            auto r = __builtin_amdgcn_permlane32_swap(aa, aa, false, false);
            float tot = __builtin_bit_cast(float, (unsigned)r[0]) +
                        __builtin_bit_cast(float, (unsigned)r[1]);
            if (lane < hrem)
                dtT[chan + hbase + lane] = tot;
        }
    }
}

// ---------------- gate: xz_lo[row][d] = yT[d][t] * silu(z[row][1024+d]) -----
__global__ __launch_bounds__(256)
void gate_k(const float* __restrict__ yT0, const float* __restrict__ yT1,
            float* __restrict__ xz0, float* __restrict__ xz1)
{
    __shared__ float Ls[64 * 65];
    int dirb = blockIdx.z;
    int dir = dirb >> 1, b = dirb & 1;
    int d0 = blockIdx.x * 64, t0 = blockIdx.y * 64;
    int tid = threadIdx.x;
    const float* yT = (dir ? yT1 : yT0) + (size_t)b * 1024 * LL;
    float*       xz = (dir ? xz1 : xz0) + (size_t)b * LL * 2048;

    int tl = tid & 63, dg = tid >> 6;
    #pragma unroll
    for (int i = 0; i < 16; i++) {
        int dd = dg * 16 + i;
        int t = t0 + tl;
        float v = (t < LL) ? yT[(size_t)(d0 + dd) * LL + t] : 0.f;
        Ls[dd * 65 + tl] = v;
    }
    __syncthreads();
    int dcol = tid & 63, tg = tid >> 6;
    #pragma unroll
    for (int i = 0; i < 16; i++) {
        int t = t0 + tg * 16 + i;
        if (t >= LL) continue;
        float z = xz[(size_t)t * 2048 + 1024 + d0 + dcol];
        float y = Ls[dcol * 65 + tg * 16 + i];
        float s = z / (1.f + __expf(-z));
        xz[(size_t)t * 2048 + d0 + dcol] = y * s;
    }
}

// ---------------- yg (xz lo half, strided) -> bf16 ygb [t][1024] ------------
__global__ __launch_bounds__(256)
void cvt_yg_k(const float* __restrict__ xz0, const float* __restrict__ xz1,
              unsigned short* __restrict__ y0, unsigned short* __restrict__ y1)
{
    int idx = blockIdx.x * 256 + threadIdx.x;
    if (idx >= MROWS * 256) return;
    int dir = blockIdx.y;
    int t = idx >> 8, dq = idx & 255;
    const float* xz = dir ? xz1 : xz0;
    unsigned short* y = dir ? y1 : y0;
    float4 v = *(const float4*)(xz + (size_t)t * 2048 + dq * 4);
    short4 o;
    o.x = (short)f2bf(v.x); o.y = (short)f2bf(v.y);
    o.z = (short)f2bf(v.z); o.w = (short)f2bf(v.w);
    *(short4*)(y + (size_t)t * 1024 + dq * 4) = o;
}

// -------------------------------------------------------------------- launch
extern "C" void kernel_launch(void* const* d_in, const int* in_sizes, int n_in,
                              void* d_out, int out_size, void* d_ws, size_t ws_size,
                              hipStream_t stream) {
    const float* x = (const float*)d_in[0];
    const float* P[2][10];
    for (int dir = 0; dir < 2; dir++)
        for (int i = 0; i < 10; i++)
            P[dir][i] = (const float*)d_in[1 + dir * 10 + i];

    float* ws = (float*)d_ws;
    float* xz0   = ws;                    // 4,096,000
    float* xz1   = ws + 4096000;          // 4,096,000
    float* xcT0  = ws + 8192000;          // 2,048,000
    float* xcT1  = ws + 10240000;         // 2,048,000
    float* dtT0  = ws + 12288000;         // 2,048,000
    float* dtT1  = ws + 14336000;         // 2,048,000
    float* xdbl0 = ws + 16384000;         //   320,000
    float* xdbl1 = ws + 16704000;         //   320,000
    unsigned short* xnb0 = (unsigned short*)(ws + 17024000);  // 256,000 fl
    unsigned short* xnb1 = (unsigned short*)(ws + 17280000);  // 256,000 fl
    // aliases (lifetimes disjoint, stream-ordered):
    unsigned short* wib0 = (unsigned short*)dtT0;
    unsigned short* wib1 = (unsigned short*)dtT1;
    unsigned short* ygb0 = (unsigned short*)xcT0;
    unsigned short* ygb1 = (unsigned short*)xcT1;
    unsigned short* wob0 = (unsigned short*)dtT0;
    unsigned short* wob1 = (unsigned short*)dtT1;
    float* partial = xz0;
    float* bct = (float*)d_out;           // BCT scratch lives in d_out (512k fl)
    float* out = (float*)d_out;

    rmsnorm_k<<<MROWS, 256, 0, stream>>>(x, P[0][0], P[1][0], xnb0, xnb1);

    cvt_k<<<1024, 256, 0, stream>>>(P[0][1], wib0, 262144);
    cvt_k<<<1024, 256, 0, stream>>>(P[1][1], wib1, 262144);

    gemm1_mfma<<<dim3(16, 16, 2), 256, 0, stream>>>(
        xnb0, xnb1, wib0, wib1, xz0, xz1);

    conv_silu_k<<<dim3(16, 16, 4), 256, 0, stream>>>(
        xz0, xz1, P[0][2], P[1][2], P[0][3], P[1][3], xcT0, xcT1);

    gemm_xp_k<<<dim3(3, 16, 4), 256, 0, stream>>>(
        xcT0, xcT1, P[0][4], P[1][4], xdbl0, xdbl1, bct);

    gemm_dt_k<<<dim3(16, 16, 4), 256, 0, stream>>>(
        xdbl0, xdbl1, P[0][5], P[1][5], P[0][6], P[1][6], dtT0, dtT1);

    scan_k<<<dim3(256, 4), 256, 0, stream>>>(
        dtT0, dtT1, xcT0, xcT1, bct,
        P[0][7], P[1][7], P[0][8], P[1][8]);

    gate_k<<<dim3(16, 16, 4), 256, 0, stream>>>(
        dtT0, dtT1, xz0, xz1);

    cvt_yg_k<<<dim3(2000, 2), 256, 0, stream>>>(xz0, xz1, ygb0, ygb1);

    cvt_k<<<512, 256, 0, stream>>>(P[0][9], wob0, 131072);
    cvt_k<<<512, 256, 0, stream>>>(P[1][9], wob1, 131072);

    gemm_out_mfma<<<dim3(8, 32, 4), 256, 0, stream>>>(
        ygb0, ygb1, wob0, wob1, partial);

    reduce_out_k<<<1000, 256, 0, stream>>>(x, partial, out);
}

// Round 6
// 354.712 us; speedup vs baseline: 3.6046x; 1.1108x over previous
//
#include <hip/hip_runtime.h>
#include <hip/hip_bf16.h>
#include <math.h>

#define DM   512
#define DI   1024
#define NS   64
#define RDT  32
#define BB   2
#define LL   1000
#define MROWS (BB*LL)   // 2000

typedef __attribute__((ext_vector_type(8))) short bf16x8;
typedef __attribute__((ext_vector_type(4))) float f32x4;

// f32 -> bf16 RNE (finite inputs)
__device__ __forceinline__ unsigned short f2bf(float f) {
    unsigned u = __builtin_bit_cast(unsigned, f);
    u = (u + 0x7FFF + ((u >> 16) & 1)) >> 16;
    return (unsigned short)u;
}

__device__ __forceinline__ float bcast_lane(float v, int lane) {
    return __builtin_bit_cast(float,
        __builtin_amdgcn_readlane(__builtin_bit_cast(int, v), lane));
}

// ------------------- rmsnorm -> per-dir bf16 (norm_w folded) ----------------
__global__ __launch_bounds__(256)
void rmsnorm_k(const float* __restrict__ x,
               const float* __restrict__ nw0, const float* __restrict__ nw1,
               unsigned short* __restrict__ xnb0, unsigned short* __restrict__ xnb1) {
    int row = blockIdx.x;
    int tid = threadIdx.x;
    const float* xr = x + (size_t)row * DM;
    float2 v = *(const float2*)(xr + tid * 2);
    float ss = v.x * v.x + v.y * v.y;
    #pragma unroll
    for (int off = 32; off; off >>= 1) ss += __shfl_xor(ss, off, 64);
    __shared__ float red[4];
    if ((tid & 63) == 0) red[tid >> 6] = ss;
    __syncthreads();
    float tot = red[0] + red[1] + red[2] + red[3];
    float scale = rsqrtf(tot / (float)DM + 1e-5f);
    float2 w0 = *(const float2*)(nw0 + tid * 2);
    float2 w1 = *(const float2*)(nw1 + tid * 2);
    short2 o0, o1;
    o0.x = (short)f2bf(v.x * scale * w0.x);
    o0.y = (short)f2bf(v.y * scale * w0.y);
    o1.x = (short)f2bf(v.x * scale * w1.x);
    o1.y = (short)f2bf(v.y * scale * w1.y);
    *(short2*)(xnb0 + (size_t)row * DM + tid * 2) = o0;
    *(short2*)(xnb1 + (size_t)row * DM + tid * 2) = o1;
}

// ------------------------------------------------ f32 -> bf16 convert ------
__global__ __launch_bounds__(256)
void cvt_k(const float* __restrict__ in, unsigned short* __restrict__ out, int n4) {
    int idx = blockIdx.x * 256 + threadIdx.x;
    if (idx >= n4) return;
    float4 v = *(const float4*)(in + (size_t)idx * 4);
    short4 o;
    o.x = (short)f2bf(v.x); o.y = (short)f2bf(v.y);
    o.z = (short)f2bf(v.z); o.w = (short)f2bf(v.w);
    *(short4*)(out + (size_t)idx * 4) = o;
}

// ------------- GEMM1 (in_proj) bf16 MFMA: xz[dir] = xn_dir @ W^T ------------
__global__ __launch_bounds__(256, 2)
void gemm1_mfma(const unsigned short* __restrict__ xnb0,
                const unsigned short* __restrict__ xnb1,
                const unsigned short* __restrict__ wib0,
                const unsigned short* __restrict__ wib1,
                float* __restrict__ xz0, float* __restrict__ xz1)
{
    __shared__ __align__(16) unsigned short As[128 * 40];
    __shared__ __align__(16) unsigned short Bs[128 * 40];
    int dir = blockIdx.z;
    const unsigned short* A = dir ? xnb1 : xnb0;
    const unsigned short* W = dir ? wib1 : wib0;
    float* C = dir ? xz1 : xz0;
    int n0 = blockIdx.x * 128, m0 = blockIdx.y * 128;
    int tid = threadIdx.x;
    int wv = tid >> 6, lane = tid & 63;
    int wr = wv >> 1, wc = wv & 1;
    int fl = lane & 15, kg = lane >> 4;

    f32x4 acc[4][4];
    #pragma unroll
    for (int i = 0; i < 4; i++)
        #pragma unroll
        for (int j = 0; j < 4; j++) acc[i][j] = (f32x4){0.f, 0.f, 0.f, 0.f};

    int sr = tid >> 2, cg = tid & 3;
    for (int k0 = 0; k0 < 512; k0 += 32) {
        #pragma unroll
        for (int i = 0; i < 2; i++) {
            int row = sr + i * 64;
            int m = m0 + row;
            float4 av = make_float4(0.f, 0.f, 0.f, 0.f);
            if (m < MROWS) {
                int rs = m;
                if (dir) { int b = m / LL, t = m % LL; rs = b * LL + (LL - 1 - t); }
                av = *(const float4*)(A + (size_t)rs * 512 + k0 + cg * 8);
            }
            *(float4*)(&As[row * 40 + cg * 8]) = av;
            float4 wv4 = *(const float4*)(W + (size_t)(n0 + row) * 512 + k0 + cg * 8);
            *(float4*)(&Bs[row * 40 + cg * 8]) = wv4;
        }
        __syncthreads();
        bf16x8 af[4], bf[4];
        #pragma unroll
        for (int fr = 0; fr < 4; fr++)
            af[fr] = *(const bf16x8*)(&As[(wr * 64 + fr * 16 + fl) * 40 + kg * 8]);
        #pragma unroll
        for (int fc = 0; fc < 4; fc++)
            bf[fc] = *(const bf16x8*)(&Bs[(wc * 64 + fc * 16 + fl) * 40 + kg * 8]);
        #pragma unroll
        for (int fr = 0; fr < 4; fr++)
            #pragma unroll
            for (int fc = 0; fc < 4; fc++)
                acc[fr][fc] = __builtin_amdgcn_mfma_f32_16x16x32_bf16(
                    af[fr], bf[fc], acc[fr][fc], 0, 0, 0);
        __syncthreads();
    }
    #pragma unroll
    for (int fr = 0; fr < 4; fr++)
        #pragma unroll
        for (int fc = 0; fc < 4; fc++)
            #pragma unroll
            for (int j = 0; j < 4; j++) {
                int m = m0 + wr * 64 + fr * 16 + kg * 4 + j;
                if (m < MROWS) {
                    int n = n0 + wc * 64 + fc * 16 + fl;
                    C[(size_t)m * 2048 + n] = acc[fr][fc][j];
                }
            }
}

// -------- out_proj bf16 MFMA, split (dir,kslice) -> f32 partials ------------
__global__ __launch_bounds__(256, 2)
void gemm_out_mfma(const unsigned short* __restrict__ ygb0,
                   const unsigned short* __restrict__ ygb1,
                   const unsigned short* __restrict__ wob0,
                   const unsigned short* __restrict__ wob1,
                   float* __restrict__ partial)
{
    __shared__ __align__(16) unsigned short As[64 * 40];
    __shared__ __align__(16) unsigned short Bs[64 * 40];
    int z = blockIdx.z;
    int dir = z >> 1, ks = z & 1;
    const unsigned short* A = dir ? ygb1 : ygb0;
    const unsigned short* W = dir ? wob1 : wob0;
    float* P = partial + (size_t)z * MROWS * 512;
    int n0 = blockIdx.x * 64, m0 = blockIdx.y * 64;
    int kbase = ks * 512;
    int tid = threadIdx.x;
    int wv = tid >> 6, lane = tid & 63;
    int wr = wv >> 1, wc = wv & 1;
    int fl = lane & 15, kg = lane >> 4;

    f32x4 acc[2][2];
    #pragma unroll
    for (int i = 0; i < 2; i++)
        #pragma unroll
        for (int j = 0; j < 2; j++) acc[i][j] = (f32x4){0.f, 0.f, 0.f, 0.f};

    int sr = tid >> 2, cg = tid & 3;
    for (int k0 = 0; k0 < 512; k0 += 32) {
        int m = m0 + sr;
        float4 av = make_float4(0.f, 0.f, 0.f, 0.f);
        if (m < MROWS)
            av = *(const float4*)(A + (size_t)m * 1024 + kbase + k0 + cg * 8);
        *(float4*)(&As[sr * 40 + cg * 8]) = av;
        float4 wv4 = *(const float4*)(W + (size_t)(n0 + sr) * 1024 + kbase + k0 + cg * 8);
        *(float4*)(&Bs[sr * 40 + cg * 8]) = wv4;
        __syncthreads();
        bf16x8 af[2], bf[2];
        #pragma unroll
        for (int fr = 0; fr < 2; fr++)
            af[fr] = *(const bf16x8*)(&As[(wr * 32 + fr * 16 + fl) * 40 + kg * 8]);
        #pragma unroll
        for (int fc = 0; fc < 2; fc++)
            bf[fc] = *(const bf16x8*)(&Bs[(wc * 32 + fc * 16 + fl) * 40 + kg * 8]);
        #pragma unroll
        for (int fr = 0; fr < 2; fr++)
            #pragma unroll
            for (int fc = 0; fc < 2; fc++)
                acc[fr][fc] = __builtin_amdgcn_mfma_f32_16x16x32_bf16(
                    af[fr], bf[fc], acc[fr][fc], 0, 0, 0);
        __syncthreads();
    }
    #pragma unroll
    for (int fr = 0; fr < 2; fr++)
        #pragma unroll
        for (int fc = 0; fc < 2; fc++)
            #pragma unroll
            for (int j = 0; j < 4; j++) {
                int m = m0 + wr * 32 + fr * 16 + kg * 4 + j;
                if (m < MROWS) {
                    int n = n0 + wc * 32 + fc * 16 + fl;
                    P[(size_t)m * 512 + n] = acc[fr][fc][j];
                }
            }
}

// out[m] = 2x[m] + pf0[m] + pf1[m] + pb0[flip(m)] + pb1[flip(m)]
__global__ __launch_bounds__(256)
void reduce_out_k(const float* __restrict__ x, const float* __restrict__ partial,
                  float* __restrict__ out)
{
    int idx = blockIdx.x * 256 + threadIdx.x;
    if (idx >= MROWS * 128) return;
    int m = idx >> 7, q = idx & 127;
    int b = m / LL, t = m % LL;
    int fm = b * LL + (LL - 1 - t);
    const float* p0 = partial;
    const float* p1 = partial + (size_t)MROWS * 512;
    const float* p2 = partial + (size_t)2 * MROWS * 512;
    const float* p3 = partial + (size_t)3 * MROWS * 512;
    float4 xv = *(const float4*)(x  + (size_t)m  * 512 + q * 4);
    float4 a  = *(const float4*)(p0 + (size_t)m  * 512 + q * 4);
    float4 bv = *(const float4*)(p1 + (size_t)m  * 512 + q * 4);
    float4 c  = *(const float4*)(p2 + (size_t)fm * 512 + q * 4);
    float4 d  = *(const float4*)(p3 + (size_t)fm * 512 + q * 4);
    float4 o;
    o.x = 2.f * xv.x + a.x + bv.x + c.x + d.x;
    o.y = 2.f * xv.y + a.y + bv.y + c.y + d.y;
    o.z = 2.f * xv.z + a.z + bv.z + c.z + d.z;
    o.w = 2.f * xv.w + a.w + bv.w + c.w + d.w;
    *(float4*)(out + (size_t)m * 512 + q * 4) = o;
}

// ------------------------- causal dwconv + silu -> TRANSPOSED xcT [b][d][t] --
__global__ __launch_bounds__(256)
void conv_silu_k(const float* __restrict__ xz0, const float* __restrict__ xz1,
                 const float* __restrict__ cw0, const float* __restrict__ cw1,
                 const float* __restrict__ cb0, const float* __restrict__ cb1,
                 float* __restrict__ xcT0, float* __restrict__ xcT1)
{
    __shared__ float Ls[64 * 65];
    int dirb = blockIdx.z;
    int dir = dirb >> 1, b = dirb & 1;
    int d0 = blockIdx.x * 64, t0 = blockIdx.y * 64;
    int tid = threadIdx.x;
    int dl = tid & 63, tg = tid >> 6;

    const float* in = (dir ? xz1 : xz0) + (size_t)b * LL * 2048;
    const float* cw = dir ? cw1 : cw0;
    const float* cb = dir ? cb1 : cb0;
    float*      xcT = dir ? xcT1 : xcT0;

    float4 w4 = ((const float4*)cw)[d0 + dl];
    float bias = cb[d0 + dl];

    int ts = t0 + tg * 16;
    float x3 = 0.f, x2 = 0.f, x1 = 0.f;
    if (ts - 3 >= 0 && ts - 3 < LL) x3 = in[(size_t)(ts - 3) * 2048 + d0 + dl];
    if (ts - 2 >= 0 && ts - 2 < LL) x2 = in[(size_t)(ts - 2) * 2048 + d0 + dl];
    if (ts - 1 >= 0 && ts - 1 < LL) x1 = in[(size_t)(ts - 1) * 2048 + d0 + dl];

    #pragma unroll
    for (int i = 0; i < 16; i++) {
        int t = ts + i;
        float x0v = (t < LL) ? in[(size_t)t * 2048 + d0 + dl] : 0.f;
        float a = bias + x3 * w4.x + x2 * w4.y + x1 * w4.z + x0v * w4.w;
        float s = a / (1.f + __expf(-a));
        Ls[dl * 65 + tg * 16 + i] = s;
        x3 = x2; x2 = x1; x1 = x0v;
    }
    __syncthreads();
    int tl = tid & 63, dg = tid >> 6;
    #pragma unroll
    for (int i = 0; i < 16; i++) {
        int dd = dg * 16 + i;
        int t = t0 + tl;
        if (t < LL)
            xcT[((size_t)(b * 1024) + d0 + dd) * LL + t] = Ls[dd * 65 + tl];
    }
}

// --------------------- x_proj GEMM + BCT transposed epilogue ----------------
__global__ __launch_bounds__(256)
void gemm_xp_k(const float* __restrict__ xcT0, const float* __restrict__ xcT1,
               const float* __restrict__ xp0, const float* __restrict__ xp1,
               float* __restrict__ xd0, float* __restrict__ xd1,
               float* __restrict__ bct)
{
    __shared__ float As[16 * 68];   // [k][m=t]
    __shared__ float Ws[16 * 68];   // [k][n]
    __shared__ float T[64 * 67];    // [n][m] transposed staging
    int dirb = blockIdx.z;
    int dir = dirb >> 1, b = dirb & 1;
    const float* xcT = (dir ? xcT1 : xcT0) + (size_t)b * 1024 * LL;
    const float* W   = dir ? xp1 : xp0;     // (160,1024)
    float*       C   = (dir ? xd1 : xd0) + (size_t)b * LL * 160;
    int n0 = blockIdx.x * 64, t0 = blockIdx.y * 64;
    int tid = threadIdx.x;
    int tx = tid & 15, ty = tid >> 4;

    float acc[4][4] = {};

    for (int k0 = 0; k0 < 1024; k0 += 16) {
        {
            int kk = tid & 15, mq = tid >> 4;
            float4 v = make_float4(0.f, 0.f, 0.f, 0.f);
            if (t0 + mq * 4 + 3 < LL)
                v = *(const float4*)(xcT + (size_t)(k0 + kk) * LL + t0 + mq * 4);
            *(float4*)(As + kk * 68 + mq * 4) = v;
        }
        {
            int row = tid >> 2, q = tid & 3;
            float4 v = make_float4(0.f, 0.f, 0.f, 0.f);
            if (n0 + row < 160)
                v = *(const float4*)(W + (size_t)(n0 + row) * 1024 + k0 + q * 4);
            Ws[(q * 4 + 0) * 68 + row] = v.x;
            Ws[(q * 4 + 1) * 68 + row] = v.y;
            Ws[(q * 4 + 2) * 68 + row] = v.z;
            Ws[(q * 4 + 3) * 68 + row] = v.w;
        }
        __syncthreads();
        #pragma unroll
        for (int k = 0; k < 16; k++) {
            float4 a = *(const float4*)(As + k * 68 + ty * 4);
            float4 w = *(const float4*)(Ws + k * 68 + tx * 4);
            float av[4] = {a.x, a.y, a.z, a.w};
            float wvv[4] = {w.x, w.y, w.z, w.w};
            #pragma unroll
            for (int i = 0; i < 4; i++)
                #pragma unroll
                for (int j = 0; j < 4; j++)
                    acc[i][j] = fmaf(av[i], wvv[j], acc[i][j]);
        }
        __syncthreads();
    }

    if (n0 == 0) {
        #pragma unroll
        for (int i = 0; i < 4; i++) {
            int t = t0 + ty * 4 + i;
            if (t >= LL) continue;
            #pragma unroll
            for (int j = 0; j < 4; j++) {
                int n = tx * 4 + j;
                C[(size_t)t * 160 + n] = acc[i][j];
            }
        }
    }

    #pragma unroll
    for (int i = 0; i < 4; i++)
        #pragma unroll
        for (int j = 0; j < 4; j++)
            T[(tx * 4 + j) * 67 + ty * 4 + i] = acc[i][j];
    __syncthreads();
    int tl = tid & 63, ng = tid >> 6;
    #pragma unroll
    for (int i = 0; i < 16; i++) {
        int nl = ng * 16 + i;
        int n = n0 + nl;
        int t = t0 + tl;
        if (n >= 32 && n < 160 && t < LL)
            bct[((size_t)dirb * 128 + (n - 32)) * LL + t] = T[nl * 67 + tl];
    }
}

// ---- dt GEMM (K=32) + softplus, output TRANSPOSED dtT [b][d][t] ------------
__global__ __launch_bounds__(256)
void gemm_dt_k(const float* __restrict__ xd0, const float* __restrict__ xd1,
               const float* __restrict__ w0, const float* __restrict__ w1,
               const float* __restrict__ bb0, const float* __restrict__ bb1,
               float* __restrict__ dtT0, float* __restrict__ dtT1)
{
    __shared__ float As[64 * 33];
    __shared__ float Ws[32 * 68];
    __shared__ float T[64 * 67];
    int dirb = blockIdx.z;
    int dir = dirb >> 1, b = dirb & 1;
    const float* xd = (dir ? xd1 : xd0) + (size_t)b * LL * 160;
    const float* W  = dir ? w1 : w0;
    const float* bi = dir ? bb1 : bb0;
    float*      dtT = (dir ? dtT1 : dtT0) + (size_t)b * 1024 * LL;
    int n0 = blockIdx.x * 64, t0 = blockIdx.y * 64;
    int tid = threadIdx.x;
    int tx = tid & 15, ty = tid >> 4;

    #pragma unroll
    for (int i = 0; i < 2; i++) {
        int j = tid + 256 * i;
        int row = j >> 3, q = j & 7;
        float4 v = make_float4(0.f, 0.f, 0.f, 0.f);
        if (t0 + row < LL)
            v = *(const float4*)(xd + (size_t)(t0 + row) * 160 + q * 4);
        As[row * 33 + q * 4 + 0] = v.x;
        As[row * 33 + q * 4 + 1] = v.y;
        As[row * 33 + q * 4 + 2] = v.z;
        As[row * 33 + q * 4 + 3] = v.w;
        float4 wv = *(const float4*)(W + (size_t)(n0 + row) * 32 + q * 4);
        Ws[(q * 4 + 0) * 68 + row] = wv.x;
        Ws[(q * 4 + 1) * 68 + row] = wv.y;
        Ws[(q * 4 + 2) * 68 + row] = wv.z;
        Ws[(q * 4 + 3) * 68 + row] = wv.w;
    }
    __syncthreads();

    float acc[4][4] = {};
    #pragma unroll 8
    for (int k = 0; k < 32; k++) {
        float4 w = *(const float4*)(Ws + k * 68 + tx * 4);
        float wvv[4] = {w.x, w.y, w.z, w.w};
        float av[4];
        #pragma unroll
        for (int i = 0; i < 4; i++) av[i] = As[(ty * 4 + i) * 33 + k];
        #pragma unroll
        for (int i = 0; i < 4; i++)
            #pragma unroll
            for (int j = 0; j < 4; j++)
                acc[i][j] = fmaf(av[i], wvv[j], acc[i][j]);
    }
    __syncthreads();

    #pragma unroll
    for (int i = 0; i < 4; i++) {
        #pragma unroll
        for (int j = 0; j < 4; j++) {
            int n = tx * 4 + j;
            float v = acc[i][j] + bi[n0 + n];
            v = (v > 20.f) ? v : log1pf(__expf(v));
            T[n * 67 + ty * 4 + i] = v;
        }
    }
    __syncthreads();

    int tl = tid & 63, ng = tid >> 6;
    #pragma unroll
    for (int i = 0; i < 16; i++) {
        int nl = ng * 16 + i;
        int t = t0 + tl;
        if (t < LL)
            dtT[(size_t)(n0 + nl) * LL + t] = T[nl * 67 + tl];
    }
}

// ------------------------------------------------------------ selective scan
// Block = 4 waves sharing (dirb, t-tile): B/C staged cooperatively into LDS
// in [n][t] layout (coalesced global, per-lane-row ds_read_b128 consumption).
// Per-16-step P-tile transpose-sum with permlane quarter-combines.
__global__ __launch_bounds__(256)
void scan_k(float* __restrict__ dtT0, float* __restrict__ dtT1,
            const float* __restrict__ ucT0, const float* __restrict__ ucT1,
            const float* __restrict__ bct,
            const float* __restrict__ Al0, const float* __restrict__ Al1,
            const float* __restrict__ Dc0, const float* __restrict__ Dc1)
{
    __shared__ float Bs[64 * 66];
    __shared__ float Cs[64 * 66];
    __shared__ float Pt[4][16 * 66];
    int dirb = blockIdx.y;
    int dir = dirb >> 1, b = dirb & 1;
    int wid = threadIdx.x >> 6, lane = threadIdx.x & 63;
    int d = blockIdx.x * 4 + wid;
    float* Pw = Pt[wid];

    float*       dtT = (dir ? dtT1 : dtT0);
    const float* ucT = (dir ? ucT1 : ucT0);
    const float* Al  = dir ? Al1 : Al0;
    const float* Dc  = dir ? Dc1 : Dc0;

    float a    = -__expf(Al[d * 64 + lane]) * 1.44269504f;
    float Dp64 = Dc[d] * (1.f / 64.f);
    float h    = 0.f;
    size_t chan = ((size_t)(b * 1024 + d)) * LL;
    const float* Bg = bct + (size_t)dirb * 128 * LL;   // rows 0..63=B, 64..127=C

    int sr = threadIdx.x >> 4, c4 = (threadIdx.x & 15) * 4;
    int tl16 = lane & 15, qq = lane >> 4;
    const float* Prow = Pw + tl16 * 66 + qq * 16;

    for (int t0 = 0; t0 < LL; t0 += 64) {
        int rem = min(64, LL - t0);
        __syncthreads();
        // cooperative stage: B/C tile [n=64][t=64] (tail overread is in-bounds)
        #pragma unroll
        for (int i = 0; i < 4; i++) {
            int row = sr + i * 16;
            float4 bv = *(const float4*)(Bg + (size_t)row * LL + t0 + c4);
            float4 cv = *(const float4*)(Bg + (size_t)(row + 64) * LL + t0 + c4);
            *(float4*)(&Bs[row * 66 + c4]) = bv;
            *(float4*)(&Cs[row * 66 + c4]) = cv;
        }
        float dta = 0.f, ua = 0.f;
        if (lane < rem) {
            dta = dtT[chan + t0 + lane];
            ua  = ucT[chan + t0 + lane];
        }
        __syncthreads();

        for (int sec = 0; sec < 4; sec++) {
            int sbase = sec * 16;
            int steps = rem - sbase;
            if (steps <= 0) break;
            if (steps > 16) steps = 16;
            if (steps < 16) {               // zero stale tail rows (rare)
                for (int i = steps; i < 16; i++) Pw[i * 66 + lane] = 0.f;
            }
            int ngr = (steps + 7) >> 3;     // 1 or 2 groups of 8
            for (int g = 0; g < ngr; g++) {
                int tb = sbase + g * 8;
                float4 B0 = *(const float4*)(&Bs[lane * 66 + tb]);
                float4 B1 = *(const float4*)(&Bs[lane * 66 + tb + 4]);
                float4 C0 = *(const float4*)(&Cs[lane * 66 + tb]);
                float4 C1 = *(const float4*)(&Cs[lane * 66 + tb + 4]);
                #pragma unroll
                for (int i = 0; i < 8; i++) {
                    float dtv = bcast_lane(dta, tb + i);
                    float u   = bcast_lane(ua,  tb + i);
                    float dA  = exp2f(dtv * a);
                    float Bn  = (i < 4) ? B0[i] : B1[i - 4];
                    float Cn  = (i < 4) ? C0[i] : C1[i - 4];
                    h = fmaf(dA, h, dtv * u * Bn);
                    Pw[(g * 8 + i) * 66 + lane] = fmaf(u, Dp64, h * Cn);
                }
            }
            // transpose-sum: lane (qq,tl16) sums 16 of row tl16
            float s = 0.f;
            #pragma unroll
            for (int j = 0; j < 8; j++) {
                float2 v = *(const float2*)(Prow + j * 2);
                s += v.x + v.y;
            }
#if __has_builtin(__builtin_amdgcn_permlane32_swap)
            {
                unsigned aa = __builtin_bit_cast(unsigned, s);
                auto r = __builtin_amdgcn_permlane32_swap(aa, aa, false, false);
                s = __builtin_bit_cast(float, (unsigned)r[0]) +
                    __builtin_bit_cast(float, (unsigned)r[1]);
            }
#else
            s += __shfl_xor(s, 32, 64);
#endif
#if __has_builtin(__builtin_amdgcn_permlane16_swap)
            {
                unsigned aa = __builtin_bit_cast(unsigned, s);
                auto r = __builtin_amdgcn_permlane16_swap(aa, aa, false, false);
                s = __builtin_bit_cast(float, (unsigned)r[0]) +
                    __builtin_bit_cast(float, (unsigned)r[1]);
            }
#else
            s += __shfl_xor(s, 16, 64);
#endif
            if (lane < steps)
                dtT[chan + t0 + sbase + lane] = s;
        }
    }
}

// ---------------- gate: xz_lo[row][d] = yT[d][t] * silu(z[row][1024+d]) -----
__global__ __launch_bounds__(256)
void gate_k(const float* __restrict__ yT0, const float* __restrict__ yT1,
            float* __restrict__ xz0, float* __restrict__ xz1)
{
    __shared__ float Ls[64 * 65];
    int dirb = blockIdx.z;
    int dir = dirb >> 1, b = dirb & 1;
    int d0 = blockIdx.x * 64, t0 = blockIdx.y * 64;
    int tid = threadIdx.x;
    const float* yT = (dir ? yT1 : yT0) + (size_t)b * 1024 * LL;
    float*       xz = (dir ? xz1 : xz0) + (size_t)b * LL * 2048;

    int tl = tid & 63, dg = tid >> 6;
    #pragma unroll
    for (int i = 0; i < 16; i++) {
        int dd = dg * 16 + i;
        int t = t0 + tl;
        float v = (t < LL) ? yT[(size_t)(d0 + dd) * LL + t] : 0.f;
        Ls[dd * 65 + tl] = v;
    }
    __syncthreads();
    int dcol = tid & 63, tg = tid >> 6;
    #pragma unroll
    for (int i = 0; i < 16; i++) {
        int t = t0 + tg * 16 + i;
        if (t >= LL) continue;
        float z = xz[(size_t)t * 2048 + 1024 + d0 + dcol];
        float y = Ls[dcol * 65 + tg * 16 + i];
        float s = z / (1.f + __expf(-z));
        xz[(size_t)t * 2048 + d0 + dcol] = y * s;
    }
}

// ---------------- yg (xz lo half, strided) -> bf16 ygb [t][1024] ------------
__global__ __launch_bounds__(256)
void cvt_yg_k(const float* __restrict__ xz0, const float* __restrict__ xz1,
              unsigned short* __restrict__ y0, unsigned short* __restrict__ y1)
{
    int idx = blockIdx.x * 256 + threadIdx.x;
    if (idx >= MROWS * 256) return;
    int dir = blockIdx.y;
    int t = idx >> 8, dq = idx & 255;
    const float* xz = dir ? xz1 : xz0;
    unsigned short* y = dir ? y1 : y0;
    float4 v = *(const float4*)(xz + (size_t)t * 2048 + dq * 4);
    short4 o;
    o.x = (short)f2bf(v.x); o.y = (short)f2bf(v.y);
    o.z = (short)f2bf(v.z); o.w = (short)f2bf(v.w);
    *(short4*)(y + (size_t)t * 1024 + dq * 4) = o;
}

// -------------------------------------------------------------------- launch
extern "C" void kernel_launch(void* const* d_in, const int* in_sizes, int n_in,
                              void* d_out, int out_size, void* d_ws, size_t ws_size,
                              hipStream_t stream) {
    const float* x = (const float*)d_in[0];
    const float* P[2][10];
    for (int dir = 0; dir < 2; dir++)
        for (int i = 0; i < 10; i++)
            P[dir][i] = (const float*)d_in[1 + dir * 10 + i];

    float* ws = (float*)d_ws;
    float* xz0   = ws;                    // 4,096,000
    float* xz1   = ws + 4096000;          // 4,096,000
    float* xcT0  = ws + 8192000;          // 2,048,000
    float* xcT1  = ws + 10240000;         // 2,048,000
    float* dtT0  = ws + 12288000;         // 2,048,000
    float* dtT1  = ws + 14336000;         // 2,048,000
    float* xdbl0 = ws + 16384000;         //   320,000
    float* xdbl1 = ws + 16704000;         //   320,000
    unsigned short* xnb0 = (unsigned short*)(ws + 17024000);  // 256,000 fl
    unsigned short* xnb1 = (unsigned short*)(ws + 17280000);  // 256,000 fl
    // aliases (lifetimes disjoint, stream-ordered):
    unsigned short* wib0 = (unsigned short*)dtT0;
    unsigned short* wib1 = (unsigned short*)dtT1;
    unsigned short* ygb0 = (unsigned short*)xcT0;
    unsigned short* ygb1 = (unsigned short*)xcT1;
    unsigned short* wob0 = (unsigned short*)dtT0;
    unsigned short* wob1 = (unsigned short*)dtT1;
    float* partial = xz0;
    float* bct = (float*)d_out;           // BCT scratch lives in d_out
    float* out = (float*)d_out;

    rmsnorm_k<<<MROWS, 256, 0, stream>>>(x, P[0][0], P[1][0], xnb0, xnb1);

    cvt_k<<<1024, 256, 0, stream>>>(P[0][1], wib0, 262144);
    cvt_k<<<1024, 256, 0, stream>>>(P[1][1], wib1, 262144);

    gemm1_mfma<<<dim3(16, 16, 2), 256, 0, stream>>>(
        xnb0, xnb1, wib0, wib1, xz0, xz1);

    conv_silu_k<<<dim3(16, 16, 4), 256, 0, stream>>>(
        xz0, xz1, P[0][2], P[1][2], P[0][3], P[1][3], xcT0, xcT1);

    gemm_xp_k<<<dim3(3, 16, 4), 256, 0, stream>>>(
        xcT0, xcT1, P[0][4], P[1][4], xdbl0, xdbl1, bct);

    gemm_dt_k<<<dim3(16, 16, 4), 256, 0, stream>>>(
        xdbl0, xdbl1, P[0][5], P[1][5], P[0][6], P[1][6], dtT0, dtT1);

    scan_k<<<dim3(256, 4), 256, 0, stream>>>(
        dtT0, dtT1, xcT0, xcT1, bct,
        P[0][7], P[1][7], P[0][8], P[1][8]);

    gate_k<<<dim3(16, 16, 4), 256, 0, stream>>>(
        dtT0, dtT1, xz0, xz1);

    cvt_yg_k<<<dim3(2000, 2), 256, 0, stream>>>(xz0, xz1, ygb0, ygb1);

    cvt_k<<<512, 256, 0, stream>>>(P[0][9], wob0, 131072);
    cvt_k<<<512, 256, 0, stream>>>(P[1][9], wob1, 131072);

    gemm_out_mfma<<<dim3(8, 32, 4), 256, 0, stream>>>(
        ygb0, ygb1, wob0, wob1, partial);

    reduce_out_k<<<1000, 256, 0, stream>>>(x, partial, out);
}

// Round 7
// 335.068 us; speedup vs baseline: 3.8160x; 1.0586x over previous
//
#include <hip/hip_runtime.h>
#include <hip/hip_bf16.h>
#include <math.h>

#define DM   512
#define DI   1024
#define NS   64
#define RDT  32
#define BB   2
#define LL   1000
#define MROWS (BB*LL)   // 2000

typedef __attribute__((ext_vector_type(8))) short bf16x8;
typedef __attribute__((ext_vector_type(4))) float f32x4;

// f32 -> bf16 RNE (finite inputs)
__device__ __forceinline__ unsigned short f2bf(float f) {
    unsigned u = __builtin_bit_cast(unsigned, f);
    u = (u + 0x7FFF + ((u >> 16) & 1)) >> 16;
    return (unsigned short)u;
}

__device__ __forceinline__ float bcast_lane(float v, int lane) {
    return __builtin_bit_cast(float,
        __builtin_amdgcn_readlane(__builtin_bit_cast(int, v), lane));
}

// ------------------- rmsnorm -> per-dir bf16 (norm_w folded) ----------------
__global__ __launch_bounds__(256)
void rmsnorm_k(const float* __restrict__ x,
               const float* __restrict__ nw0, const float* __restrict__ nw1,
               unsigned short* __restrict__ xnb0, unsigned short* __restrict__ xnb1) {
    int row = blockIdx.x;
    int tid = threadIdx.x;
    const float* xr = x + (size_t)row * DM;
    float2 v = *(const float2*)(xr + tid * 2);
    float ss = v.x * v.x + v.y * v.y;
    #pragma unroll
    for (int off = 32; off; off >>= 1) ss += __shfl_xor(ss, off, 64);
    __shared__ float red[4];
    if ((tid & 63) == 0) red[tid >> 6] = ss;
    __syncthreads();
    float tot = red[0] + red[1] + red[2] + red[3];
    float scale = rsqrtf(tot / (float)DM + 1e-5f);
    float2 w0 = *(const float2*)(nw0 + tid * 2);
    float2 w1 = *(const float2*)(nw1 + tid * 2);
    short2 o0, o1;
    o0.x = (short)f2bf(v.x * scale * w0.x);
    o0.y = (short)f2bf(v.y * scale * w0.y);
    o1.x = (short)f2bf(v.x * scale * w1.x);
    o1.y = (short)f2bf(v.y * scale * w1.y);
    *(short2*)(xnb0 + (size_t)row * DM + tid * 2) = o0;
    *(short2*)(xnb1 + (size_t)row * DM + tid * 2) = o1;
}

// ------------------------------------ f32 -> bf16 convert, 2 arrays batched --
__global__ __launch_bounds__(256)
void cvt2_k(const float* __restrict__ in0, const float* __restrict__ in1,
            unsigned short* __restrict__ out0, unsigned short* __restrict__ out1,
            int n4) {
    int idx = blockIdx.x * 256 + threadIdx.x;
    if (idx >= n4) return;
    const float* in = blockIdx.y ? in1 : in0;
    unsigned short* out = blockIdx.y ? out1 : out0;
    float4 v = *(const float4*)(in + (size_t)idx * 4);
    short4 o;
    o.x = (short)f2bf(v.x); o.y = (short)f2bf(v.y);
    o.z = (short)f2bf(v.z); o.w = (short)f2bf(v.w);
    *(short4*)(out + (size_t)idx * 4) = o;
}

// ------------- GEMM1 (in_proj) bf16 MFMA: xz[dir] = xn_dir @ W^T ------------
__global__ __launch_bounds__(256, 2)
void gemm1_mfma(const unsigned short* __restrict__ xnb0,
                const unsigned short* __restrict__ xnb1,
                const unsigned short* __restrict__ wib0,
                const unsigned short* __restrict__ wib1,
                float* __restrict__ xz0, float* __restrict__ xz1)
{
    __shared__ __align__(16) unsigned short As[128 * 40];
    __shared__ __align__(16) unsigned short Bs[128 * 40];
    int dir = blockIdx.z;
    const unsigned short* A = dir ? xnb1 : xnb0;
    const unsigned short* W = dir ? wib1 : wib0;
    float* C = dir ? xz1 : xz0;
    int n0 = blockIdx.x * 128, m0 = blockIdx.y * 128;
    int tid = threadIdx.x;
    int wv = tid >> 6, lane = tid & 63;
    int wr = wv >> 1, wc = wv & 1;
    int fl = lane & 15, kg = lane >> 4;

    f32x4 acc[4][4];
    #pragma unroll
    for (int i = 0; i < 4; i++)
        #pragma unroll
        for (int j = 0; j < 4; j++) acc[i][j] = (f32x4){0.f, 0.f, 0.f, 0.f};

    int sr = tid >> 2, cg = tid & 3;
    for (int k0 = 0; k0 < 512; k0 += 32) {
        #pragma unroll
        for (int i = 0; i < 2; i++) {
            int row = sr + i * 64;
            int m = m0 + row;
            float4 av = make_float4(0.f, 0.f, 0.f, 0.f);
            if (m < MROWS) {
                int rs = m;
                if (dir) { int b = m / LL, t = m % LL; rs = b * LL + (LL - 1 - t); }
                av = *(const float4*)(A + (size_t)rs * 512 + k0 + cg * 8);
            }
            *(float4*)(&As[row * 40 + cg * 8]) = av;
            float4 wv4 = *(const float4*)(W + (size_t)(n0 + row) * 512 + k0 + cg * 8);
            *(float4*)(&Bs[row * 40 + cg * 8]) = wv4;
        }
        __syncthreads();
        bf16x8 af[4], bf[4];
        #pragma unroll
        for (int fr = 0; fr < 4; fr++)
            af[fr] = *(const bf16x8*)(&As[(wr * 64 + fr * 16 + fl) * 40 + kg * 8]);
        #pragma unroll
        for (int fc = 0; fc < 4; fc++)
            bf[fc] = *(const bf16x8*)(&Bs[(wc * 64 + fc * 16 + fl) * 40 + kg * 8]);
        #pragma unroll
        for (int fr = 0; fr < 4; fr++)
            #pragma unroll
            for (int fc = 0; fc < 4; fc++)
                acc[fr][fc] = __builtin_amdgcn_mfma_f32_16x16x32_bf16(
                    af[fr], bf[fc], acc[fr][fc], 0, 0, 0);
        __syncthreads();
    }
    #pragma unroll
    for (int fr = 0; fr < 4; fr++)
        #pragma unroll
        for (int fc = 0; fc < 4; fc++)
            #pragma unroll
            for (int j = 0; j < 4; j++) {
                int m = m0 + wr * 64 + fr * 16 + kg * 4 + j;
                if (m < MROWS) {
                    int n = n0 + wc * 64 + fc * 16 + fl;
                    C[(size_t)m * 2048 + n] = acc[fr][fc][j];
                }
            }
}

// -------- out_proj bf16 MFMA, full K, per-dir -> f32 partials ---------------
__global__ __launch_bounds__(256, 2)
void gemm_out_mfma(const unsigned short* __restrict__ ygb0,
                   const unsigned short* __restrict__ ygb1,
                   const unsigned short* __restrict__ wob0,
                   const unsigned short* __restrict__ wob1,
                   float* __restrict__ partial)
{
    __shared__ __align__(16) unsigned short As[64 * 40];
    __shared__ __align__(16) unsigned short Bs[64 * 40];
    int dir = blockIdx.z;
    const unsigned short* A = dir ? ygb1 : ygb0;
    const unsigned short* W = dir ? wob1 : wob0;
    float* P = partial + (size_t)dir * MROWS * 512;
    int n0 = blockIdx.x * 64, m0 = blockIdx.y * 64;
    int tid = threadIdx.x;
    int wv = tid >> 6, lane = tid & 63;
    int wr = wv >> 1, wc = wv & 1;
    int fl = lane & 15, kg = lane >> 4;

    f32x4 acc[2][2];
    #pragma unroll
    for (int i = 0; i < 2; i++)
        #pragma unroll
        for (int j = 0; j < 2; j++) acc[i][j] = (f32x4){0.f, 0.f, 0.f, 0.f};

    int sr = tid >> 2, cg = tid & 3;
    for (int k0 = 0; k0 < 1024; k0 += 32) {
        int m = m0 + sr;
        float4 av = make_float4(0.f, 0.f, 0.f, 0.f);
        if (m < MROWS)
            av = *(const float4*)(A + (size_t)m * 1024 + k0 + cg * 8);
        *(float4*)(&As[sr * 40 + cg * 8]) = av;
        float4 wv4 = *(const float4*)(W + (size_t)(n0 + sr) * 1024 + k0 + cg * 8);
        *(float4*)(&Bs[sr * 40 + cg * 8]) = wv4;
        __syncthreads();
        bf16x8 af[2], bf[2];
        #pragma unroll
        for (int fr = 0; fr < 2; fr++)
            af[fr] = *(const bf16x8*)(&As[(wr * 32 + fr * 16 + fl) * 40 + kg * 8]);
        #pragma unroll
        for (int fc = 0; fc < 2; fc++)
            bf[fc] = *(const bf16x8*)(&Bs[(wc * 32 + fc * 16 + fl) * 40 + kg * 8]);
        #pragma unroll
        for (int fr = 0; fr < 2; fr++)
            #pragma unroll
            for (int fc = 0; fc < 2; fc++)
                acc[fr][fc] = __builtin_amdgcn_mfma_f32_16x16x32_bf16(
                    af[fr], bf[fc], acc[fr][fc], 0, 0, 0);
        __syncthreads();
    }
    #pragma unroll
    for (int fr = 0; fr < 2; fr++)
        #pragma unroll
        for (int fc = 0; fc < 2; fc++)
            #pragma unroll
            for (int j = 0; j < 4; j++) {
                int m = m0 + wr * 32 + fr * 16 + kg * 4 + j;
                if (m < MROWS) {
                    int n = n0 + wc * 32 + fc * 16 + fl;
                    P[(size_t)m * 512 + n] = acc[fr][fc][j];
                }
            }
}

// out[m] = 2x[m] + pf[m] + pb[flip(m)]
__global__ __launch_bounds__(256)
void reduce_out_k(const float* __restrict__ x, const float* __restrict__ partial,
                  float* __restrict__ out)
{
    int idx = blockIdx.x * 256 + threadIdx.x;
    if (idx >= MROWS * 128) return;
    int m = idx >> 7, q = idx & 127;
    int b = m / LL, t = m % LL;
    int fm = b * LL + (LL - 1 - t);
    const float* p0 = partial;
    const float* p1 = partial + (size_t)MROWS * 512;
    float4 xv = *(const float4*)(x  + (size_t)m  * 512 + q * 4);
    float4 a  = *(const float4*)(p0 + (size_t)m  * 512 + q * 4);
    float4 c  = *(const float4*)(p1 + (size_t)fm * 512 + q * 4);
    float4 o;
    o.x = 2.f * xv.x + a.x + c.x;
    o.y = 2.f * xv.y + a.y + c.y;
    o.z = 2.f * xv.z + a.z + c.z;
    o.w = 2.f * xv.w + a.w + c.w;
    *(float4*)(out + (size_t)m * 512 + q * 4) = o;
}

// ------------------------- causal dwconv + silu -> TRANSPOSED xcT [b][d][t] --
__global__ __launch_bounds__(256)
void conv_silu_k(const float* __restrict__ xz0, const float* __restrict__ xz1,
                 const float* __restrict__ cw0, const float* __restrict__ cw1,
                 const float* __restrict__ cb0, const float* __restrict__ cb1,
                 float* __restrict__ xcT0, float* __restrict__ xcT1)
{
    __shared__ float Ls[64 * 65];
    int dirb = blockIdx.z;
    int dir = dirb >> 1, b = dirb & 1;
    int d0 = blockIdx.x * 64, t0 = blockIdx.y * 64;
    int tid = threadIdx.x;
    int dl = tid & 63, tg = tid >> 6;

    const float* in = (dir ? xz1 : xz0) + (size_t)b * LL * 2048;
    const float* cw = dir ? cw1 : cw0;
    const float* cb = dir ? cb1 : cb0;
    float*      xcT = dir ? xcT1 : xcT0;

    float4 w4 = ((const float4*)cw)[d0 + dl];
    float bias = cb[d0 + dl];

    int ts = t0 + tg * 16;
    float x3 = 0.f, x2 = 0.f, x1 = 0.f;
    if (ts - 3 >= 0 && ts - 3 < LL) x3 = in[(size_t)(ts - 3) * 2048 + d0 + dl];
    if (ts - 2 >= 0 && ts - 2 < LL) x2 = in[(size_t)(ts - 2) * 2048 + d0 + dl];
    if (ts - 1 >= 0 && ts - 1 < LL) x1 = in[(size_t)(ts - 1) * 2048 + d0 + dl];

    #pragma unroll
    for (int i = 0; i < 16; i++) {
        int t = ts + i;
        float x0v = (t < LL) ? in[(size_t)t * 2048 + d0 + dl] : 0.f;
        float a = bias + x3 * w4.x + x2 * w4.y + x1 * w4.z + x0v * w4.w;
        float s = a / (1.f + __expf(-a));
        Ls[dl * 65 + tg * 16 + i] = s;
        x3 = x2; x2 = x1; x1 = x0v;
    }
    __syncthreads();
    int tl = tid & 63, dg = tid >> 6;
    #pragma unroll
    for (int i = 0; i < 16; i++) {
        int dd = dg * 16 + i;
        int t = t0 + tl;
        if (t < LL)
            xcT[((size_t)(b * 1024) + d0 + dd) * LL + t] = Ls[dd * 65 + tl];
    }
}

// --------------------- x_proj GEMM + BCT transposed epilogue ----------------
__global__ __launch_bounds__(256)
void gemm_xp_k(const float* __restrict__ xcT0, const float* __restrict__ xcT1,
               const float* __restrict__ xp0, const float* __restrict__ xp1,
               float* __restrict__ xd0, float* __restrict__ xd1,
               float* __restrict__ bct)
{
    __shared__ float As[16 * 68];   // [k][m=t]
    __shared__ float Ws[16 * 68];   // [k][n]
    __shared__ float T[64 * 67];    // [n][m] transposed staging
    int dirb = blockIdx.z;
    int dir = dirb >> 1, b = dirb & 1;
    const float* xcT = (dir ? xcT1 : xcT0) + (size_t)b * 1024 * LL;
    const float* W   = dir ? xp1 : xp0;     // (160,1024)
    float*       C   = (dir ? xd1 : xd0) + (size_t)b * LL * 160;
    int n0 = blockIdx.x * 64, t0 = blockIdx.y * 64;
    int tid = threadIdx.x;
    int tx = tid & 15, ty = tid >> 4;

    float acc[4][4] = {};

    for (int k0 = 0; k0 < 1024; k0 += 16) {
        {
            int kk = tid & 15, mq = tid >> 4;
            float4 v = make_float4(0.f, 0.f, 0.f, 0.f);
            if (t0 + mq * 4 + 3 < LL)
                v = *(const float4*)(xcT + (size_t)(k0 + kk) * LL + t0 + mq * 4);
            *(float4*)(As + kk * 68 + mq * 4) = v;
        }
        {
            int row = tid >> 2, q = tid & 3;
            float4 v = make_float4(0.f, 0.f, 0.f, 0.f);
            if (n0 + row < 160)
                v = *(const float4*)(W + (size_t)(n0 + row) * 1024 + k0 + q * 4);
            Ws[(q * 4 + 0) * 68 + row] = v.x;
            Ws[(q * 4 + 1) * 68 + row] = v.y;
            Ws[(q * 4 + 2) * 68 + row] = v.z;
            Ws[(q * 4 + 3) * 68 + row] = v.w;
        }
        __syncthreads();
        #pragma unroll
        for (int k = 0; k < 16; k++) {
            float4 a = *(const float4*)(As + k * 68 + ty * 4);
            float4 w = *(const float4*)(Ws + k * 68 + tx * 4);
            float av[4] = {a.x, a.y, a.z, a.w};
            float wvv[4] = {w.x, w.y, w.z, w.w};
            #pragma unroll
            for (int i = 0; i < 4; i++)
                #pragma unroll
                for (int j = 0; j < 4; j++)
                    acc[i][j] = fmaf(av[i], wvv[j], acc[i][j]);
        }
        __syncthreads();
    }

    if (n0 == 0) {
        #pragma unroll
        for (int i = 0; i < 4; i++) {
            int t = t0 + ty * 4 + i;
            if (t >= LL) continue;
            #pragma unroll
            for (int j = 0; j < 4; j++) {
                int n = tx * 4 + j;
                C[(size_t)t * 160 + n] = acc[i][j];
            }
        }
    }

    #pragma unroll
    for (int i = 0; i < 4; i++)
        #pragma unroll
        for (int j = 0; j < 4; j++)
            T[(tx * 4 + j) * 67 + ty * 4 + i] = acc[i][j];
    __syncthreads();
    int tl = tid & 63, ng = tid >> 6;
    #pragma unroll
    for (int i = 0; i < 16; i++) {
        int nl = ng * 16 + i;
        int n = n0 + nl;
        int t = t0 + tl;
        if (n >= 32 && n < 160 && t < LL)
            bct[((size_t)dirb * 128 + (n - 32)) * LL + t] = T[nl * 67 + tl];
    }
}

// ---- dt GEMM (K=32) + softplus, output TRANSPOSED dtT [b][d][t] ------------
__global__ __launch_bounds__(256)
void gemm_dt_k(const float* __restrict__ xd0, const float* __restrict__ xd1,
               const float* __restrict__ w0, const float* __restrict__ w1,
               const float* __restrict__ bb0, const float* __restrict__ bb1,
               float* __restrict__ dtT0, float* __restrict__ dtT1)
{
    __shared__ float As[64 * 33];
    __shared__ float Ws[32 * 68];
    __shared__ float T[64 * 67];
    int dirb = blockIdx.z;
    int dir = dirb >> 1, b = dirb & 1;
    const float* xd = (dir ? xd1 : xd0) + (size_t)b * LL * 160;
    const float* W  = dir ? w1 : w0;
    const float* bi = dir ? bb1 : bb0;
    float*      dtT = (dir ? dtT1 : dtT0) + (size_t)b * 1024 * LL;
    int n0 = blockIdx.x * 64, t0 = blockIdx.y * 64;
    int tid = threadIdx.x;
    int tx = tid & 15, ty = tid >> 4;

    #pragma unroll
    for (int i = 0; i < 2; i++) {
        int j = tid + 256 * i;
        int row = j >> 3, q = j & 7;
        float4 v = make_float4(0.f, 0.f, 0.f, 0.f);
        if (t0 + row < LL)
            v = *(const float4*)(xd + (size_t)(t0 + row) * 160 + q * 4);
        As[row * 33 + q * 4 + 0] = v.x;
        As[row * 33 + q * 4 + 1] = v.y;
        As[row * 33 + q * 4 + 2] = v.z;
        As[row * 33 + q * 4 + 3] = v.w;
        float4 wv = *(const float4*)(W + (size_t)(n0 + row) * 32 + q * 4);
        Ws[(q * 4 + 0) * 68 + row] = wv.x;
        Ws[(q * 4 + 1) * 68 + row] = wv.y;
        Ws[(q * 4 + 2) * 68 + row] = wv.z;
        Ws[(q * 4 + 3) * 68 + row] = wv.w;
    }
    __syncthreads();

    float acc[4][4] = {};
    #pragma unroll 8
    for (int k = 0; k < 32; k++) {
        float4 w = *(const float4*)(Ws + k * 68 + tx * 4);
        float wvv[4] = {w.x, w.y, w.z, w.w};
        float av[4];
        #pragma unroll
        for (int i = 0; i < 4; i++) av[i] = As[(ty * 4 + i) * 33 + k];
        #pragma unroll
        for (int i = 0; i < 4; i++)
            #pragma unroll
            for (int j = 0; j < 4; j++)
                acc[i][j] = fmaf(av[i], wvv[j], acc[i][j]);
    }
    __syncthreads();

    #pragma unroll
    for (int i = 0; i < 4; i++) {
        #pragma unroll
        for (int j = 0; j < 4; j++) {
            int n = tx * 4 + j;
            float v = acc[i][j] + bi[n0 + n];
            v = (v > 20.f) ? v : log1pf(__expf(v));
            T[n * 67 + ty * 4 + i] = v;
        }
    }
    __syncthreads();

    int tl = tid & 63, ng = tid >> 6;
    #pragma unroll
    for (int i = 0; i < 16; i++) {
        int nl = ng * 16 + i;
        int t = t0 + tl;
        if (t < LL)
            dtT[(size_t)(n0 + nl) * LL + t] = T[nl * 67 + tl];
    }
}

// ------------------------------------------------------------ selective scan
// 32-timestep B/C tiles -> LDS 33.5 KB -> 4 blocks/CU (all 1024 blocks
// co-resident, single pass). Inner structure unchanged from r6.
__global__ __launch_bounds__(256)
void scan_k(float* __restrict__ dtT0, float* __restrict__ dtT1,
            const float* __restrict__ ucT0, const float* __restrict__ ucT1,
            const float* __restrict__ bct,
            const float* __restrict__ Al0, const float* __restrict__ Al1,
            const float* __restrict__ Dc0, const float* __restrict__ Dc1)
{
    __shared__ float Bs[64 * 34];
    __shared__ float Cs[64 * 34];
    __shared__ float Pt[4][16 * 66];
    int dirb = blockIdx.y;
    int dir = dirb >> 1, b = dirb & 1;
    int wid = threadIdx.x >> 6, lane = threadIdx.x & 63;
    int d = blockIdx.x * 4 + wid;
    float* Pw = Pt[wid];

    float*       dtT = (dir ? dtT1 : dtT0);
    const float* ucT = (dir ? ucT1 : ucT0);
    const float* Al  = dir ? Al1 : Al0;
    const float* Dc  = dir ? Dc1 : Dc0;

    float a    = -__expf(Al[d * 64 + lane]) * 1.44269504f;
    float Dp64 = Dc[d] * (1.f / 64.f);
    float h    = 0.f;
    size_t chan = ((size_t)(b * 1024 + d)) * LL;
    const float* Bg = bct + (size_t)dirb * 128 * LL;   // rows 0..63=B, 64..127=C

    int srow = threadIdx.x >> 2;          // 0..63
    int scol = (threadIdx.x & 3) * 8;     // 0,8,16,24
    int tl16 = lane & 15, qq = lane >> 4;
    const float* Prow = Pw + tl16 * 66 + qq * 16;

    for (int t0 = 0; t0 < LL; t0 += 32) {
        int rem = min(32, LL - t0);
        __syncthreads();
        // cooperative stage: B/C tile [n=64][t=32] (tail overread stays in d_out)
        {
            float4 b0 = *(const float4*)(Bg + (size_t)srow * LL + t0 + scol);
            float4 b1 = *(const float4*)(Bg + (size_t)srow * LL + t0 + scol + 4);
            float4 c0 = *(const float4*)(Bg + (size_t)(srow + 64) * LL + t0 + scol);
            float4 c1 = *(const float4*)(Bg + (size_t)(srow + 64) * LL + t0 + scol + 4);
            *(float4*)(&Bs[srow * 34 + scol])     = b0;
            *(float4*)(&Bs[srow * 34 + scol + 4]) = b1;
            *(float4*)(&Cs[srow * 34 + scol])     = c0;
            *(float4*)(&Cs[srow * 34 + scol + 4]) = c1;
        }
        float dta = 0.f, ua = 0.f;
        if (lane < rem) {
            dta = dtT[chan + t0 + lane];
            ua  = ucT[chan + t0 + lane];
        }
        __syncthreads();

        for (int sec = 0; sec < 2; sec++) {
            int sbase = sec * 16;
            int steps = rem - sbase;
            if (steps <= 0) break;
            if (steps > 16) steps = 16;
            if (steps < 16) {               // zero stale tail rows (rare)
                for (int i = steps; i < 16; i++) Pw[i * 66 + lane] = 0.f;
            }
            int ngr = (steps + 7) >> 3;     // 1 or 2 groups of 8
            for (int g = 0; g < ngr; g++) {
                int tb = sbase + g * 8;
                float4 B0 = *(const float4*)(&Bs[lane * 34 + tb]);
                float4 B1 = *(const float4*)(&Bs[lane * 34 + tb + 4]);
                float4 C0 = *(const float4*)(&Cs[lane * 34 + tb]);
                float4 C1 = *(const float4*)(&Cs[lane * 34 + tb + 4]);
                #pragma unroll
                for (int i = 0; i < 8; i++) {
                    float dtv = bcast_lane(dta, tb + i);
                    float u   = bcast_lane(ua,  tb + i);
                    float dA  = exp2f(dtv * a);
                    float Bn  = (i < 4) ? B0[i] : B1[i - 4];
                    float Cn  = (i < 4) ? C0[i] : C1[i - 4];
                    h = fmaf(dA, h, dtv * u * Bn);
                    Pw[(g * 8 + i) * 66 + lane] = fmaf(u, Dp64, h * Cn);
                }
            }
            // transpose-sum: lane (qq,tl16) sums 16 of row tl16
            float s = 0.f;
            #pragma unroll
            for (int j = 0; j < 8; j++) {
                float2 v = *(const float2*)(Prow + j * 2);
                s += v.x + v.y;
            }
#if __has_builtin(__builtin_amdgcn_permlane32_swap)
            {
                unsigned aa = __builtin_bit_cast(unsigned, s);
                auto r = __builtin_amdgcn_permlane32_swap(aa, aa, false, false);
                s = __builtin_bit_cast(float, (unsigned)r[0]) +
                    __builtin_bit_cast(float, (unsigned)r[1]);
            }
#else
            s += __shfl_xor(s, 32, 64);
#endif
#if __has_builtin(__builtin_amdgcn_permlane16_swap)
            {
                unsigned aa = __builtin_bit_cast(unsigned, s);
                auto r = __builtin_amdgcn_permlane16_swap(aa, aa, false, false);
                s = __builtin_bit_cast(float, (unsigned)r[0]) +
                    __builtin_bit_cast(float, (unsigned)r[1]);
            }
#else
            s += __shfl_xor(s, 16, 64);
#endif
            if (lane < steps)
                dtT[chan + t0 + sbase + lane] = s;
        }
    }
}

// ------- gate: ygb[t][d] = bf16( yT[d][t] * silu(z[t][1024+d]) ) ------------
__global__ __launch_bounds__(256)
void gate_k(const float* __restrict__ yT0, const float* __restrict__ yT1,
            const float* __restrict__ xz0, const float* __restrict__ xz1,
            unsigned short* __restrict__ yg0, unsigned short* __restrict__ yg1)
{
    __shared__ float Ls[64 * 65];
    int dirb = blockIdx.z;
    int dir = dirb >> 1, b = dirb & 1;
    int d0 = blockIdx.x * 64, t0 = blockIdx.y * 64;
    int tid = threadIdx.x;
    const float* yT = (dir ? yT1 : yT0) + (size_t)b * 1024 * LL;
    const float* xz = (dir ? xz1 : xz0) + (size_t)b * LL * 2048;
    unsigned short* yg = dir ? yg1 : yg0;

    int tl = tid & 63, dg = tid >> 6;
    #pragma unroll
    for (int i = 0; i < 16; i++) {
        int dd = dg * 16 + i;
        int t = t0 + tl;
        float v = (t < LL) ? yT[(size_t)(d0 + dd) * LL + t] : 0.f;
        Ls[dd * 65 + tl] = v;
    }
    __syncthreads();
    int dcol = tid & 63, tg = tid >> 6;
    #pragma unroll
    for (int i = 0; i < 16; i++) {
        int t = t0 + tg * 16 + i;
        if (t >= LL) continue;
        float z = xz[(size_t)t * 2048 + 1024 + d0 + dcol];
        float y = Ls[dcol * 65 + tg * 16 + i];
        float s = z / (1.f + __expf(-z));
        yg[((size_t)(b * LL + t)) * 1024 + d0 + dcol] = f2bf(y * s);
    }
}

// -------------------------------------------------------------------- launch
extern "C" void kernel_launch(void* const* d_in, const int* in_sizes, int n_in,
                              void* d_out, int out_size, void* d_ws, size_t ws_size,
                              hipStream_t stream) {
    const float* x = (const float*)d_in[0];
    const float* P[2][10];
    for (int dir = 0; dir < 2; dir++)
        for (int i = 0; i < 10; i++)
            P[dir][i] = (const float*)d_in[1 + dir * 10 + i];

    float* ws = (float*)d_ws;
    float* xz0   = ws;                    // 4,096,000
    float* xz1   = ws + 4096000;          // 4,096,000
    float* xcT0  = ws + 8192000;          // 2,048,000
    float* xcT1  = ws + 10240000;         // 2,048,000
    float* dtT0  = ws + 12288000;         // 2,048,000
    float* dtT1  = ws + 14336000;         // 2,048,000
    float* xdbl0 = ws + 16384000;         //   320,000
    float* xdbl1 = ws + 16704000;         //   320,000
    unsigned short* xnb0 = (unsigned short*)(ws + 17024000);  // 256,000 fl
    unsigned short* xnb1 = (unsigned short*)(ws + 17280000);  // 256,000 fl
    // aliases (lifetimes disjoint, stream-ordered):
    unsigned short* wib0 = (unsigned short*)dtT0;   // dead once gemm_dt writes
    unsigned short* wib1 = (unsigned short*)dtT1;
    unsigned short* ygb0 = (unsigned short*)xcT0;   // xcT dead after scan
    unsigned short* ygb1 = (unsigned short*)xcT1;
    unsigned short* wob0 = (unsigned short*)dtT0;   // dtT dead after gate
    unsigned short* wob1 = (unsigned short*)dtT1;
    float* partial = xz0;                           // xz dead after gate
    float* bct = (float*)d_out;                     // BCT scratch lives in d_out
    float* out = (float*)d_out;

    rmsnorm_k<<<MROWS, 256, 0, stream>>>(x, P[0][0], P[1][0], xnb0, xnb1);

    cvt2_k<<<dim3(1024, 2), 256, 0, stream>>>(P[0][1], P[1][1], wib0, wib1, 262144);

    gemm1_mfma<<<dim3(16, 16, 2), 256, 0, stream>>>(
        xnb0, xnb1, wib0, wib1, xz0, xz1);

    conv_silu_k<<<dim3(16, 16, 4), 256, 0, stream>>>(
        xz0, xz1, P[0][2], P[1][2], P[0][3], P[1][3], xcT0, xcT1);

    gemm_xp_k<<<dim3(3, 16, 4), 256, 0, stream>>>(
        xcT0, xcT1, P[0][4], P[1][4], xdbl0, xdbl1, bct);

    gemm_dt_k<<<dim3(16, 16, 4), 256, 0, stream>>>(
        xdbl0, xdbl1, P[0][5], P[1][5], P[0][6], P[1][6], dtT0, dtT1);

    scan_k<<<dim3(256, 4), 256, 0, stream>>>(
        dtT0, dtT1, xcT0, xcT1, bct,
        P[0][7], P[1][7], P[0][8], P[1][8]);

    gate_k<<<dim3(16, 16, 4), 256, 0, stream>>>(
        dtT0, dtT1, xz0, xz1, ygb0, ygb1);

    cvt2_k<<<dim3(512, 2), 256, 0, stream>>>(P[0][9], P[1][9], wob0, wob1, 131072);

    gemm_out_mfma<<<dim3(8, 32, 2), 256, 0, stream>>>(
        ygb0, ygb1, wob0, wob1, partial);

    reduce_out_k<<<1000, 256, 0, stream>>>(x, partial, out);
}

// Round 8
// 315.963 us; speedup vs baseline: 4.0467x; 1.0605x over previous
//
#include <hip/hip_runtime.h>
#include <hip/hip_bf16.h>
#include <math.h>

#define DM   512
#define DI   1024
#define NS   64
#define RDT  32
#define BB   2
#define LL   1000
#define MROWS (BB*LL)   // 2000

typedef __attribute__((ext_vector_type(8))) short bf16x8;
typedef __attribute__((ext_vector_type(4))) float f32x4;

// f32 -> bf16 RNE (finite inputs)
__device__ __forceinline__ unsigned short f2bf(float f) {
    unsigned u = __builtin_bit_cast(unsigned, f);
    u = (u + 0x7FFF + ((u >> 16) & 1)) >> 16;
    return (unsigned short)u;
}

__device__ __forceinline__ float bcast_lane(float v, int lane) {
    return __builtin_bit_cast(float,
        __builtin_amdgcn_readlane(__builtin_bit_cast(int, v), lane));
}

// ------------------- rmsnorm -> per-dir bf16 (norm_w folded) ----------------
__global__ __launch_bounds__(256)
void rmsnorm_k(const float* __restrict__ x,
               const float* __restrict__ nw0, const float* __restrict__ nw1,
               unsigned short* __restrict__ xnb0, unsigned short* __restrict__ xnb1) {
    int row = blockIdx.x;
    int tid = threadIdx.x;
    const float* xr = x + (size_t)row * DM;
    float2 v = *(const float2*)(xr + tid * 2);
    float ss = v.x * v.x + v.y * v.y;
    #pragma unroll
    for (int off = 32; off; off >>= 1) ss += __shfl_xor(ss, off, 64);
    __shared__ float red[4];
    if ((tid & 63) == 0) red[tid >> 6] = ss;
    __syncthreads();
    float tot = red[0] + red[1] + red[2] + red[3];
    float scale = rsqrtf(tot / (float)DM + 1e-5f);
    float2 w0 = *(const float2*)(nw0 + tid * 2);
    float2 w1 = *(const float2*)(nw1 + tid * 2);
    short2 o0, o1;
    o0.x = (short)f2bf(v.x * scale * w0.x);
    o0.y = (short)f2bf(v.y * scale * w0.y);
    o1.x = (short)f2bf(v.x * scale * w1.x);
    o1.y = (short)f2bf(v.y * scale * w1.y);
    *(short2*)(xnb0 + (size_t)row * DM + tid * 2) = o0;
    *(short2*)(xnb1 + (size_t)row * DM + tid * 2) = o1;
}

// ------------------------------------ f32 -> bf16 convert, 2 arrays batched --
__global__ __launch_bounds__(256)
void cvt2_k(const float* __restrict__ in0, const float* __restrict__ in1,
            unsigned short* __restrict__ out0, unsigned short* __restrict__ out1,
            int n4) {
    int idx = blockIdx.x * 256 + threadIdx.x;
    if (idx >= n4) return;
    const float* in = blockIdx.y ? in1 : in0;
    unsigned short* out = blockIdx.y ? out1 : out0;
    float4 v = *(const float4*)(in + (size_t)idx * 4);
    short4 o;
    o.x = (short)f2bf(v.x); o.y = (short)f2bf(v.y);
    o.z = (short)f2bf(v.z); o.w = (short)f2bf(v.w);
    *(short4*)(out + (size_t)idx * 4) = o;
}

// ------------- GEMM1 (in_proj) bf16 MFMA: xz[dir] = xn_dir @ W^T ------------
__global__ __launch_bounds__(256, 2)
void gemm1_mfma(const unsigned short* __restrict__ xnb0,
                const unsigned short* __restrict__ xnb1,
                const unsigned short* __restrict__ wib0,
                const unsigned short* __restrict__ wib1,
                float* __restrict__ xz0, float* __restrict__ xz1)
{
    __shared__ __align__(16) unsigned short As[128 * 40];
    __shared__ __align__(16) unsigned short Bs[128 * 40];
    int dir = blockIdx.z;
    const unsigned short* A = dir ? xnb1 : xnb0;
    const unsigned short* W = dir ? wib1 : wib0;
    float* C = dir ? xz1 : xz0;
    int n0 = blockIdx.x * 128, m0 = blockIdx.y * 128;
    int tid = threadIdx.x;
    int wv = tid >> 6, lane = tid & 63;
    int wr = wv >> 1, wc = wv & 1;
    int fl = lane & 15, kg = lane >> 4;

    f32x4 acc[4][4];
    #pragma unroll
    for (int i = 0; i < 4; i++)
        #pragma unroll
        for (int j = 0; j < 4; j++) acc[i][j] = (f32x4){0.f, 0.f, 0.f, 0.f};

    int sr = tid >> 2, cg = tid & 3;
    for (int k0 = 0; k0 < 512; k0 += 32) {
        #pragma unroll
        for (int i = 0; i < 2; i++) {
            int row = sr + i * 64;
            int m = m0 + row;
            float4 av = make_float4(0.f, 0.f, 0.f, 0.f);
            if (m < MROWS) {
                int rs = m;
                if (dir) { int b = m / LL, t = m % LL; rs = b * LL + (LL - 1 - t); }
                av = *(const float4*)(A + (size_t)rs * 512 + k0 + cg * 8);
            }
            *(float4*)(&As[row * 40 + cg * 8]) = av;
            float4 wv4 = *(const float4*)(W + (size_t)(n0 + row) * 512 + k0 + cg * 8);
            *(float4*)(&Bs[row * 40 + cg * 8]) = wv4;
        }
        __syncthreads();
        bf16x8 af[4], bf[4];
        #pragma unroll
        for (int fr = 0; fr < 4; fr++)
            af[fr] = *(const bf16x8*)(&As[(wr * 64 + fr * 16 + fl) * 40 + kg * 8]);
        #pragma unroll
        for (int fc = 0; fc < 4; fc++)
            bf[fc] = *(const bf16x8*)(&Bs[(wc * 64 + fc * 16 + fl) * 40 + kg * 8]);
        #pragma unroll
        for (int fr = 0; fr < 4; fr++)
            #pragma unroll
            for (int fc = 0; fc < 4; fc++)
                acc[fr][fc] = __builtin_amdgcn_mfma_f32_16x16x32_bf16(
                    af[fr], bf[fc], acc[fr][fc], 0, 0, 0);
        __syncthreads();
    }
    #pragma unroll
    for (int fr = 0; fr < 4; fr++)
        #pragma unroll
        for (int fc = 0; fc < 4; fc++)
            #pragma unroll
            for (int j = 0; j < 4; j++) {
                int m = m0 + wr * 64 + fr * 16 + kg * 4 + j;
                if (m < MROWS) {
                    int n = n0 + wc * 64 + fc * 16 + fl;
                    C[(size_t)m * 2048 + n] = acc[fr][fc][j];
                }
            }
}

// -------- out_proj bf16 MFMA, full K, per-dir -> f32 partials ---------------
__global__ __launch_bounds__(256, 2)
void gemm_out_mfma(const unsigned short* __restrict__ ygb0,
                   const unsigned short* __restrict__ ygb1,
                   const unsigned short* __restrict__ wob0,
                   const unsigned short* __restrict__ wob1,
                   float* __restrict__ partial)
{
    __shared__ __align__(16) unsigned short As[64 * 40];
    __shared__ __align__(16) unsigned short Bs[64 * 40];
    int dir = blockIdx.z;
    const unsigned short* A = dir ? ygb1 : ygb0;
    const unsigned short* W = dir ? wob1 : wob0;
    float* P = partial + (size_t)dir * MROWS * 512;
    int n0 = blockIdx.x * 64, m0 = blockIdx.y * 64;
    int tid = threadIdx.x;
    int wv = tid >> 6, lane = tid & 63;
    int wr = wv >> 1, wc = wv & 1;
    int fl = lane & 15, kg = lane >> 4;

    f32x4 acc[2][2];
    #pragma unroll
    for (int i = 0; i < 2; i++)
        #pragma unroll
        for (int j = 0; j < 2; j++) acc[i][j] = (f32x4){0.f, 0.f, 0.f, 0.f};

    int sr = tid >> 2, cg = tid & 3;
    for (int k0 = 0; k0 < 1024; k0 += 32) {
        int m = m0 + sr;
        float4 av = make_float4(0.f, 0.f, 0.f, 0.f);
        if (m < MROWS)
            av = *(const float4*)(A + (size_t)m * 1024 + k0 + cg * 8);
        *(float4*)(&As[sr * 40 + cg * 8]) = av;
        float4 wv4 = *(const float4*)(W + (size_t)(n0 + sr) * 1024 + k0 + cg * 8);
        *(float4*)(&Bs[sr * 40 + cg * 8]) = wv4;
        __syncthreads();
        bf16x8 af[2], bf[2];
        #pragma unroll
        for (int fr = 0; fr < 2; fr++)
            af[fr] = *(const bf16x8*)(&As[(wr * 32 + fr * 16 + fl) * 40 + kg * 8]);
        #pragma unroll
        for (int fc = 0; fc < 2; fc++)
            bf[fc] = *(const bf16x8*)(&Bs[(wc * 32 + fc * 16 + fl) * 40 + kg * 8]);
        #pragma unroll
        for (int fr = 0; fr < 2; fr++)
            #pragma unroll
            for (int fc = 0; fc < 2; fc++)
                acc[fr][fc] = __builtin_amdgcn_mfma_f32_16x16x32_bf16(
                    af[fr], bf[fc], acc[fr][fc], 0, 0, 0);
        __syncthreads();
    }
    #pragma unroll
    for (int fr = 0; fr < 2; fr++)
        #pragma unroll
        for (int fc = 0; fc < 2; fc++)
            #pragma unroll
            for (int j = 0; j < 4; j++) {
                int m = m0 + wr * 32 + fr * 16 + kg * 4 + j;
                if (m < MROWS) {
                    int n = n0 + wc * 32 + fc * 16 + fl;
                    P[(size_t)m * 512 + n] = acc[fr][fc][j];
                }
            }
}

// out[m] = 2x[m] + pf[m] + pb[flip(m)]
__global__ __launch_bounds__(256)
void reduce_out_k(const float* __restrict__ x, const float* __restrict__ partial,
                  float* __restrict__ out)
{
    int idx = blockIdx.x * 256 + threadIdx.x;
    if (idx >= MROWS * 128) return;
    int m = idx >> 7, q = idx & 127;
    int b = m / LL, t = m % LL;
    int fm = b * LL + (LL - 1 - t);
    const float* p0 = partial;
    const float* p1 = partial + (size_t)MROWS * 512;
    float4 xv = *(const float4*)(x  + (size_t)m  * 512 + q * 4);
    float4 a  = *(const float4*)(p0 + (size_t)m  * 512 + q * 4);
    float4 c  = *(const float4*)(p1 + (size_t)fm * 512 + q * 4);
    float4 o;
    o.x = 2.f * xv.x + a.x + c.x;
    o.y = 2.f * xv.y + a.y + c.y;
    o.z = 2.f * xv.z + a.z + c.z;
    o.w = 2.f * xv.w + a.w + c.w;
    *(float4*)(out + (size_t)m * 512 + q * 4) = o;
}

// ------------------------- causal dwconv + silu -> TRANSPOSED xcT [b][d][t] --
__global__ __launch_bounds__(256)
void conv_silu_k(const float* __restrict__ xz0, const float* __restrict__ xz1,
                 const float* __restrict__ cw0, const float* __restrict__ cw1,
                 const float* __restrict__ cb0, const float* __restrict__ cb1,
                 float* __restrict__ xcT0, float* __restrict__ xcT1)
{
    __shared__ float Ls[64 * 65];
    int dirb = blockIdx.z;
    int dir = dirb >> 1, b = dirb & 1;
    int d0 = blockIdx.x * 64, t0 = blockIdx.y * 64;
    int tid = threadIdx.x;
    int dl = tid & 63, tg = tid >> 6;

    const float* in = (dir ? xz1 : xz0) + (size_t)b * LL * 2048;
    const float* cw = dir ? cw1 : cw0;
    const float* cb = dir ? cb1 : cb0;
    float*      xcT = dir ? xcT1 : xcT0;

    float4 w4 = ((const float4*)cw)[d0 + dl];
    float bias = cb[d0 + dl];

    int ts = t0 + tg * 16;
    float x3 = 0.f, x2 = 0.f, x1 = 0.f;
    if (ts - 3 >= 0 && ts - 3 < LL) x3 = in[(size_t)(ts - 3) * 2048 + d0 + dl];
    if (ts - 2 >= 0 && ts - 2 < LL) x2 = in[(size_t)(ts - 2) * 2048 + d0 + dl];
    if (ts - 1 >= 0 && ts - 1 < LL) x1 = in[(size_t)(ts - 1) * 2048 + d0 + dl];

    #pragma unroll
    for (int i = 0; i < 16; i++) {
        int t = ts + i;
        float x0v = (t < LL) ? in[(size_t)t * 2048 + d0 + dl] : 0.f;
        float a = bias + x3 * w4.x + x2 * w4.y + x1 * w4.z + x0v * w4.w;
        float s = a / (1.f + __expf(-a));
        Ls[dl * 65 + tg * 16 + i] = s;
        x3 = x2; x2 = x1; x1 = x0v;
    }
    __syncthreads();
    int tl = tid & 63, dg = tid >> 6;
    #pragma unroll
    for (int i = 0; i < 16; i++) {
        int dd = dg * 16 + i;
        int t = t0 + tl;
        if (t < LL)
            xcT[((size_t)(b * 1024) + d0 + dd) * LL + t] = Ls[dd * 65 + tl];
    }
}

// --------------------- x_proj GEMM + BCT transposed epilogue ----------------
__global__ __launch_bounds__(256)
void gemm_xp_k(const float* __restrict__ xcT0, const float* __restrict__ xcT1,
               const float* __restrict__ xp0, const float* __restrict__ xp1,
               float* __restrict__ xd0, float* __restrict__ xd1,
               float* __restrict__ bct)
{
    __shared__ float As[16 * 68];   // [k][m=t]
    __shared__ float Ws[16 * 68];   // [k][n]
    __shared__ float T[64 * 67];    // [n][m] transposed staging
    int dirb = blockIdx.z;
    int dir = dirb >> 1, b = dirb & 1;
    const float* xcT = (dir ? xcT1 : xcT0) + (size_t)b * 1024 * LL;
    const float* W   = dir ? xp1 : xp0;     // (160,1024)
    float*       C   = (dir ? xd1 : xd0) + (size_t)b * LL * 160;
    int n0 = blockIdx.x * 64, t0 = blockIdx.y * 64;
    int tid = threadIdx.x;
    int tx = tid & 15, ty = tid >> 4;

    float acc[4][4] = {};

    for (int k0 = 0; k0 < 1024; k0 += 16) {
        {
            int kk = tid & 15, mq = tid >> 4;
            float4 v = make_float4(0.f, 0.f, 0.f, 0.f);
            if (t0 + mq * 4 + 3 < LL)
                v = *(const float4*)(xcT + (size_t)(k0 + kk) * LL + t0 + mq * 4);
            *(float4*)(As + kk * 68 + mq * 4) = v;
        }
        {
            int row = tid >> 2, q = tid & 3;
            float4 v = make_float4(0.f, 0.f, 0.f, 0.f);
            if (n0 + row < 160)
                v = *(const float4*)(W + (size_t)(n0 + row) * 1024 + k0 + q * 4);
            Ws[(q * 4 + 0) * 68 + row] = v.x;
            Ws[(q * 4 + 1) * 68 + row] = v.y;
            Ws[(q * 4 + 2) * 68 + row] = v.z;
            Ws[(q * 4 + 3) * 68 + row] = v.w;
        }
        __syncthreads();
        #pragma unroll
        for (int k = 0; k < 16; k++) {
            float4 a = *(const float4*)(As + k * 68 + ty * 4);
            float4 w = *(const float4*)(Ws + k * 68 + tx * 4);
            float av[4] = {a.x, a.y, a.z, a.w};
            float wvv[4] = {w.x, w.y, w.z, w.w};
            #pragma unroll
            for (int i = 0; i < 4; i++)
                #pragma unroll
                for (int j = 0; j < 4; j++)
                    acc[i][j] = fmaf(av[i], wvv[j], acc[i][j]);
        }
        __syncthreads();
    }

    if (n0 == 0) {
        #pragma unroll
        for (int i = 0; i < 4; i++) {
            int t = t0 + ty * 4 + i;
            if (t >= LL) continue;
            #pragma unroll
            for (int j = 0; j < 4; j++) {
                int n = tx * 4 + j;
                C[(size_t)t * 160 + n] = acc[i][j];
            }
        }
    }

    #pragma unroll
    for (int i = 0; i < 4; i++)
        #pragma unroll
        for (int j = 0; j < 4; j++)
            T[(tx * 4 + j) * 67 + ty * 4 + i] = acc[i][j];
    __syncthreads();
    int tl = tid & 63, ng = tid >> 6;
    #pragma unroll
    for (int i = 0; i < 16; i++) {
        int nl = ng * 16 + i;
        int n = n0 + nl;
        int t = t0 + tl;
        if (n >= 32 && n < 160 && t < LL)
            bct[((size_t)dirb * 128 + (n - 32)) * LL + t] = T[nl * 67 + tl];
    }
}

// ---- dt GEMM (K=32) + softplus, output TRANSPOSED dtT [b][d][t] ------------
__global__ __launch_bounds__(256)
void gemm_dt_k(const float* __restrict__ xd0, const float* __restrict__ xd1,
               const float* __restrict__ w0, const float* __restrict__ w1,
               const float* __restrict__ bb0, const float* __restrict__ bb1,
               float* __restrict__ dtT0, float* __restrict__ dtT1)
{
    __shared__ float As[64 * 33];
    __shared__ float Ws[32 * 68];
    __shared__ float T[64 * 67];
    int dirb = blockIdx.z;
    int dir = dirb >> 1, b = dirb & 1;
    const float* xd = (dir ? xd1 : xd0) + (size_t)b * LL * 160;
    const float* W  = dir ? w1 : w0;
    const float* bi = dir ? bb1 : bb0;
    float*      dtT = (dir ? dtT1 : dtT0) + (size_t)b * 1024 * LL;
    int n0 = blockIdx.x * 64, t0 = blockIdx.y * 64;
    int tid = threadIdx.x;
    int tx = tid & 15, ty = tid >> 4;

    #pragma unroll
    for (int i = 0; i < 2; i++) {
        int j = tid + 256 * i;
        int row = j >> 3, q = j & 7;
        float4 v = make_float4(0.f, 0.f, 0.f, 0.f);
        if (t0 + row < LL)
            v = *(const float4*)(xd + (size_t)(t0 + row) * 160 + q * 4);
        As[row * 33 + q * 4 + 0] = v.x;
        As[row * 33 + q * 4 + 1] = v.y;
        As[row * 33 + q * 4 + 2] = v.z;
        As[row * 33 + q * 4 + 3] = v.w;
        float4 wv = *(const float4*)(W + (size_t)(n0 + row) * 32 + q * 4);
        Ws[(q * 4 + 0) * 68 + row] = wv.x;
        Ws[(q * 4 + 1) * 68 + row] = wv.y;
        Ws[(q * 4 + 2) * 68 + row] = wv.z;
        Ws[(q * 4 + 3) * 68 + row] = wv.w;
    }
    __syncthreads();

    float acc[4][4] = {};
    #pragma unroll 8
    for (int k = 0; k < 32; k++) {
        float4 w = *(const float4*)(Ws + k * 68 + tx * 4);
        float wvv[4] = {w.x, w.y, w.z, w.w};
        float av[4];
        #pragma unroll
        for (int i = 0; i < 4; i++) av[i] = As[(ty * 4 + i) * 33 + k];
        #pragma unroll
        for (int i = 0; i < 4; i++)
            #pragma unroll
            for (int j = 0; j < 4; j++)
                acc[i][j] = fmaf(av[i], wvv[j], acc[i][j]);
    }
    __syncthreads();

    #pragma unroll
    for (int i = 0; i < 4; i++) {
        #pragma unroll
        for (int j = 0; j < 4; j++) {
            int n = tx * 4 + j;
            float v = acc[i][j] + bi[n0 + n];
            v = (v > 20.f) ? v : log1pf(__expf(v));
            T[n * 67 + ty * 4 + i] = v;
        }
    }
    __syncthreads();

    int tl = tid & 63, ng = tid >> 6;
    #pragma unroll
    for (int i = 0; i < 16; i++) {
        int nl = ng * 16 + i;
        int t = t0 + tl;
        if (t < LL)
            dtT[(size_t)(n0 + nl) * LL + t] = T[nl * 67 + tl];
    }
}

// ------------------------------------------------------------ selective scan
// T14 async-stage: next tile's B/C + dt/u prefetched into REGISTERS during
// current tile's compute; LDS write happens at loop head (write-late).
// D-term folded post-reduce via one __shfl per 16-step section.
__global__ __launch_bounds__(256)
void scan_k(float* __restrict__ dtT0, float* __restrict__ dtT1,
            const float* __restrict__ ucT0, const float* __restrict__ ucT1,
            const float* __restrict__ bct,
            const float* __restrict__ Al0, const float* __restrict__ Al1,
            const float* __restrict__ Dc0, const float* __restrict__ Dc1)
{
    __shared__ float Bs[64 * 34];
    __shared__ float Cs[64 * 34];
    __shared__ float Pt[4][16 * 66];
    int dirb = blockIdx.y;
    int dir = dirb >> 1, b = dirb & 1;
    int wid = threadIdx.x >> 6, lane = threadIdx.x & 63;
    int d = blockIdx.x * 4 + wid;
    float* Pw = Pt[wid];

    float*       dtT = (dir ? dtT1 : dtT0);
    const float* ucT = (dir ? ucT1 : ucT0);
    const float* Al  = dir ? Al1 : Al0;
    const float* Dc  = dir ? Dc1 : Dc0;

    float a  = -__expf(Al[d * 64 + lane]) * 1.44269504f;
    float Dp = Dc[d];
    float h  = 0.f;
    size_t chan = ((size_t)(b * 1024 + d)) * LL;
    const float* Bg = bct + (size_t)dirb * 128 * LL;   // rows 0..63=B, 64..127=C

    int srow = threadIdx.x >> 2;          // 0..63
    int scol = (threadIdx.x & 3) * 8;     // 0,8,16,24
    int tl16 = lane & 15, qq = lane >> 4;
    const float* Prow = Pw + tl16 * 66 + qq * 16;

    // ---- prologue: prefetch tile 0 into regs
    float4 rb0, rb1, rc0, rc1;
    float dta = 0.f, ua = 0.f;
    {
        const float* Bp = Bg + (size_t)srow * LL + scol;
        const float* Cp = Bg + (size_t)(srow + 64) * LL + scol;
        rb0 = *(const float4*)(Bp);     rb1 = *(const float4*)(Bp + 4);
        rc0 = *(const float4*)(Cp);     rc1 = *(const float4*)(Cp + 4);
        if (lane < 32) {
            dta = dtT[chan + lane];
            ua  = ucT[chan + lane];
        }
    }

    for (int t0 = 0; t0 < LL; t0 += 32) {
        int rem = min(32, LL - t0);
        __syncthreads();                        // prev tile's LDS reads done
        *(float4*)(&Bs[srow * 34 + scol])     = rb0;
        *(float4*)(&Bs[srow * 34 + scol + 4]) = rb1;
        *(float4*)(&Cs[srow * 34 + scol])     = rc0;
        *(float4*)(&Cs[srow * 34 + scol + 4]) = rc1;
        float dcur = dta, ucur = ua;
        float wsc  = dcur * ucur;               // dt*u, valid lanes<32
        __syncthreads();                        // stage visible

        // ---- issue next tile's loads (consumed next iteration)
        if (t0 + 32 < LL) {
            const float* Bp = Bg + (size_t)srow * LL + (t0 + 32) + scol;
            const float* Cp = Bg + (size_t)(srow + 64) * LL + (t0 + 32) + scol;
            rb0 = *(const float4*)(Bp);     rb1 = *(const float4*)(Bp + 4);
            rc0 = *(const float4*)(Cp);     rc1 = *(const float4*)(Cp + 4);
            if (lane < min(32, LL - t0 - 32)) {
                dta = dtT[chan + t0 + 32 + lane];
                ua  = ucT[chan + t0 + 32 + lane];
            }
        }

        // ---- compute 32 steps (2 sections of 16)
        for (int sec = 0; sec < 2; sec++) {
            int sbase = sec * 16;
            int steps = rem - sbase;
            if (steps <= 0) break;
            if (steps > 16) steps = 16;
            if (steps < 16) {                   // zero stale tail rows (rare)
                for (int i = steps; i < 16; i++) Pw[i * 66 + lane] = 0.f;
            }
            int ngr = (steps + 7) >> 3;
            for (int g = 0; g < ngr; g++) {
                int tb = sbase + g * 8;
                float4 B0 = *(const float4*)(&Bs[lane * 34 + tb]);
                float4 B1 = *(const float4*)(&Bs[lane * 34 + tb + 4]);
                float4 C0 = *(const float4*)(&Cs[lane * 34 + tb]);
                float4 C1 = *(const float4*)(&Cs[lane * 34 + tb + 4]);
                #pragma unroll
                for (int i = 0; i < 8; i++) {
                    float dtv = bcast_lane(dcur, tb + i);
                    float w   = bcast_lane(wsc,  tb + i);
                    float dA  = exp2f(dtv * a);
                    float Bn  = (i < 4) ? B0[i] : B1[i - 4];
                    float Cn  = (i < 4) ? C0[i] : C1[i - 4];
                    h = fmaf(dA, h, w * Bn);
                    Pw[(g * 8 + i) * 66 + lane] = h * Cn;
                }
            }
            // transpose-sum: lane (qq,tl16) sums 16 of row tl16
            float s = 0.f;
            #pragma unroll
            for (int j = 0; j < 8; j++) {
                float2 v = *(const float2*)(Prow + j * 2);
                s += v.x + v.y;
            }
#if __has_builtin(__builtin_amdgcn_permlane32_swap)
            {
                unsigned aa = __builtin_bit_cast(unsigned, s);
                auto r = __builtin_amdgcn_permlane32_swap(aa, aa, false, false);
                s = __builtin_bit_cast(float, (unsigned)r[0]) +
                    __builtin_bit_cast(float, (unsigned)r[1]);
            }
#else
            s += __shfl_xor(s, 32, 64);
#endif
#if __has_builtin(__builtin_amdgcn_permlane16_swap)
            {
                unsigned aa = __builtin_bit_cast(unsigned, s);
                auto r = __builtin_amdgcn_permlane16_swap(aa, aa, false, false);
                s = __builtin_bit_cast(float, (unsigned)r[0]) +
                    __builtin_bit_cast(float, (unsigned)r[1]);
            }
#else
            s += __shfl_xor(s, 16, 64);
#endif
            // fold u*D post-reduce (u for t = sbase + (lane&15))
            float uf = __shfl(ucur, sbase + tl16, 64);
            s = fmaf(uf, Dp, s);
            if (lane < steps)
                dtT[chan + t0 + sbase + lane] = s;
        }
    }
}

// ------- gate: ygb[t][d] = bf16( yT[d][t] * silu(z[t][1024+d]) ) ------------
__global__ __launch_bounds__(256)
void gate_k(const float* __restrict__ yT0, const float* __restrict__ yT1,
            const float* __restrict__ xz0, const float* __restrict__ xz1,
            unsigned short* __restrict__ yg0, unsigned short* __restrict__ yg1)
{
    __shared__ float Ls[64 * 65];
    int dirb = blockIdx.z;
    int dir = dirb >> 1, b = dirb & 1;
    int d0 = blockIdx.x * 64, t0 = blockIdx.y * 64;
    int tid = threadIdx.x;
    const float* yT = (dir ? yT1 : yT0) + (size_t)b * 1024 * LL;
    const float* xz = (dir ? xz1 : xz0) + (size_t)b * LL * 2048;
    unsigned short* yg = dir ? yg1 : yg0;

    int tl = tid & 63, dg = tid >> 6;
    #pragma unroll
    for (int i = 0; i < 16; i++) {
        int dd = dg * 16 + i;
        int t = t0 + tl;
        float v = (t < LL) ? yT[(size_t)(d0 + dd) * LL + t] : 0.f;
        Ls[dd * 65 + tl] = v;
    }
    __syncthreads();
    int dcol = tid & 63, tg = tid >> 6;
    #pragma unroll
    for (int i = 0; i < 16; i++) {
        int t = t0 + tg * 16 + i;
        if (t >= LL) continue;
        float z = xz[(size_t)t * 2048 + 1024 + d0 + dcol];
        float y = Ls[dcol * 65 + tg * 16 + i];
        float s = z / (1.f + __expf(-z));
        yg[((size_t)(b * LL + t)) * 1024 + d0 + dcol] = f2bf(y * s);
    }
}

// -------------------------------------------------------------------- launch
extern "C" void kernel_launch(void* const* d_in, const int* in_sizes, int n_in,
                              void* d_out, int out_size, void* d_ws, size_t ws_size,
                              hipStream_t stream) {
    const float* x = (const float*)d_in[0];
    const float* P[2][10];
    for (int dir = 0; dir < 2; dir++)
        for (int i = 0; i < 10; i++)
            P[dir][i] = (const float*)d_in[1 + dir * 10 + i];

    float* ws = (float*)d_ws;
    float* xz0   = ws;                    // 4,096,000
    float* xz1   = ws + 4096000;          // 4,096,000
    float* xcT0  = ws + 8192000;          // 2,048,000
    float* xcT1  = ws + 10240000;         // 2,048,000
    float* dtT0  = ws + 12288000;         // 2,048,000
    float* dtT1  = ws + 14336000;         // 2,048,000
    float* xdbl0 = ws + 16384000;         //   320,000
    float* xdbl1 = ws + 16704000;         //   320,000
    unsigned short* xnb0 = (unsigned short*)(ws + 17024000);  // 256,000 fl
    unsigned short* xnb1 = (unsigned short*)(ws + 17280000);  // 256,000 fl
    // aliases (lifetimes disjoint, stream-ordered):
    unsigned short* wib0 = (unsigned short*)dtT0;   // dead once gemm_dt writes
    unsigned short* wib1 = (unsigned short*)dtT1;
    unsigned short* ygb0 = (unsigned short*)xcT0;   // xcT dead after scan
    unsigned short* ygb1 = (unsigned short*)xcT1;
    unsigned short* wob0 = (unsigned short*)dtT0;   // dtT dead after gate
    unsigned short* wob1 = (unsigned short*)dtT1;
    float* partial = xz0;                           // xz dead after gate
    float* bct = (float*)d_out;                     // BCT scratch lives in d_out
    float* out = (float*)d_out;

    rmsnorm_k<<<MROWS, 256, 0, stream>>>(x, P[0][0], P[1][0], xnb0, xnb1);

    cvt2_k<<<dim3(1024, 2), 256, 0, stream>>>(P[0][1], P[1][1], wib0, wib1, 262144);

    gemm1_mfma<<<dim3(16, 16, 2), 256, 0, stream>>>(
        xnb0, xnb1, wib0, wib1, xz0, xz1);

    conv_silu_k<<<dim3(16, 16, 4), 256, 0, stream>>>(
        xz0, xz1, P[0][2], P[1][2], P[0][3], P[1][3], xcT0, xcT1);

    gemm_xp_k<<<dim3(3, 16, 4), 256, 0, stream>>>(
        xcT0, xcT1, P[0][4], P[1][4], xdbl0, xdbl1, bct);

    gemm_dt_k<<<dim3(16, 16, 4), 256, 0, stream>>>(
        xdbl0, xdbl1, P[0][5], P[1][5], P[0][6], P[1][6], dtT0, dtT1);

    scan_k<<<dim3(256, 4), 256, 0, stream>>>(
        dtT0, dtT1, xcT0, xcT1, bct,
        P[0][7], P[1][7], P[0][8], P[1][8]);

    gate_k<<<dim3(16, 16, 4), 256, 0, stream>>>(
        dtT0, dtT1, xz0, xz1, ygb0, ygb1);

    cvt2_k<<<dim3(512, 2), 256, 0, stream>>>(P[0][9], P[1][9], wob0, wob1, 131072);

    gemm_out_mfma<<<dim3(8, 32, 2), 256, 0, stream>>>(
        ygb0, ygb1, wob0, wob1, partial);

    reduce_out_k<<<1000, 256, 0, stream>>>(x, partial, out);
}

// Round 9
// 296.665 us; speedup vs baseline: 4.3099x; 1.0651x over previous
//
#include <hip/hip_runtime.h>
#include <hip/hip_bf16.h>
#include <math.h>

#define DM   512
#define DI   1024
#define NS   64
#define RDT  32
#define BB   2
#define LL   1000
#define MROWS (BB*LL)   // 2000

typedef __attribute__((ext_vector_type(8))) short bf16x8;
typedef __attribute__((ext_vector_type(4))) float f32x4;

// f32 -> bf16 RNE (finite inputs)
__device__ __forceinline__ unsigned short f2bf(float f) {
    unsigned u = __builtin_bit_cast(unsigned, f);
    u = (u + 0x7FFF + ((u >> 16) & 1)) >> 16;
    return (unsigned short)u;
}

__device__ __forceinline__ float bcast_lane(float v, int lane) {
    return __builtin_bit_cast(float,
        __builtin_amdgcn_readlane(__builtin_bit_cast(int, v), lane));
}

// ------------------- rmsnorm -> per-dir bf16 (norm_w folded) ----------------
__global__ __launch_bounds__(256)
void rmsnorm_k(const float* __restrict__ x,
               const float* __restrict__ nw0, const float* __restrict__ nw1,
               unsigned short* __restrict__ xnb0, unsigned short* __restrict__ xnb1) {
    int row = blockIdx.x;
    int tid = threadIdx.x;
    const float* xr = x + (size_t)row * DM;
    float2 v = *(const float2*)(xr + tid * 2);
    float ss = v.x * v.x + v.y * v.y;
    #pragma unroll
    for (int off = 32; off; off >>= 1) ss += __shfl_xor(ss, off, 64);
    __shared__ float red[4];
    if ((tid & 63) == 0) red[tid >> 6] = ss;
    __syncthreads();
    float tot = red[0] + red[1] + red[2] + red[3];
    float scale = rsqrtf(tot / (float)DM + 1e-5f);
    float2 w0 = *(const float2*)(nw0 + tid * 2);
    float2 w1 = *(const float2*)(nw1 + tid * 2);
    short2 o0, o1;
    o0.x = (short)f2bf(v.x * scale * w0.x);
    o0.y = (short)f2bf(v.y * scale * w0.y);
    o1.x = (short)f2bf(v.x * scale * w1.x);
    o1.y = (short)f2bf(v.y * scale * w1.y);
    *(short2*)(xnb0 + (size_t)row * DM + tid * 2) = o0;
    *(short2*)(xnb1 + (size_t)row * DM + tid * 2) = o1;
}

// ------------------------------------ f32 -> bf16 convert, 2 arrays batched --
__global__ __launch_bounds__(256)
void cvt2_k(const float* __restrict__ in0, const float* __restrict__ in1,
            unsigned short* __restrict__ out0, unsigned short* __restrict__ out1,
            int n4) {
    int idx = blockIdx.x * 256 + threadIdx.x;
    if (idx >= n4) return;
    const float* in = blockIdx.y ? in1 : in0;
    unsigned short* out = blockIdx.y ? out1 : out0;
    float4 v = *(const float4*)(in + (size_t)idx * 4);
    short4 o;
    o.x = (short)f2bf(v.x); o.y = (short)f2bf(v.y);
    o.z = (short)f2bf(v.z); o.w = (short)f2bf(v.w);
    *(short4*)(out + (size_t)idx * 4) = o;
}

// ------------- GEMM1 (in_proj) bf16 MFMA: xz[dir] = xn_dir @ W^T ------------
__global__ __launch_bounds__(256, 2)
void gemm1_mfma(const unsigned short* __restrict__ xnb0,
                const unsigned short* __restrict__ xnb1,
                const unsigned short* __restrict__ wib0,
                const unsigned short* __restrict__ wib1,
                float* __restrict__ xz0, float* __restrict__ xz1)
{
    __shared__ __align__(16) unsigned short As[128 * 40];
    __shared__ __align__(16) unsigned short Bs[128 * 40];
    int dir = blockIdx.z;
    const unsigned short* A = dir ? xnb1 : xnb0;
    const unsigned short* W = dir ? wib1 : wib0;
    float* C = dir ? xz1 : xz0;
    int n0 = blockIdx.x * 128, m0 = blockIdx.y * 128;
    int tid = threadIdx.x;
    int wv = tid >> 6, lane = tid & 63;
    int wr = wv >> 1, wc = wv & 1;
    int fl = lane & 15, kg = lane >> 4;

    f32x4 acc[4][4];
    #pragma unroll
    for (int i = 0; i < 4; i++)
        #pragma unroll
        for (int j = 0; j < 4; j++) acc[i][j] = (f32x4){0.f, 0.f, 0.f, 0.f};

    int sr = tid >> 2, cg = tid & 3;
    for (int k0 = 0; k0 < 512; k0 += 32) {
        #pragma unroll
        for (int i = 0; i < 2; i++) {
            int row = sr + i * 64;
            int m = m0 + row;
            float4 av = make_float4(0.f, 0.f, 0.f, 0.f);
            if (m < MROWS) {
                int rs = m;
                if (dir) { int b = m / LL, t = m % LL; rs = b * LL + (LL - 1 - t); }
                av = *(const float4*)(A + (size_t)rs * 512 + k0 + cg * 8);
            }
            *(float4*)(&As[row * 40 + cg * 8]) = av;
            float4 wv4 = *(const float4*)(W + (size_t)(n0 + row) * 512 + k0 + cg * 8);
            *(float4*)(&Bs[row * 40 + cg * 8]) = wv4;
        }
        __syncthreads();
        bf16x8 af[4], bf[4];
        #pragma unroll
        for (int fr = 0; fr < 4; fr++)
            af[fr] = *(const bf16x8*)(&As[(wr * 64 + fr * 16 + fl) * 40 + kg * 8]);
        #pragma unroll
        for (int fc = 0; fc < 4; fc++)
            bf[fc] = *(const bf16x8*)(&Bs[(wc * 64 + fc * 16 + fl) * 40 + kg * 8]);
        #pragma unroll
        for (int fr = 0; fr < 4; fr++)
            #pragma unroll
            for (int fc = 0; fc < 4; fc++)
                acc[fr][fc] = __builtin_amdgcn_mfma_f32_16x16x32_bf16(
                    af[fr], bf[fc], acc[fr][fc], 0, 0, 0);
        __syncthreads();
    }
    #pragma unroll
    for (int fr = 0; fr < 4; fr++)
        #pragma unroll
        for (int fc = 0; fc < 4; fc++)
            #pragma unroll
            for (int j = 0; j < 4; j++) {
                int m = m0 + wr * 64 + fr * 16 + kg * 4 + j;
                if (m < MROWS) {
                    int n = n0 + wc * 64 + fc * 16 + fl;
                    C[(size_t)m * 2048 + n] = acc[fr][fc][j];
                }
            }
}

// -------- out_proj bf16 MFMA, 128x128 tile, full K, per-dir -> partials -----
__global__ __launch_bounds__(256, 2)
void gemm_out_mfma(const unsigned short* __restrict__ ygb0,
                   const unsigned short* __restrict__ ygb1,
                   const unsigned short* __restrict__ wob0,
                   const unsigned short* __restrict__ wob1,
                   float* __restrict__ partial)
{
    __shared__ __align__(16) unsigned short As[128 * 40];
    __shared__ __align__(16) unsigned short Bs[128 * 40];
    int dir = blockIdx.z;
    const unsigned short* A = dir ? ygb1 : ygb0;   // (2000,1024)
    const unsigned short* W = dir ? wob1 : wob0;   // (512,1024)
    float* P = partial + (size_t)dir * MROWS * 512;
    int n0 = blockIdx.x * 128, m0 = blockIdx.y * 128;
    int tid = threadIdx.x;
    int wv = tid >> 6, lane = tid & 63;
    int wr = wv >> 1, wc = wv & 1;
    int fl = lane & 15, kg = lane >> 4;

    f32x4 acc[4][4];
    #pragma unroll
    for (int i = 0; i < 4; i++)
        #pragma unroll
        for (int j = 0; j < 4; j++) acc[i][j] = (f32x4){0.f, 0.f, 0.f, 0.f};

    int sr = tid >> 2, cg = tid & 3;
    for (int k0 = 0; k0 < 1024; k0 += 32) {
        #pragma unroll
        for (int i = 0; i < 2; i++) {
            int row = sr + i * 64;
            int m = m0 + row;
            float4 av = make_float4(0.f, 0.f, 0.f, 0.f);
            if (m < MROWS)
                av = *(const float4*)(A + (size_t)m * 1024 + k0 + cg * 8);
            *(float4*)(&As[row * 40 + cg * 8]) = av;
            float4 wv4 = *(const float4*)(W + (size_t)(n0 + row) * 1024 + k0 + cg * 8);
            *(float4*)(&Bs[row * 40 + cg * 8]) = wv4;
        }
        __syncthreads();
        bf16x8 af[4], bf[4];
        #pragma unroll
        for (int fr = 0; fr < 4; fr++)
            af[fr] = *(const bf16x8*)(&As[(wr * 64 + fr * 16 + fl) * 40 + kg * 8]);
        #pragma unroll
        for (int fc = 0; fc < 4; fc++)
            bf[fc] = *(const bf16x8*)(&Bs[(wc * 64 + fc * 16 + fl) * 40 + kg * 8]);
        #pragma unroll
        for (int fr = 0; fr < 4; fr++)
            #pragma unroll
            for (int fc = 0; fc < 4; fc++)
                acc[fr][fc] = __builtin_amdgcn_mfma_f32_16x16x32_bf16(
                    af[fr], bf[fc], acc[fr][fc], 0, 0, 0);
        __syncthreads();
    }
    #pragma unroll
    for (int fr = 0; fr < 4; fr++)
        #pragma unroll
        for (int fc = 0; fc < 4; fc++)
            #pragma unroll
            for (int j = 0; j < 4; j++) {
                int m = m0 + wr * 64 + fr * 16 + kg * 4 + j;
                if (m < MROWS) {
                    int n = n0 + wc * 64 + fc * 16 + fl;
                    P[(size_t)m * 512 + n] = acc[fr][fc][j];
                }
            }
}

// out[m] = 2x[m] + pf[m] + pb[flip(m)]
__global__ __launch_bounds__(256)
void reduce_out_k(const float* __restrict__ x, const float* __restrict__ partial,
                  float* __restrict__ out)
{
    int idx = blockIdx.x * 256 + threadIdx.x;
    if (idx >= MROWS * 128) return;
    int m = idx >> 7, q = idx & 127;
    int b = m / LL, t = m % LL;
    int fm = b * LL + (LL - 1 - t);
    const float* p0 = partial;
    const float* p1 = partial + (size_t)MROWS * 512;
    float4 xv = *(const float4*)(x  + (size_t)m  * 512 + q * 4);
    float4 a  = *(const float4*)(p0 + (size_t)m  * 512 + q * 4);
    float4 c  = *(const float4*)(p1 + (size_t)fm * 512 + q * 4);
    float4 o;
    o.x = 2.f * xv.x + a.x + c.x;
    o.y = 2.f * xv.y + a.y + c.y;
    o.z = 2.f * xv.z + a.z + c.z;
    o.w = 2.f * xv.w + a.w + c.w;
    *(float4*)(out + (size_t)m * 512 + q * 4) = o;
}

// --------- causal dwconv + silu -> xcT f32 [b][d][t]  AND  xcb bf16 [t][d] --
__global__ __launch_bounds__(256)
void conv_silu_k(const float* __restrict__ xz0, const float* __restrict__ xz1,
                 const float* __restrict__ cw0, const float* __restrict__ cw1,
                 const float* __restrict__ cb0, const float* __restrict__ cb1,
                 float* __restrict__ xcT0, float* __restrict__ xcT1,
                 unsigned short* __restrict__ xcb0, unsigned short* __restrict__ xcb1)
{
    __shared__ float Ls[64 * 65];
    int dirb = blockIdx.z;
    int dir = dirb >> 1, b = dirb & 1;
    int d0 = blockIdx.x * 64, t0 = blockIdx.y * 64;
    int tid = threadIdx.x;
    int dl = tid & 63, tg = tid >> 6;

    const float* in = (dir ? xz1 : xz0) + (size_t)b * LL * 2048;
    const float* cw = dir ? cw1 : cw0;
    const float* cb = dir ? cb1 : cb0;
    float*      xcT = dir ? xcT1 : xcT0;
    unsigned short* xcb = dir ? xcb1 : xcb0;

    float4 w4 = ((const float4*)cw)[d0 + dl];
    float bias = cb[d0 + dl];

    int ts = t0 + tg * 16;
    float x3 = 0.f, x2 = 0.f, x1 = 0.f;
    if (ts - 3 >= 0 && ts - 3 < LL) x3 = in[(size_t)(ts - 3) * 2048 + d0 + dl];
    if (ts - 2 >= 0 && ts - 2 < LL) x2 = in[(size_t)(ts - 2) * 2048 + d0 + dl];
    if (ts - 1 >= 0 && ts - 1 < LL) x1 = in[(size_t)(ts - 1) * 2048 + d0 + dl];

    #pragma unroll
    for (int i = 0; i < 16; i++) {
        int t = ts + i;
        float x0v = (t < LL) ? in[(size_t)t * 2048 + d0 + dl] : 0.f;
        float a = bias + x3 * w4.x + x2 * w4.y + x1 * w4.z + x0v * w4.w;
        float s = a / (1.f + __expf(-a));
        Ls[dl * 65 + tg * 16 + i] = s;
        if (t < LL)
            xcb[((size_t)(b * LL + t)) * 1024 + d0 + dl] = f2bf(s);
        x3 = x2; x2 = x1; x1 = x0v;
    }
    __syncthreads();
    int tl = tid & 63, dg = tid >> 6;
    #pragma unroll
    for (int i = 0; i < 16; i++) {
        int dd = dg * 16 + i;
        int t = t0 + tl;
        if (t < LL)
            xcT[((size_t)(b * 1024) + d0 + dd) * LL + t] = Ls[dd * 65 + tl];
    }
}

// --------------- x_proj bf16 MFMA: per (dirb) 1000x160 = xcb @ xp^T ---------
// outputs: xd [t][32] f32 (dt_raw cols 0..31), bct[dirb][n-32][t] (cols 32..159)
__global__ __launch_bounds__(256, 2)
void gemm_xp_mfma(const unsigned short* __restrict__ xcb0,
                  const unsigned short* __restrict__ xcb1,
                  const unsigned short* __restrict__ xpb0,
                  const unsigned short* __restrict__ xpb1,
                  float* __restrict__ xd0, float* __restrict__ xd1,
                  float* __restrict__ bct)
{
    __shared__ __align__(16) unsigned short As[64 * 40];
    __shared__ __align__(16) unsigned short Ws[160 * 40];
    int dirb = blockIdx.y;
    int dir = dirb >> 1, b = dirb & 1;
    const unsigned short* A = (dir ? xcb1 : xcb0) + (size_t)b * LL * 1024;
    const unsigned short* W = dir ? xpb1 : xpb0;   // (160,1024)
    float* xd = (dir ? xd1 : xd0) + (size_t)b * LL * 32;
    float* bc = bct + (size_t)dirb * 128 * LL;
    int m0 = blockIdx.x * 64;
    int tid = threadIdx.x;
    int wv = tid >> 6, lane = tid & 63;
    int fl = lane & 15, kg = lane >> 4;

    f32x4 acc[10];
    #pragma unroll
    for (int f = 0; f < 10; f++) acc[f] = (f32x4){0.f, 0.f, 0.f, 0.f};

    int sr = tid >> 2, cg = tid & 3;
    for (int k0 = 0; k0 < 1024; k0 += 32) {
        {   // A tile 64x32
            int t = m0 + sr;
            float4 av = make_float4(0.f, 0.f, 0.f, 0.f);
            if (t < LL)
                av = *(const float4*)(A + (size_t)t * 1024 + k0 + cg * 8);
            *(float4*)(&As[sr * 40 + cg * 8]) = av;
        }
        #pragma unroll
        for (int it = 0; it < 3; it++) {   // W tile 160x32
            int row = sr + it * 64;
            if (row < 160) {
                float4 wv4 = *(const float4*)(W + (size_t)row * 1024 + k0 + cg * 8);
                *(float4*)(&Ws[row * 40 + cg * 8]) = wv4;
            }
        }
        __syncthreads();
        bf16x8 af = *(const bf16x8*)(&As[(wv * 16 + fl) * 40 + kg * 8]);
        #pragma unroll
        for (int f = 0; f < 10; f++) {
            bf16x8 bf = *(const bf16x8*)(&Ws[(f * 16 + fl) * 40 + kg * 8]);
            acc[f] = __builtin_amdgcn_mfma_f32_16x16x32_bf16(af, bf, acc[f], 0, 0, 0);
        }
        __syncthreads();
    }

    // epilogue: f=0,1 -> xd[t][32]; f=2..9 -> bct[n-32][t]
    #pragma unroll
    for (int f = 0; f < 10; f++) {
        int n = f * 16 + fl;
        #pragma unroll
        for (int j = 0; j < 4; j++) {
            int t = m0 + wv * 16 + kg * 4 + j;
            if (t >= LL) continue;
            if (f < 2) xd[(size_t)t * 32 + n] = acc[f][j];
            else       bc[(size_t)(n - 32) * LL + t] = acc[f][j];
        }
    }
}

// ---- dt GEMM (K=32) + softplus, output TRANSPOSED dtT [b][d][t] ------------
__global__ __launch_bounds__(256)
void gemm_dt_k(const float* __restrict__ xd0, const float* __restrict__ xd1,
               const float* __restrict__ w0, const float* __restrict__ w1,
               const float* __restrict__ bb0, const float* __restrict__ bb1,
               float* __restrict__ dtT0, float* __restrict__ dtT1)
{
    __shared__ float As[64 * 33];
    __shared__ float Ws[32 * 68];
    __shared__ float T[64 * 67];
    int dirb = blockIdx.z;
    int dir = dirb >> 1, b = dirb & 1;
    const float* xd = (dir ? xd1 : xd0) + (size_t)b * LL * 32;
    const float* W  = dir ? w1 : w0;
    const float* bi = dir ? bb1 : bb0;
    float*      dtT = (dir ? dtT1 : dtT0) + (size_t)b * 1024 * LL;
    int n0 = blockIdx.x * 64, t0 = blockIdx.y * 64;
    int tid = threadIdx.x;
    int tx = tid & 15, ty = tid >> 4;

    #pragma unroll
    for (int i = 0; i < 2; i++) {
        int j = tid + 256 * i;
        int row = j >> 3, q = j & 7;
        float4 v = make_float4(0.f, 0.f, 0.f, 0.f);
        if (t0 + row < LL)
            v = *(const float4*)(xd + (size_t)(t0 + row) * 32 + q * 4);
        As[row * 33 + q * 4 + 0] = v.x;
        As[row * 33 + q * 4 + 1] = v.y;
        As[row * 33 + q * 4 + 2] = v.z;
        As[row * 33 + q * 4 + 3] = v.w;
        float4 wv = *(const float4*)(W + (size_t)(n0 + row) * 32 + q * 4);
        Ws[(q * 4 + 0) * 68 + row] = wv.x;
        Ws[(q * 4 + 1) * 68 + row] = wv.y;
        Ws[(q * 4 + 2) * 68 + row] = wv.z;
        Ws[(q * 4 + 3) * 68 + row] = wv.w;
    }
    __syncthreads();

    float acc[4][4] = {};
    #pragma unroll 8
    for (int k = 0; k < 32; k++) {
        float4 w = *(const float4*)(Ws + k * 68 + tx * 4);
        float wvv[4] = {w.x, w.y, w.z, w.w};
        float av[4];
        #pragma unroll
        for (int i = 0; i < 4; i++) av[i] = As[(ty * 4 + i) * 33 + k];
        #pragma unroll
        for (int i = 0; i < 4; i++)
            #pragma unroll
            for (int j = 0; j < 4; j++)
                acc[i][j] = fmaf(av[i], wvv[j], acc[i][j]);
    }
    __syncthreads();

    #pragma unroll
    for (int i = 0; i < 4; i++) {
        #pragma unroll
        for (int j = 0; j < 4; j++) {
            int n = tx * 4 + j;
            float v = acc[i][j] + bi[n0 + n];
            v = (v > 20.f) ? v : log1pf(__expf(v));
            T[n * 67 + ty * 4 + i] = v;
        }
    }
    __syncthreads();

    int tl = tid & 63, ng = tid >> 6;
    #pragma unroll
    for (int i = 0; i < 16; i++) {
        int nl = ng * 16 + i;
        int t = t0 + tl;
        if (t < LL)
            dtT[(size_t)(n0 + nl) * LL + t] = T[nl * 67 + tl];
    }
}

// ------------------------------------------------------------ selective scan
// T14 async-stage: next tile's B/C + dt/u prefetched into REGISTERS during
// current tile's compute; LDS write happens at loop head (write-late).
__global__ __launch_bounds__(256)
void scan_k(float* __restrict__ dtT0, float* __restrict__ dtT1,
            const float* __restrict__ ucT0, const float* __restrict__ ucT1,
            const float* __restrict__ bct,
            const float* __restrict__ Al0, const float* __restrict__ Al1,
            const float* __restrict__ Dc0, const float* __restrict__ Dc1)
{
    __shared__ float Bs[64 * 34];
    __shared__ float Cs[64 * 34];
    __shared__ float Pt[4][16 * 66];
    int dirb = blockIdx.y;
    int dir = dirb >> 1, b = dirb & 1;
    int wid = threadIdx.x >> 6, lane = threadIdx.x & 63;
    int d = blockIdx.x * 4 + wid;
    float* Pw = Pt[wid];

    float*       dtT = (dir ? dtT1 : dtT0);
    const float* ucT = (dir ? ucT1 : ucT0);
    const float* Al  = dir ? Al1 : Al0;
    const float* Dc  = dir ? Dc1 : Dc0;

    float a  = -__expf(Al[d * 64 + lane]) * 1.44269504f;
    float Dp = Dc[d];
    float h  = 0.f;
    size_t chan = ((size_t)(b * 1024 + d)) * LL;
    const float* Bg = bct + (size_t)dirb * 128 * LL;

    int srow = threadIdx.x >> 2;
    int scol = (threadIdx.x & 3) * 8;
    int tl16 = lane & 15, qq = lane >> 4;
    const float* Prow = Pw + tl16 * 66 + qq * 16;

    float4 rb0, rb1, rc0, rc1;
    float dta = 0.f, ua = 0.f;
    {
        const float* Bp = Bg + (size_t)srow * LL + scol;
        const float* Cp = Bg + (size_t)(srow + 64) * LL + scol;
        rb0 = *(const float4*)(Bp);     rb1 = *(const float4*)(Bp + 4);
        rc0 = *(const float4*)(Cp);     rc1 = *(const float4*)(Cp + 4);
        if (lane < 32) {
            dta = dtT[chan + lane];
            ua  = ucT[chan + lane];
        }
    }

    for (int t0 = 0; t0 < LL; t0 += 32) {
        int rem = min(32, LL - t0);
        __syncthreads();
        *(float4*)(&Bs[srow * 34 + scol])     = rb0;
        *(float4*)(&Bs[srow * 34 + scol + 4]) = rb1;
        *(float4*)(&Cs[srow * 34 + scol])     = rc0;
        *(float4*)(&Cs[srow * 34 + scol + 4]) = rc1;
        float dcur = dta, ucur = ua;
        float wsc  = dcur * ucur;
        __syncthreads();

        if (t0 + 32 < LL) {
            const float* Bp = Bg + (size_t)srow * LL + (t0 + 32) + scol;
            const float* Cp = Bg + (size_t)(srow + 64) * LL + (t0 + 32) + scol;
            rb0 = *(const float4*)(Bp);     rb1 = *(const float4*)(Bp + 4);
            rc0 = *(const float4*)(Cp);     rc1 = *(const float4*)(Cp + 4);
            if (lane < min(32, LL - t0 - 32)) {
                dta = dtT[chan + t0 + 32 + lane];
                ua  = ucT[chan + t0 + 32 + lane];
            }
        }

        for (int sec = 0; sec < 2; sec++) {
            int sbase = sec * 16;
            int steps = rem - sbase;
            if (steps <= 0) break;
            if (steps > 16) steps = 16;
            if (steps < 16) {
                for (int i = steps; i < 16; i++) Pw[i * 66 + lane] = 0.f;
            }
            int ngr = (steps + 7) >> 3;
            for (int g = 0; g < ngr; g++) {
                int tb = sbase + g * 8;
                float4 B0 = *(const float4*)(&Bs[lane * 34 + tb]);
                float4 B1 = *(const float4*)(&Bs[lane * 34 + tb + 4]);
                float4 C0 = *(const float4*)(&Cs[lane * 34 + tb]);
                float4 C1 = *(const float4*)(&Cs[lane * 34 + tb + 4]);
                #pragma unroll
                for (int i = 0; i < 8; i++) {
                    float dtv = bcast_lane(dcur, tb + i);
                    float w   = bcast_lane(wsc,  tb + i);
                    float dA  = exp2f(dtv * a);
                    float Bn  = (i < 4) ? B0[i] : B1[i - 4];
                    float Cn  = (i < 4) ? C0[i] : C1[i - 4];
                    h = fmaf(dA, h, w * Bn);
                    Pw[(g * 8 + i) * 66 + lane] = h * Cn;
                }
            }
            float s = 0.f;
            #pragma unroll
            for (int j = 0; j < 8; j++) {
                float2 v = *(const float2*)(Prow + j * 2);
                s += v.x + v.y;
            }
#if __has_builtin(__builtin_amdgcn_permlane32_swap)
            {
                unsigned aa = __builtin_bit_cast(unsigned, s);
                auto r = __builtin_amdgcn_permlane32_swap(aa, aa, false, false);
                s = __builtin_bit_cast(float, (unsigned)r[0]) +
                    __builtin_bit_cast(float, (unsigned)r[1]);
            }
#else
            s += __shfl_xor(s, 32, 64);
#endif
#if __has_builtin(__builtin_amdgcn_permlane16_swap)
            {
                unsigned aa = __builtin_bit_cast(unsigned, s);
                auto r = __builtin_amdgcn_permlane16_swap(aa, aa, false, false);
                s = __builtin_bit_cast(float, (unsigned)r[0]) +
                    __builtin_bit_cast(float, (unsigned)r[1]);
            }
#else
            s += __shfl_xor(s, 16, 64);
#endif
            float uf = __shfl(ucur, sbase + tl16, 64);
            s = fmaf(uf, Dp, s);
            if (lane < steps)
                dtT[chan + t0 + sbase + lane] = s;
        }
    }
}

// ------- gate: ygb[t][d] = bf16( yT[d][t] * silu(z[t][1024+d]) ) ------------
__global__ __launch_bounds__(256)
void gate_k(const float* __restrict__ yT0, const float* __restrict__ yT1,
            const float* __restrict__ xz0, const float* __restrict__ xz1,
            unsigned short* __restrict__ yg0, unsigned short* __restrict__ yg1)
{
    __shared__ float Ls[64 * 65];
    int dirb = blockIdx.z;
    int dir = dirb >> 1, b = dirb & 1;
    int d0 = blockIdx.x * 64, t0 = blockIdx.y * 64;
    int tid = threadIdx.x;
    const float* yT = (dir ? yT1 : yT0) + (size_t)b * 1024 * LL;
    const float* xz = (dir ? xz1 : xz0) + (size_t)b * LL * 2048;
    unsigned short* yg = dir ? yg1 : yg0;

    int tl = tid & 63, dg = tid >> 6;
    #pragma unroll
    for (int i = 0; i < 16; i++) {
        int dd = dg * 16 + i;
        int t = t0 + tl;
        float v = (t < LL) ? yT[(size_t)(d0 + dd) * LL + t] : 0.f;
        Ls[dd * 65 + tl] = v;
    }
    __syncthreads();
    int dcol = tid & 63, tg = tid >> 6;
    #pragma unroll
    for (int i = 0; i < 16; i++) {
        int t = t0 + tg * 16 + i;
        if (t >= LL) continue;
        float z = xz[(size_t)t * 2048 + 1024 + d0 + dcol];
        float y = Ls[dcol * 65 + tg * 16 + i];
        float s = z / (1.f + __expf(-z));
        yg[((size_t)(b * LL + t)) * 1024 + d0 + dcol] = f2bf(y * s);
    }
}

// -------------------------------------------------------------------- launch
extern "C" void kernel_launch(void* const* d_in, const int* in_sizes, int n_in,
                              void* d_out, int out_size, void* d_ws, size_t ws_size,
                              hipStream_t stream) {
    const float* x = (const float*)d_in[0];
    const float* P[2][10];
    for (int dir = 0; dir < 2; dir++)
        for (int i = 0; i < 10; i++)
            P[dir][i] = (const float*)d_in[1 + dir * 10 + i];

    float* ws = (float*)d_ws;
    float* xz0   = ws;                    // 4,096,000
    float* xz1   = ws + 4096000;          // 4,096,000
    float* xcT0  = ws + 8192000;          // 2,048,000
    float* xcT1  = ws + 10240000;         // 2,048,000
    float* dtT0  = ws + 12288000;         // 2,048,000
    float* dtT1  = ws + 14336000;         // 2,048,000
    float* xdbl0 = ws + 16384000;         //    64,000
    float* xdbl1 = ws + 16448000;         //    64,000
    unsigned short* xnb0 = (unsigned short*)(ws + 17024000);  // 256,000 fl
    unsigned short* xnb1 = (unsigned short*)(ws + 17280000);  // 256,000 fl
    // aliases (lifetimes disjoint, stream-ordered):
    unsigned short* wib0 = (unsigned short*)(ws + 14336000);  // dtT1 region, dead before gemm_dt
    unsigned short* wib1 = (unsigned short*)(ws + 14860288);
    unsigned short* xcb0 = (unsigned short*)(ws + 12288000);  // dtT0 region, dead before gemm_dt
    unsigned short* xcb1 = (unsigned short*)(ws + 13312000);
    unsigned short* xpb0 = (unsigned short*)(ws + 17024000);  // xnb region, after gemm1
    unsigned short* xpb1 = (unsigned short*)(ws + 17280000);
    unsigned short* ygb0 = (unsigned short*)xcT0;   // xcT dead after scan
    unsigned short* ygb1 = (unsigned short*)xcT1;
    unsigned short* wob0 = (unsigned short*)dtT0;   // dtT dead after gate
    unsigned short* wob1 = (unsigned short*)(dtT0 + 262144);
    float* partial = xz0;                           // xz dead after gate
    float* bct = (float*)d_out;                     // BCT scratch lives in d_out
    float* out = (float*)d_out;

    rmsnorm_k<<<MROWS, 256, 0, stream>>>(x, P[0][0], P[1][0], xnb0, xnb1);

    cvt2_k<<<dim3(1024, 2), 256, 0, stream>>>(P[0][1], P[1][1], wib0, wib1, 262144);

    gemm1_mfma<<<dim3(16, 16, 2), 256, 0, stream>>>(
        xnb0, xnb1, wib0, wib1, xz0, xz1);

    // x_proj weights -> bf16 (reuses dead xnb slots)
    cvt2_k<<<dim3(160, 2), 256, 0, stream>>>(P[0][4], P[1][4], xpb0, xpb1, 40960);

    conv_silu_k<<<dim3(16, 16, 4), 256, 0, stream>>>(
        xz0, xz1, P[0][2], P[1][2], P[0][3], P[1][3], xcT0, xcT1, xcb0, xcb1);

    gemm_xp_mfma<<<dim3(16, 4), 256, 0, stream>>>(
        xcb0, xcb1, xpb0, xpb1, xdbl0, xdbl1, bct);

    gemm_dt_k<<<dim3(16, 16, 4), 256, 0, stream>>>(
        xdbl0, xdbl1, P[0][5], P[1][5], P[0][6], P[1][6], dtT0, dtT1);

    scan_k<<<dim3(256, 4), 256, 0, stream>>>(
        dtT0, dtT1, xcT0, xcT1, bct,
        P[0][7], P[1][7], P[0][8], P[1][8]);

    gate_k<<<dim3(16, 16, 4), 256, 0, stream>>>(
        dtT0, dtT1, xz0, xz1, ygb0, ygb1);

    cvt2_k<<<dim3(512, 2), 256, 0, stream>>>(P[0][9], P[1][9], wob0, wob1, 131072);

    gemm_out_mfma<<<dim3(4, 16, 2), 256, 0, stream>>>(
        ygb0, ygb1, wob0, wob1, partial);

    reduce_out_k<<<1000, 256, 0, stream>>>(x, partial, out);
}